// Round 1
// baseline (2157.437 us; speedup 1.0000x reference)
//
#include <hip/hip_runtime.h>
#include <math.h>

// Problem constants
// B=2, DIM=256, H=W=32, L=1024, HALF=128, DI=256, DS=16, DTR=8, DEPTH=2, K1=4

__device__ __forceinline__ float dev_silu(float x){ return x * (1.0f/(1.0f + __expf(-x))); }
__device__ __forceinline__ float dev_softplus(float x){ return fmaxf(x,0.0f) + log1pf(__expf(-fabsf(x))); }

// ---------------- proj: p1/p2 = proj_w @ x + b ; store as (B, L, 128) ----------------
__global__ void __launch_bounds__(256)
k_proj(const float* __restrict__ x, const float* __restrict__ w1, const float* __restrict__ b1,
       const float* __restrict__ w2, const float* __restrict__ b2,
       float* __restrict__ sm, float* __restrict__ sv)
{
    int bl = blockIdx.x;            // b*L + l
    int b = bl >> 10, l = bl & 1023;
    int tid = threadIdx.x;
    __shared__ float xs[256];
    xs[tid] = x[(size_t)(b*256 + tid)*1024 + l];
    __syncthreads();
    int o = tid & 127;
    const float* wr = (tid < 128) ? (w1 + o*256) : (w2 + o*256);
    float acc = (tid < 128) ? b1[o] : b2[o];
    #pragma unroll 8
    for (int c = 0; c < 256; ++c) acc = fmaf(wr[c], xs[c], acc);
    if (tid < 128) sm[(size_t)bl*128 + o] = acc;
    else           sv[(size_t)bl*128 + o] = acc;
}

// ---------------- LN over 128 + matmul (128->512) -> u (B,L,256), z (B,L,256) --------
__global__ void __launch_bounds__(256)
k_lnmm(const float* __restrict__ s, const float* __restrict__ lnw, const float* __restrict__ lnb,
       const float* __restrict__ inw, float* __restrict__ u, float* __restrict__ z)
{
    int bl = blockIdx.x; int tid = threadIdx.x;
    __shared__ float row[128];
    __shared__ float hn[128];
    __shared__ float sA[4], sB[4];
    float v = 0.f;
    if (tid < 128){ v = s[(size_t)bl*128 + tid]; row[tid] = v; }
    float a = v, q = v*v;
    for (int o = 32; o; o >>= 1){ a += __shfl_down(a,o); q += __shfl_down(q,o); }
    if ((tid & 63) == 0){ sA[tid>>6] = a; sB[tid>>6] = q; }
    __syncthreads();
    float mean = (sA[0]+sA[1]+sA[2]+sA[3]) * (1.0f/128.0f);
    float var  = (sB[0]+sB[1]+sB[2]+sB[3]) * (1.0f/128.0f) - mean*mean;
    float rs = rsqrtf(var + 1e-5f);
    if (tid < 128) hn[tid] = (row[tid]-mean)*rs*lnw[tid] + lnb[tid];
    __syncthreads();
    float a0 = 0.f, a1 = 0.f;
    for (int c = 0; c < 128; ++c){
        float hc = hn[c];
        a0 = fmaf(hc, inw[c*512 + tid],       a0);
        a1 = fmaf(hc, inw[c*512 + tid + 256], a1);
    }
    u[(size_t)bl*256 + tid] = a0;
    z[(size_t)bl*256 + tid] = a1;
}

// ---------------- mamba causal conv (K1=4) + silu ----------------
__global__ void __launch_bounds__(256)
k_mconv(const float* __restrict__ ur, const float* __restrict__ cw, const float* __restrict__ cb,
        float* __restrict__ uc)
{
    int bl = blockIdx.x; int b = bl >> 10, l = bl & 1023; int d = threadIdx.x;
    float acc = cb[d];
    #pragma unroll
    for (int k = 0; k < 4; ++k){
        int lp = l - 3 + k;
        if (lp >= 0) acc = fmaf(ur[((size_t)(b<<10) + lp)*256 + d], cw[d*4 + k], acc);
    }
    uc[(size_t)bl*256 + d] = dev_silu(acc);
}

// ---------------- vss depthwise 3x3 conv + silu + 4-direction scatter ----------------
__global__ void __launch_bounds__(256)
k_vconv(const float* __restrict__ ur, const float* __restrict__ cw, const float* __restrict__ cb,
        float* __restrict__ us)
{
    int bl = blockIdx.x; int b = bl >> 10, l = bl & 1023; int d = threadIdx.x;
    int h = l >> 5, w = l & 31;
    float acc = cb[d];
    #pragma unroll
    for (int kh = 0; kh < 3; ++kh){
        int hh = h + kh - 1; if (hh < 0 || hh > 31) continue;
        #pragma unroll
        for (int kw = 0; kw < 3; ++kw){
            int ww = w + kw - 1; if (ww < 0 || ww > 31) continue;
            acc = fmaf(ur[((size_t)(b<<10) + (hh<<5) + ww)*256 + d], cw[d*9 + kh*3 + kw], acc);
        }
    }
    float v = dev_silu(acc);
    int l1 = (w<<5) + h;   // column-major scan position
    size_t base = (size_t)b*4*1024*256;
    us[base + ((size_t)0*1024 + l        )*256 + d] = v;
    us[base + ((size_t)1*1024 + l1       )*256 + d] = v;
    us[base + ((size_t)2*1024 + (1023-l ))*256 + d] = v;
    us[base + ((size_t)3*1024 + (1023-l1))*256 + d] = v;
}

// ---------------- xproj (u @ xw -> dtr,B,C) + dt = softplus(dtr@dtw + dtb) ----------------
__global__ void __launch_bounds__(256)
k_xproj(const float* __restrict__ u, const float* __restrict__ xw, const float* __restrict__ dtw,
        const float* __restrict__ dtb, float* __restrict__ dt, float* __restrict__ Bm,
        float* __restrict__ Cm, int K)
{
    int idx = blockIdx.x;          // bk*L + l   (bk = b*K + k)
    int bk = idx >> 10;
    int k = bk % K;
    int tid = threadIdx.x;
    __shared__ float ursh[256];
    __shared__ float part[4][40];
    __shared__ float dbc[40];
    ursh[tid] = u[(size_t)idx*256 + tid];
    __syncthreads();
    if (tid < 160){
        int r = tid % 40, p = tid / 40;    // p in [0,4)
        const float* xwc = xw + (size_t)k*256*40 + r;
        float a = 0.f;
        int c0 = p*64;
        for (int c = c0; c < c0 + 64; ++c) a = fmaf(ursh[c], xwc[c*40], a);
        part[p][r] = a;
    }
    __syncthreads();
    if (tid < 40) dbc[tid] = part[0][tid] + part[1][tid] + part[2][tid] + part[3][tid];
    __syncthreads();
    const float* dtwk = dtw + (size_t)k*8*256;
    float a = dtb[k*256 + tid];
    #pragma unroll
    for (int r = 0; r < 8; ++r) a = fmaf(dbc[r], dtwk[r*256 + tid], a);
    dt[(size_t)idx*256 + tid] = dev_softplus(a);
    if (tid < 16)      Bm[(size_t)idx*16 + tid]        = dbc[8 + tid];
    else if (tid < 32) Cm[(size_t)idx*16 + (tid - 16)] = dbc[8 + tid];  // dbc[24..39]
}

// ---------------- selective scan: thread per (d,s); 16 d x 16 s per block ----------------
__global__ void __launch_bounds__(256)
k_scan(const float* __restrict__ dt, const float* __restrict__ u, const float* __restrict__ Bm,
       const float* __restrict__ Cm, const float* __restrict__ Alog, float* __restrict__ y, int K)
{
    int blk = blockIdx.x;          // bk*16 + g
    int g = blk & 15; int bk = blk >> 4; int k = bk % K;
    int tid = threadIdx.x;
    int dd = tid >> 4, s = tid & 15;
    int d = g*16 + dd;
    float A = -__expf(Alog[((size_t)k*256 + d)*16 + s]);
    const float* dtp = dt + (size_t)bk*1024*256 + d;
    const float* up  = u  + (size_t)bk*1024*256 + d;
    const float* Bp  = Bm + (size_t)bk*1024*16 + s;
    const float* Cp  = Cm + (size_t)bk*1024*16 + s;
    float* yp = y + (size_t)bk*1024*256 + d;
    float h = 0.f;
    #pragma unroll 4
    for (int l = 0; l < 1024; ++l){
        float dtv = dtp[(size_t)l*256];
        float uv  = up[(size_t)l*256];
        float bv  = Bp[l*16];
        float cv  = Cp[l*16];
        float av  = __expf(dtv * A);
        h = fmaf(av, h, dtv*uv*bv);
        float py = h * cv;
        py += __shfl_xor(py, 1);
        py += __shfl_xor(py, 2);
        py += __shfl_xor(py, 4);
        py += __shfl_xor(py, 8);
        if (s == 0) yp[(size_t)l*256] = py;
    }
}

// ---------------- mamba epilogue: (y + u*D) * silu(z) @ ow  -> sm += ----------------
__global__ void __launch_bounds__(256)
k_mout(const float* __restrict__ y, const float* __restrict__ uc, const float* __restrict__ z,
       const float* __restrict__ Dp, const float* __restrict__ ow, float* __restrict__ sm)
{
    int bl = blockIdx.x; int tid = threadIdx.x;
    __shared__ float gld[256];
    float yv = y[(size_t)bl*256 + tid] + uc[(size_t)bl*256 + tid]*Dp[tid];
    gld[tid] = yv * dev_silu(z[(size_t)bl*256 + tid]);
    __syncthreads();
    if (tid < 128){
        float a = 0.f;
        for (int c = 0; c < 256; ++c) a = fmaf(gld[c], ow[c*128 + tid], a);
        sm[(size_t)bl*128 + tid] += a;
    }
}

// ---------------- vss epilogue: gather 4 dirs (+us*D), LN(256), *silu(z), @ ow -> sv += ----
__global__ void __launch_bounds__(256)
k_vcomb(const float* __restrict__ y, const float* __restrict__ us, const float* __restrict__ z,
        const float* __restrict__ Dp, const float* __restrict__ onw, const float* __restrict__ onb,
        const float* __restrict__ ow, float* __restrict__ sv)
{
    int bl = blockIdx.x; int b = bl >> 10, l = bl & 1023; int d = threadIdx.x;
    int h = l >> 5, w = l & 31;
    int l1 = (w<<5) + h;
    int l2 = 1023 - l;
    int l3 = 1023 - l1;
    size_t base = (size_t)b*4*1024*256;
    size_t i0 = base + ((size_t)0*1024 + l )*256 + d;
    size_t i1 = base + ((size_t)1*1024 + l1)*256 + d;
    size_t i2 = base + ((size_t)2*1024 + l2)*256 + d;
    size_t i3 = base + ((size_t)3*1024 + l3)*256 + d;
    float t = (y[i0] + us[i0]*Dp[0*256 + d])
            + (y[i1] + us[i1]*Dp[1*256 + d])
            + (y[i2] + us[i2]*Dp[2*256 + d])
            + (y[i3] + us[i3]*Dp[3*256 + d]);
    __shared__ float gld[256];
    __shared__ float sA[4], sB[4];
    float a = t, q = t*t;
    for (int o = 32; o; o >>= 1){ a += __shfl_down(a,o); q += __shfl_down(q,o); }
    if ((d & 63) == 0){ sA[d>>6] = a; sB[d>>6] = q; }
    __syncthreads();
    float mean = (sA[0]+sA[1]+sA[2]+sA[3]) * (1.0f/256.0f);
    float var  = (sB[0]+sB[1]+sB[2]+sB[3]) * (1.0f/256.0f) - mean*mean;
    float rs = rsqrtf(var + 1e-5f);
    float ym = (t - mean)*rs*onw[d] + onb[d];
    gld[d] = ym * dev_silu(z[(size_t)bl*256 + d]);
    __syncthreads();
    if (d < 128){
        float acc = 0.f;
        for (int c = 0; c < 256; ++c) acc = fmaf(gld[c], ow[c*128 + d], acc);
        sv[(size_t)bl*128 + d] += acc;
    }
}

// ---------------- repack (B,L,128)+(B,L,128) -> zero-padded NCHW (B,256,34,34) ----------------
__global__ void __launch_bounds__(256)
k_repack(const float* __restrict__ sm, const float* __restrict__ sv, float* __restrict__ xcp)
{
    int bc = blockIdx.x;            // b*256 + c
    int b = bc >> 8, c = bc & 255;
    const float* src = (c < 128) ? (sm + (size_t)b*1024*128 + c)
                                 : (sv + (size_t)b*1024*128 + (c - 128));
    float* dst = xcp + (size_t)bc*34*34;
    for (int i = threadIdx.x; i < 34*34; i += 256){
        int hp = i / 34, wp = i % 34;
        float v = 0.f;
        if (hp >= 1 && hp <= 32 && wp >= 1 && wp <= 32)
            v = src[(size_t)(((hp-1)<<5) + (wp-1))*128];
        dst[i] = v;
    }
}

// ---------------- fuse 3x3 conv (256->256) + BN + ReLU ----------------
__global__ void __launch_bounds__(256)
k_fuse(const float* __restrict__ xcp, const float* __restrict__ fw, const float* __restrict__ fb,
       const float* __restrict__ bg, const float* __restrict__ bb, const float* __restrict__ bm,
       const float* __restrict__ bv, float* __restrict__ out)
{
    int gid = blockIdx.x;           // (b*256 + o)*4 + hg
    int hg = gid & 3; int bo = gid >> 2; int b = bo >> 8, o = bo & 255;
    int tid = threadIdx.x;
    int hl = tid >> 5, wx = tid & 31;
    int h0 = hg * 8;
    __shared__ float wt[2304];       // 256 c x 9
    __shared__ float xt[4][340];     // 4 c x 10 rows x 34
    for (int i = tid; i < 2304; i += 256) wt[i] = fw[(size_t)o*2304 + i];
    float acc = 0.f;
    for (int c0 = 0; c0 < 256; c0 += 4){
        __syncthreads();
        for (int i = tid; i < 4*340; i += 256){
            int cc = i / 340, j = i % 340;
            xt[cc][j] = xcp[((size_t)(b*256 + c0 + cc)*34 + h0)*34 + j];
        }
        __syncthreads();
        #pragma unroll
        for (int cc = 0; cc < 4; ++cc){
            const float* wp_ = &wt[(c0 + cc)*9];
            const float* xp  = &xt[cc][hl*34 + wx];
            acc += xp[0]*wp_[0] + xp[1]*wp_[1] + xp[2]*wp_[2]
                 + xp[34]*wp_[3] + xp[35]*wp_[4] + xp[36]*wp_[5]
                 + xp[68]*wp_[6] + xp[69]*wp_[7] + xp[70]*wp_[8];
        }
    }
    acc += fb[o];
    float yv = (acc - bm[o]) * rsqrtf(bv[o] + 1e-5f) * bg[o] + bb[o];
    out[((size_t)(b*256 + o)*32 + (h0 + hl))*32 + wx] = fmaxf(yv, 0.f);
}

extern "C" void kernel_launch(void* const* d_in, const int* in_sizes, int n_in,
                              void* d_out, int out_size, void* d_ws, size_t ws_size,
                              hipStream_t stream)
{
    const float* x         = (const float*)d_in[0];
    const float* proj1_w   = (const float*)d_in[1];
    const float* proj1_b   = (const float*)d_in[2];
    const float* proj2_w   = (const float*)d_in[3];
    const float* proj2_b   = (const float*)d_in[4];
    const float* m_ln_w    = (const float*)d_in[5];
    const float* m_ln_b    = (const float*)d_in[6];
    const float* m_in_w    = (const float*)d_in[7];
    const float* m_conv_w  = (const float*)d_in[8];
    const float* m_conv_b  = (const float*)d_in[9];
    const float* m_xproj_w = (const float*)d_in[10];
    const float* m_dt_w    = (const float*)d_in[11];
    const float* m_dt_b    = (const float*)d_in[12];
    const float* m_Alog    = (const float*)d_in[13];
    const float* m_D       = (const float*)d_in[14];
    const float* m_out_w   = (const float*)d_in[15];
    const float* v_ln_w    = (const float*)d_in[16];
    const float* v_ln_b    = (const float*)d_in[17];
    const float* v_in_w    = (const float*)d_in[18];
    const float* v_conv_w  = (const float*)d_in[19];
    const float* v_conv_b  = (const float*)d_in[20];
    const float* v_xproj_w = (const float*)d_in[21];
    const float* v_dt_w    = (const float*)d_in[22];
    const float* v_dt_b    = (const float*)d_in[23];
    const float* v_Alog    = (const float*)d_in[24];
    const float* v_D       = (const float*)d_in[25];
    const float* v_onorm_w = (const float*)d_in[26];
    const float* v_onorm_b = (const float*)d_in[27];
    const float* v_out_w   = (const float*)d_in[28];
    const float* fuse_w    = (const float*)d_in[29];
    const float* fuse_b    = (const float*)d_in[30];
    const float* bn_g      = (const float*)d_in[31];
    const float* bn_b      = (const float*)d_in[32];
    const float* bn_m      = (const float*)d_in[33];
    const float* bn_v      = (const float*)d_in[34];
    float* out = (float*)d_out;

    float* ws = (float*)d_ws;
    float* sm    = ws;  ws += 2*1024*128;      // (B,L,128) mamba state
    float* sv    = ws;  ws += 2*1024*128;      // (B,L,128) vss state
    float* uraw  = ws;  ws += 2*1024*256;      // pre-conv u
    float* zb    = ws;  ws += 2*1024*256;      // z
    float* uc    = ws;  ws += 2*1024*256;      // mamba post-conv u
    float* usb   = ws;  ws += 2*4*1024*256;    // vss 4-direction sequences
    float* dtb_  = ws;  ws += 2*4*1024*256;    // dt
    float* Bmb   = ws;  ws += 2*4*1024*16;
    float* Cmb   = ws;  ws += 2*4*1024*16;
    float* yb    = ws;  ws += 2*4*1024*256;    // scan output
    float* xcp   = ws;  ws += 2*256*34*34;     // padded concat for fuse conv

    k_proj<<<2*1024, 256, 0, stream>>>(x, proj1_w, proj1_b, proj2_w, proj2_b, sm, sv);

    for (int i = 0; i < 2; ++i){
        k_lnmm <<<2*1024, 256, 0, stream>>>(sm, m_ln_w + i*128, m_ln_b + i*128,
                                            m_in_w + (size_t)i*128*512, uraw, zb);
        k_mconv<<<2*1024, 256, 0, stream>>>(uraw, m_conv_w + (size_t)i*256*4, m_conv_b + i*256, uc);
        k_xproj<<<2*1024, 256, 0, stream>>>(uc, m_xproj_w + (size_t)i*256*40,
                                            m_dt_w + (size_t)i*8*256, m_dt_b + i*256,
                                            dtb_, Bmb, Cmb, 1);
        k_scan <<<2*16,   256, 0, stream>>>(dtb_, uc, Bmb, Cmb, m_Alog + (size_t)i*256*16, yb, 1);
        k_mout <<<2*1024, 256, 0, stream>>>(yb, uc, zb, m_D + i*256,
                                            m_out_w + (size_t)i*256*128, sm);
    }

    for (int i = 0; i < 2; ++i){
        k_lnmm <<<2*1024,   256, 0, stream>>>(sv, v_ln_w + i*128, v_ln_b + i*128,
                                              v_in_w + (size_t)i*128*512, uraw, zb);
        k_vconv<<<2*1024,   256, 0, stream>>>(uraw, v_conv_w + (size_t)i*256*9, v_conv_b + i*256, usb);
        k_xproj<<<2*4*1024, 256, 0, stream>>>(usb, v_xproj_w + (size_t)i*4*256*40,
                                              v_dt_w + (size_t)i*4*8*256, v_dt_b + (size_t)i*4*256,
                                              dtb_, Bmb, Cmb, 4);
        k_scan <<<2*4*16,   256, 0, stream>>>(dtb_, usb, Bmb, Cmb,
                                              v_Alog + (size_t)i*4*256*16, yb, 4);
        k_vcomb<<<2*1024,   256, 0, stream>>>(yb, usb, zb, v_D + (size_t)i*4*256,
                                              v_onorm_w + i*256, v_onorm_b + i*256,
                                              v_out_w + (size_t)i*256*128, sv);
    }

    k_repack<<<2*256,   256, 0, stream>>>(sm, sv, xcp);
    k_fuse  <<<2*256*4, 256, 0, stream>>>(xcp, fuse_w, fuse_b, bn_g, bn_b, bn_m, bn_v, out);
}

// Round 2
// 1171.803 us; speedup vs baseline: 1.8411x; 1.8411x over previous
//
#include <hip/hip_runtime.h>
#include <math.h>

// Problem constants
// B=2, DIM=256, H=W=32, L=1024, HALF=128, DI=256, DS=16, DTR=8, DEPTH=2, K1=4

__device__ __forceinline__ float dev_silu(float x){ return x * (1.0f/(1.0f + __expf(-x))); }
__device__ __forceinline__ float dev_softplus(float x){ return fmaxf(x,0.0f) + log1pf(__expf(-fabsf(x))); }

// ---------------- proj: p1/p2 = proj_w @ x + b ; store as (B, L, 128) ----------------
__global__ void __launch_bounds__(256)
k_proj(const float* __restrict__ x, const float* __restrict__ w1, const float* __restrict__ b1,
       const float* __restrict__ w2, const float* __restrict__ b2,
       float* __restrict__ sm, float* __restrict__ sv)
{
    int bl = blockIdx.x;            // b*L + l
    int b = bl >> 10, l = bl & 1023;
    int tid = threadIdx.x;
    __shared__ float xs[256];
    xs[tid] = x[(size_t)(b*256 + tid)*1024 + l];
    __syncthreads();
    int o = tid & 127;
    const float* wr = (tid < 128) ? (w1 + o*256) : (w2 + o*256);
    float acc = (tid < 128) ? b1[o] : b2[o];
    #pragma unroll 8
    for (int c = 0; c < 256; ++c) acc = fmaf(wr[c], xs[c], acc);
    if (tid < 128) sm[(size_t)bl*128 + o] = acc;
    else           sv[(size_t)bl*128 + o] = acc;
}

// ---------------- LN over 128 + matmul (128->512) -> u (B,L,256), z (B,L,256) --------
__global__ void __launch_bounds__(256)
k_lnmm(const float* __restrict__ s, const float* __restrict__ lnw, const float* __restrict__ lnb,
       const float* __restrict__ inw, float* __restrict__ u, float* __restrict__ z)
{
    int bl = blockIdx.x; int tid = threadIdx.x;
    __shared__ float row[128];
    __shared__ float hn[128];
    __shared__ float sA[4], sB[4];
    float v = 0.f;
    if (tid < 128){ v = s[(size_t)bl*128 + tid]; row[tid] = v; }
    float a = v, q = v*v;
    for (int o = 32; o; o >>= 1){ a += __shfl_down(a,o); q += __shfl_down(q,o); }
    if ((tid & 63) == 0){ sA[tid>>6] = a; sB[tid>>6] = q; }
    __syncthreads();
    float mean = (sA[0]+sA[1]+sA[2]+sA[3]) * (1.0f/128.0f);
    float var  = (sB[0]+sB[1]+sB[2]+sB[3]) * (1.0f/128.0f) - mean*mean;
    float rs = rsqrtf(var + 1e-5f);
    if (tid < 128) hn[tid] = (row[tid]-mean)*rs*lnw[tid] + lnb[tid];
    __syncthreads();
    float a0 = 0.f, a1 = 0.f;
    for (int c = 0; c < 128; ++c){
        float hc = hn[c];
        a0 = fmaf(hc, inw[c*512 + tid],       a0);
        a1 = fmaf(hc, inw[c*512 + tid + 256], a1);
    }
    u[(size_t)bl*256 + tid] = a0;
    z[(size_t)bl*256 + tid] = a1;
}

// ---------------- mamba causal conv (K1=4) + silu ----------------
__global__ void __launch_bounds__(256)
k_mconv(const float* __restrict__ ur, const float* __restrict__ cw, const float* __restrict__ cb,
        float* __restrict__ uc)
{
    int bl = blockIdx.x; int b = bl >> 10, l = bl & 1023; int d = threadIdx.x;
    float acc = cb[d];
    #pragma unroll
    for (int k = 0; k < 4; ++k){
        int lp = l - 3 + k;
        if (lp >= 0) acc = fmaf(ur[((size_t)(b<<10) + lp)*256 + d], cw[d*4 + k], acc);
    }
    uc[(size_t)bl*256 + d] = dev_silu(acc);
}

// ---------------- vss depthwise 3x3 conv + silu + 4-direction scatter ----------------
__global__ void __launch_bounds__(256)
k_vconv(const float* __restrict__ ur, const float* __restrict__ cw, const float* __restrict__ cb,
        float* __restrict__ us)
{
    int bl = blockIdx.x; int b = bl >> 10, l = bl & 1023; int d = threadIdx.x;
    int h = l >> 5, w = l & 31;
    float acc = cb[d];
    #pragma unroll
    for (int kh = 0; kh < 3; ++kh){
        int hh = h + kh - 1; if (hh < 0 || hh > 31) continue;
        #pragma unroll
        for (int kw = 0; kw < 3; ++kw){
            int ww = w + kw - 1; if (ww < 0 || ww > 31) continue;
            acc = fmaf(ur[((size_t)(b<<10) + (hh<<5) + ww)*256 + d], cw[d*9 + kh*3 + kw], acc);
        }
    }
    float v = dev_silu(acc);
    int l1 = (w<<5) + h;   // column-major scan position
    size_t base = (size_t)b*4*1024*256;
    us[base + ((size_t)0*1024 + l        )*256 + d] = v;
    us[base + ((size_t)1*1024 + l1       )*256 + d] = v;
    us[base + ((size_t)2*1024 + (1023-l ))*256 + d] = v;
    us[base + ((size_t)3*1024 + (1023-l1))*256 + d] = v;
}

// ---------------- xproj (u @ xw -> dtr,B,C) + dt = softplus(dtr@dtw + dtb) ----------------
__global__ void __launch_bounds__(256)
k_xproj(const float* __restrict__ u, const float* __restrict__ xw, const float* __restrict__ dtw,
        const float* __restrict__ dtb, float* __restrict__ dt, float* __restrict__ Bm,
        float* __restrict__ Cm, int K)
{
    int idx = blockIdx.x;          // bk*L + l   (bk = b*K + k)
    int bk = idx >> 10;
    int k = bk % K;
    int tid = threadIdx.x;
    __shared__ float ursh[256];
    __shared__ float part[4][40];
    __shared__ float dbc[40];
    ursh[tid] = u[(size_t)idx*256 + tid];
    __syncthreads();
    if (tid < 160){
        int r = tid % 40, p = tid / 40;    // p in [0,4)
        const float* xwc = xw + (size_t)k*256*40 + r;
        float a = 0.f;
        int c0 = p*64;
        for (int c = c0; c < c0 + 64; ++c) a = fmaf(ursh[c], xwc[c*40], a);
        part[p][r] = a;
    }
    __syncthreads();
    if (tid < 40) dbc[tid] = part[0][tid] + part[1][tid] + part[2][tid] + part[3][tid];
    __syncthreads();
    const float* dtwk = dtw + (size_t)k*8*256;
    float a = dtb[k*256 + tid];
    #pragma unroll
    for (int r = 0; r < 8; ++r) a = fmaf(dbc[r], dtwk[r*256 + tid], a);
    dt[(size_t)idx*256 + tid] = dev_softplus(a);
    if (tid < 16)      Bm[(size_t)idx*16 + tid]        = dbc[8 + tid];
    else if (tid < 32) Cm[(size_t)idx*16 + (tid - 16)] = dbc[8 + tid];  // dbc[24..39]
}

// ------- transpose dt[bk,l,d]->dt_t[bk,d,l] and (dt*u)->dut_t[bk,d,l], 32x32 LDS tiles -------
__global__ void __launch_bounds__(256)
k_trans(const float* __restrict__ dt, const float* __restrict__ u,
        float* __restrict__ dt_t, float* __restrict__ dut_t)
{
    int gid = blockIdx.x;           // bk*256 + lt*8 + dt8
    int dt8 = gid & 7;
    int lt  = (gid >> 3) & 31;
    int bk  = gid >> 8;
    __shared__ float t1[32][33], t2[32][33];
    int col = threadIdx.x & 31, row8 = threadIdx.x >> 5;
    size_t base = ((size_t)bk*1024 + lt*32)*256 + dt8*32;
    #pragma unroll
    for (int i = 0; i < 4; ++i){
        int r = i*8 + row8;
        float a = dt[base + (size_t)r*256 + col];
        float b = u [base + (size_t)r*256 + col];
        t1[r][col] = a;
        t2[r][col] = a*b;
    }
    __syncthreads();
    size_t obase = ((size_t)bk*256 + dt8*32)*1024 + lt*32;
    #pragma unroll
    for (int i = 0; i < 4; ++i){
        int r = i*8 + row8;
        dt_t[obase + (size_t)r*1024 + col]  = t1[col][r];
        dut_t[obase + (size_t)r*1024 + col] = t2[col][r];
    }
}

// ------- chunked parallel selective scan: one block per (bk,d); 16 chunks x 16 states -------
__global__ void __launch_bounds__(256)
k_scan2(const float* __restrict__ dt_t, const float* __restrict__ dut_t,
        const float* __restrict__ Bm, const float* __restrict__ Cm,
        const float* __restrict__ Alog, float* __restrict__ y, int K)
{
    int blk = blockIdx.x;           // bk*256 + d
    int d = blk & 255; int bk = blk >> 8; int k = bk % K;
    int tid = threadIdx.x;
    int c = tid >> 4, s = tid & 15; // chunk, state
    __shared__ float sdt[1024];
    __shared__ float sdu[1024];
    __shared__ float Pc[16][17], Qc[16][17], hin[16][17];
    const float4* dt4 = (const float4*)(dt_t + ((size_t)bk*256 + d)*1024);
    const float4* du4 = (const float4*)(dut_t + ((size_t)bk*256 + d)*1024);
    ((float4*)sdt)[tid] = dt4[tid];
    ((float4*)sdu)[tid] = du4[tid];
    float A = -__expf(Alog[((size_t)k*256 + d)*16 + s]);
    const float* Bp = Bm + (size_t)bk*1024*16 + s;
    const float* Cp = Cm + (size_t)bk*1024*16 + s;
    __syncthreads();
    int l0 = c*64;
    // pass A: per-chunk (P = prod a, Q = chunk-local h); keep av in registers
    float av[64];
    float P = 1.f, Q = 0.f;
    #pragma unroll
    for (int j = 0; j < 64; ++j){
        av[j] = __expf(sdt[l0 + j]*A);
        float b = sdu[l0 + j]*Bp[(l0 + j)*16];
        P *= av[j];
        Q = fmaf(av[j], Q, b);
    }
    Pc[c][s] = P; Qc[c][s] = Q;
    __syncthreads();
    // exclusive prefix across 16 chunks (serial per state, 16 lanes)
    if (tid < 16){
        float h = 0.f;
        #pragma unroll
        for (int cc = 0; cc < 16; ++cc){
            hin[cc][tid] = h;
            h = fmaf(Pc[cc][tid], h, Qc[cc][tid]);
        }
    }
    __syncthreads();
    // pass B: replay with correct h_in; y[l,d] = sum_s h*C
    float h = hin[c][s];
    float* yp = y + (size_t)bk*1024*256 + d;
    #pragma unroll
    for (int j = 0; j < 64; ++j){
        int l = l0 + j;
        h = fmaf(av[j], h, sdu[l]*Bp[l*16]);
        float py = h * Cp[l*16];
        py += __shfl_xor(py, 1);
        py += __shfl_xor(py, 2);
        py += __shfl_xor(py, 4);
        py += __shfl_xor(py, 8);
        if (s == 0) yp[(size_t)l*256] = py;
    }
}

// ---------------- mamba epilogue: (y + u*D) * silu(z) @ ow  -> sm += ----------------
__global__ void __launch_bounds__(256)
k_mout(const float* __restrict__ y, const float* __restrict__ uc, const float* __restrict__ z,
       const float* __restrict__ Dp, const float* __restrict__ ow, float* __restrict__ sm)
{
    int bl = blockIdx.x; int tid = threadIdx.x;
    __shared__ float gld[256];
    float yv = y[(size_t)bl*256 + tid] + uc[(size_t)bl*256 + tid]*Dp[tid];
    gld[tid] = yv * dev_silu(z[(size_t)bl*256 + tid]);
    __syncthreads();
    if (tid < 128){
        float a = 0.f;
        for (int c = 0; c < 256; ++c) a = fmaf(gld[c], ow[c*128 + tid], a);
        sm[(size_t)bl*128 + tid] += a;
    }
}

// ---------------- vss epilogue: gather 4 dirs (+us*D), LN(256), *silu(z), @ ow -> sv += ----
__global__ void __launch_bounds__(256)
k_vcomb(const float* __restrict__ y, const float* __restrict__ us, const float* __restrict__ z,
        const float* __restrict__ Dp, const float* __restrict__ onw, const float* __restrict__ onb,
        const float* __restrict__ ow, float* __restrict__ sv)
{
    int bl = blockIdx.x; int b = bl >> 10, l = bl & 1023; int d = threadIdx.x;
    int h = l >> 5, w = l & 31;
    int l1 = (w<<5) + h;
    int l2 = 1023 - l;
    int l3 = 1023 - l1;
    size_t base = (size_t)b*4*1024*256;
    size_t i0 = base + ((size_t)0*1024 + l )*256 + d;
    size_t i1 = base + ((size_t)1*1024 + l1)*256 + d;
    size_t i2 = base + ((size_t)2*1024 + l2)*256 + d;
    size_t i3 = base + ((size_t)3*1024 + l3)*256 + d;
    float t = (y[i0] + us[i0]*Dp[0*256 + d])
            + (y[i1] + us[i1]*Dp[1*256 + d])
            + (y[i2] + us[i2]*Dp[2*256 + d])
            + (y[i3] + us[i3]*Dp[3*256 + d]);
    __shared__ float gld[256];
    __shared__ float sA[4], sB[4];
    float a = t, q = t*t;
    for (int o = 32; o; o >>= 1){ a += __shfl_down(a,o); q += __shfl_down(q,o); }
    if ((d & 63) == 0){ sA[d>>6] = a; sB[d>>6] = q; }
    __syncthreads();
    float mean = (sA[0]+sA[1]+sA[2]+sA[3]) * (1.0f/256.0f);
    float var  = (sB[0]+sB[1]+sB[2]+sB[3]) * (1.0f/256.0f) - mean*mean;
    float rs = rsqrtf(var + 1e-5f);
    float ym = (t - mean)*rs*onw[d] + onb[d];
    gld[d] = ym * dev_silu(z[(size_t)bl*256 + d]);
    __syncthreads();
    if (d < 128){
        float acc = 0.f;
        for (int c = 0; c < 256; ++c) acc = fmaf(gld[c], ow[c*128 + d], acc);
        sv[(size_t)bl*128 + d] += acc;
    }
}

// ---------------- repack (B,L,128)+(B,L,128) -> zero-padded NCHW (B,256,34,34) ----------------
__global__ void __launch_bounds__(256)
k_repack(const float* __restrict__ sm, const float* __restrict__ sv, float* __restrict__ xcp)
{
    int bc = blockIdx.x;            // b*256 + c
    int b = bc >> 8, c = bc & 255;
    const float* src = (c < 128) ? (sm + (size_t)b*1024*128 + c)
                                 : (sv + (size_t)b*1024*128 + (c - 128));
    float* dst = xcp + (size_t)bc*34*34;
    for (int i = threadIdx.x; i < 34*34; i += 256){
        int hp = i / 34, wp = i % 34;
        float v = 0.f;
        if (hp >= 1 && hp <= 32 && wp >= 1 && wp <= 32)
            v = src[(size_t)(((hp-1)<<5) + (wp-1))*128];
        dst[i] = v;
    }
}

// ---------------- fuse 3x3 conv (256->256) + BN + ReLU ----------------
__global__ void __launch_bounds__(256)
k_fuse(const float* __restrict__ xcp, const float* __restrict__ fw, const float* __restrict__ fb,
       const float* __restrict__ bg, const float* __restrict__ bb, const float* __restrict__ bm,
       const float* __restrict__ bv, float* __restrict__ out)
{
    int gid = blockIdx.x;           // (b*256 + o)*4 + hg
    int hg = gid & 3; int bo = gid >> 2; int b = bo >> 8, o = bo & 255;
    int tid = threadIdx.x;
    int hl = tid >> 5, wx = tid & 31;
    int h0 = hg * 8;
    __shared__ float wt[2304];       // 256 c x 9
    __shared__ float xt[4][340];     // 4 c x 10 rows x 34
    for (int i = tid; i < 2304; i += 256) wt[i] = fw[(size_t)o*2304 + i];
    float acc = 0.f;
    for (int c0 = 0; c0 < 256; c0 += 4){
        __syncthreads();
        for (int i = tid; i < 4*340; i += 256){
            int cc = i / 340, j = i % 340;
            xt[cc][j] = xcp[((size_t)(b*256 + c0 + cc)*34 + h0)*34 + j];
        }
        __syncthreads();
        #pragma unroll
        for (int cc = 0; cc < 4; ++cc){
            const float* wp_ = &wt[(c0 + cc)*9];
            const float* xp  = &xt[cc][hl*34 + wx];
            acc += xp[0]*wp_[0] + xp[1]*wp_[1] + xp[2]*wp_[2]
                 + xp[34]*wp_[3] + xp[35]*wp_[4] + xp[36]*wp_[5]
                 + xp[68]*wp_[6] + xp[69]*wp_[7] + xp[70]*wp_[8];
        }
    }
    acc += fb[o];
    float yv = (acc - bm[o]) * rsqrtf(bv[o] + 1e-5f) * bg[o] + bb[o];
    out[((size_t)(b*256 + o)*32 + (h0 + hl))*32 + wx] = fmaxf(yv, 0.f);
}

extern "C" void kernel_launch(void* const* d_in, const int* in_sizes, int n_in,
                              void* d_out, int out_size, void* d_ws, size_t ws_size,
                              hipStream_t stream)
{
    const float* x         = (const float*)d_in[0];
    const float* proj1_w   = (const float*)d_in[1];
    const float* proj1_b   = (const float*)d_in[2];
    const float* proj2_w   = (const float*)d_in[3];
    const float* proj2_b   = (const float*)d_in[4];
    const float* m_ln_w    = (const float*)d_in[5];
    const float* m_ln_b    = (const float*)d_in[6];
    const float* m_in_w    = (const float*)d_in[7];
    const float* m_conv_w  = (const float*)d_in[8];
    const float* m_conv_b  = (const float*)d_in[9];
    const float* m_xproj_w = (const float*)d_in[10];
    const float* m_dt_w    = (const float*)d_in[11];
    const float* m_dt_b    = (const float*)d_in[12];
    const float* m_Alog    = (const float*)d_in[13];
    const float* m_D       = (const float*)d_in[14];
    const float* m_out_w   = (const float*)d_in[15];
    const float* v_ln_w    = (const float*)d_in[16];
    const float* v_ln_b    = (const float*)d_in[17];
    const float* v_in_w    = (const float*)d_in[18];
    const float* v_conv_w  = (const float*)d_in[19];
    const float* v_conv_b  = (const float*)d_in[20];
    const float* v_xproj_w = (const float*)d_in[21];
    const float* v_dt_w    = (const float*)d_in[22];
    const float* v_dt_b    = (const float*)d_in[23];
    const float* v_Alog    = (const float*)d_in[24];
    const float* v_D       = (const float*)d_in[25];
    const float* v_onorm_w = (const float*)d_in[26];
    const float* v_onorm_b = (const float*)d_in[27];
    const float* v_out_w   = (const float*)d_in[28];
    const float* fuse_w    = (const float*)d_in[29];
    const float* fuse_b    = (const float*)d_in[30];
    const float* bn_g      = (const float*)d_in[31];
    const float* bn_b      = (const float*)d_in[32];
    const float* bn_m      = (const float*)d_in[33];
    const float* bn_v      = (const float*)d_in[34];
    float* out = (float*)d_out;

    float* ws = (float*)d_ws;
    float* sm    = ws;  ws += 2*1024*128;      // (B,L,128) mamba state
    float* sv    = ws;  ws += 2*1024*128;      // (B,L,128) vss state
    float* uraw  = ws;  ws += 2*1024*256;      // pre-conv u
    float* zb    = ws;  ws += 2*1024*256;      // z
    float* uc    = ws;  ws += 2*1024*256;      // mamba post-conv u
    float* usb   = ws;  ws += 2*4*1024*256;    // vss 4-direction sequences
    float* dtb_  = ws;  ws += 2*4*1024*256;    // dt (B,K,L,D); aliased as yb after k_trans
    float* dt_t  = ws;  ws += 2*4*1024*256;    // dt transposed (B,K,D,L)
    float* dut_t = ws;  ws += 2*4*1024*256;    // dt*u transposed (B,K,D,L)
    float* Bmb   = ws;  ws += 2*4*1024*16;
    float* Cmb   = ws;  ws += 2*4*1024*16;
    float* xcp   = ws;  ws += 2*256*34*34;     // padded concat for fuse conv
    float* yb    = dtb_;                        // scan output aliases dt (disjoint lifetime)

    k_proj<<<2*1024, 256, 0, stream>>>(x, proj1_w, proj1_b, proj2_w, proj2_b, sm, sv);

    for (int i = 0; i < 2; ++i){
        k_lnmm <<<2*1024, 256, 0, stream>>>(sm, m_ln_w + i*128, m_ln_b + i*128,
                                            m_in_w + (size_t)i*128*512, uraw, zb);
        k_mconv<<<2*1024, 256, 0, stream>>>(uraw, m_conv_w + (size_t)i*256*4, m_conv_b + i*256, uc);
        k_xproj<<<2*1024, 256, 0, stream>>>(uc, m_xproj_w + (size_t)i*256*40,
                                            m_dt_w + (size_t)i*8*256, m_dt_b + i*256,
                                            dtb_, Bmb, Cmb, 1);
        k_trans<<<2*256,  256, 0, stream>>>(dtb_, uc, dt_t, dut_t);
        k_scan2<<<2*256,  256, 0, stream>>>(dt_t, dut_t, Bmb, Cmb,
                                            m_Alog + (size_t)i*256*16, yb, 1);
        k_mout <<<2*1024, 256, 0, stream>>>(yb, uc, zb, m_D + i*256,
                                            m_out_w + (size_t)i*256*128, sm);
    }

    for (int i = 0; i < 2; ++i){
        k_lnmm <<<2*1024,   256, 0, stream>>>(sv, v_ln_w + i*128, v_ln_b + i*128,
                                              v_in_w + (size_t)i*128*512, uraw, zb);
        k_vconv<<<2*1024,   256, 0, stream>>>(uraw, v_conv_w + (size_t)i*256*9, v_conv_b + i*256, usb);
        k_xproj<<<2*4*1024, 256, 0, stream>>>(usb, v_xproj_w + (size_t)i*4*256*40,
                                              v_dt_w + (size_t)i*4*8*256, v_dt_b + (size_t)i*4*256,
                                              dtb_, Bmb, Cmb, 4);
        k_trans<<<2*4*256,  256, 0, stream>>>(dtb_, usb, dt_t, dut_t);
        k_scan2<<<2*4*256,  256, 0, stream>>>(dt_t, dut_t, Bmb, Cmb,
                                              v_Alog + (size_t)i*4*256*16, yb, 4);
        k_vcomb<<<2*1024,   256, 0, stream>>>(yb, usb, zb, v_D + (size_t)i*4*256,
                                              v_onorm_w + i*256, v_onorm_b + i*256,
                                              v_out_w + (size_t)i*256*128, sv);
    }

    k_repack<<<2*256,   256, 0, stream>>>(sm, sv, xcp);
    k_fuse  <<<2*256*4, 256, 0, stream>>>(xcp, fuse_w, fuse_b, bn_g, bn_b, bn_m, bn_v, out);
}

// Round 3
// 573.522 us; speedup vs baseline: 3.7617x; 2.0432x over previous
//
#include <hip/hip_runtime.h>
#include <math.h>

// Problem constants
// B=2, DIM=256, H=W=32, L=1024, HALF=128, DI=256, DS=16, DTR=8, DEPTH=2, K1=4
#define CH  16      // scan chunk length
#define NCH 64      // chunks per sequence (L / CH)

__device__ __forceinline__ float dev_silu(float x){ return x * (1.0f/(1.0f + __expf(-x))); }
__device__ __forceinline__ float dev_softplus(float x){ return fmaxf(x,0.0f) + log1pf(__expf(-fabsf(x))); }

// ---------------- proj: p1/p2 = proj_w @ x + b ; store as (B, L, 128) ----------------
__global__ void __launch_bounds__(256)
k_proj(const float* __restrict__ x, const float* __restrict__ w1, const float* __restrict__ b1,
       const float* __restrict__ w2, const float* __restrict__ b2,
       float* __restrict__ sm, float* __restrict__ sv)
{
    int bl = blockIdx.x;            // b*L + l
    int b = bl >> 10, l = bl & 1023;
    int tid = threadIdx.x;
    __shared__ float xs[256];
    xs[tid] = x[(size_t)(b*256 + tid)*1024 + l];
    __syncthreads();
    int o = tid & 127;
    const float* wr = (tid < 128) ? (w1 + o*256) : (w2 + o*256);
    float acc = (tid < 128) ? b1[o] : b2[o];
    #pragma unroll 8
    for (int c = 0; c < 256; ++c) acc = fmaf(wr[c], xs[c], acc);
    if (tid < 128) sm[(size_t)bl*128 + o] = acc;
    else           sv[(size_t)bl*128 + o] = acc;
}

// ---------------- LN over 128 + matmul (128->512) -> u (B,L,256), z (B,L,256) --------
__global__ void __launch_bounds__(256)
k_lnmm(const float* __restrict__ s, const float* __restrict__ lnw, const float* __restrict__ lnb,
       const float* __restrict__ inw, float* __restrict__ u, float* __restrict__ z)
{
    int bl = blockIdx.x; int tid = threadIdx.x;
    __shared__ float row[128];
    __shared__ float hn[128];
    __shared__ float sA[4], sB[4];
    float v = 0.f;
    if (tid < 128){ v = s[(size_t)bl*128 + tid]; row[tid] = v; }
    float a = v, q = v*v;
    for (int o = 32; o; o >>= 1){ a += __shfl_down(a,o); q += __shfl_down(q,o); }
    if ((tid & 63) == 0){ sA[tid>>6] = a; sB[tid>>6] = q; }
    __syncthreads();
    float mean = (sA[0]+sA[1]+sA[2]+sA[3]) * (1.0f/128.0f);
    float var  = (sB[0]+sB[1]+sB[2]+sB[3]) * (1.0f/128.0f) - mean*mean;
    float rs = rsqrtf(var + 1e-5f);
    if (tid < 128) hn[tid] = (row[tid]-mean)*rs*lnw[tid] + lnb[tid];
    __syncthreads();
    float a0 = 0.f, a1 = 0.f;
    for (int c = 0; c < 128; ++c){
        float hc = hn[c];
        a0 = fmaf(hc, inw[c*512 + tid],       a0);
        a1 = fmaf(hc, inw[c*512 + tid + 256], a1);
    }
    u[(size_t)bl*256 + tid] = a0;
    z[(size_t)bl*256 + tid] = a1;
}

// ---------------- mamba causal conv (K1=4) + silu ----------------
__global__ void __launch_bounds__(256)
k_mconv(const float* __restrict__ ur, const float* __restrict__ cw, const float* __restrict__ cb,
        float* __restrict__ uc)
{
    int bl = blockIdx.x; int b = bl >> 10, l = bl & 1023; int d = threadIdx.x;
    float acc = cb[d];
    #pragma unroll
    for (int k = 0; k < 4; ++k){
        int lp = l - 3 + k;
        if (lp >= 0) acc = fmaf(ur[((size_t)(b<<10) + lp)*256 + d], cw[d*4 + k], acc);
    }
    uc[(size_t)bl*256 + d] = dev_silu(acc);
}

// ---------------- vss depthwise 3x3 conv + silu + 4-direction scatter ----------------
__global__ void __launch_bounds__(256)
k_vconv(const float* __restrict__ ur, const float* __restrict__ cw, const float* __restrict__ cb,
        float* __restrict__ us)
{
    int bl = blockIdx.x; int b = bl >> 10, l = bl & 1023; int d = threadIdx.x;
    int h = l >> 5, w = l & 31;
    float acc = cb[d];
    #pragma unroll
    for (int kh = 0; kh < 3; ++kh){
        int hh = h + kh - 1; if (hh < 0 || hh > 31) continue;
        #pragma unroll
        for (int kw = 0; kw < 3; ++kw){
            int ww = w + kw - 1; if (ww < 0 || ww > 31) continue;
            acc = fmaf(ur[((size_t)(b<<10) + (hh<<5) + ww)*256 + d], cw[d*9 + kh*3 + kw], acc);
        }
    }
    float v = dev_silu(acc);
    int l1 = (w<<5) + h;   // column-major scan position
    size_t base = (size_t)b*4*1024*256;
    us[base + ((size_t)0*1024 + l        )*256 + d] = v;
    us[base + ((size_t)1*1024 + l1       )*256 + d] = v;
    us[base + ((size_t)2*1024 + (1023-l ))*256 + d] = v;
    us[base + ((size_t)3*1024 + (1023-l1))*256 + d] = v;
}

// ---------------- xproj (u @ xw -> dtr,B,C) + dt = softplus(dtr@dtw + dtb) ----------------
__global__ void __launch_bounds__(256)
k_xproj(const float* __restrict__ u, const float* __restrict__ xw, const float* __restrict__ dtw,
        const float* __restrict__ dtb, float* __restrict__ dt, float* __restrict__ Bm,
        float* __restrict__ Cm, int K)
{
    int idx = blockIdx.x;          // bk*L + l   (bk = b*K + k)
    int bk = idx >> 10;
    int k = bk % K;
    int tid = threadIdx.x;
    __shared__ float ursh[256];
    __shared__ float part[4][40];
    __shared__ float dbc[40];
    ursh[tid] = u[(size_t)idx*256 + tid];
    __syncthreads();
    if (tid < 160){
        int r = tid % 40, p = tid / 40;    // p in [0,4)
        const float* xwc = xw + (size_t)k*256*40 + r;
        float a = 0.f;
        int c0 = p*64;
        for (int c = c0; c < c0 + 64; ++c) a = fmaf(ursh[c], xwc[c*40], a);
        part[p][r] = a;
    }
    __syncthreads();
    if (tid < 40) dbc[tid] = part[0][tid] + part[1][tid] + part[2][tid] + part[3][tid];
    __syncthreads();
    const float* dtwk = dtw + (size_t)k*8*256;
    float a = dtb[k*256 + tid];
    #pragma unroll
    for (int r = 0; r < 8; ++r) a = fmaf(dbc[r], dtwk[r*256 + tid], a);
    dt[(size_t)idx*256 + tid] = dev_softplus(a);
    if (tid < 16)      Bm[(size_t)idx*16 + tid]        = dbc[8 + tid];
    else if (tid < 32) Cm[(size_t)idx*16 + (tid - 16)] = dbc[8 + tid];  // dbc[24..39]
}

// ------- scan pass A: per-chunk (P = exp(A*sum dt), Q = chunk-local h), thread per d -------
__global__ void __launch_bounds__(256)
k_scanA(const float* __restrict__ dt, const float* __restrict__ u, const float* __restrict__ Bm,
        const float* __restrict__ Alog, float* __restrict__ Pb, float* __restrict__ Qb, int K)
{
    int blk = blockIdx.x;            // bk*NCH + c
    int c = blk & (NCH-1); int bk = blk >> 6; int k = bk % K;
    int d = threadIdx.x;
    __shared__ float Bsh[CH][16];
    {
        int j = threadIdx.x >> 4, s = threadIdx.x & 15;
        Bsh[j][s] = Bm[((size_t)bk*1024 + c*CH + j)*16 + s];
    }
    float dtv[CH], duv[CH];
    size_t base = ((size_t)bk*1024 + c*CH)*256 + d;
    #pragma unroll
    for (int j = 0; j < CH; ++j){
        float a = dt[base + (size_t)j*256];
        float b = u [base + (size_t)j*256];
        dtv[j] = a; duv[j] = a*b;
    }
    float A[16];
    const float4* Ap = (const float4*)(Alog + ((size_t)k*256 + d)*16);
    #pragma unroll
    for (int q = 0; q < 4; ++q){
        float4 v = Ap[q];
        A[q*4+0] = -__expf(v.x); A[q*4+1] = -__expf(v.y);
        A[q*4+2] = -__expf(v.z); A[q*4+3] = -__expf(v.w);
    }
    __syncthreads();
    float Q[16];
    #pragma unroll
    for (int s = 0; s < 16; ++s) Q[s] = 0.f;
    float S = 0.f;
    #pragma unroll
    for (int j = 0; j < CH; ++j){
        S += dtv[j];
        #pragma unroll
        for (int s = 0; s < 16; ++s){
            float av = __expf(dtv[j]*A[s]);
            Q[s] = fmaf(av, Q[s], duv[j]*Bsh[j][s]);
        }
    }
    float4* Pp = (float4*)(Pb + ((size_t)blk*256 + d)*16);
    float4* Qp = (float4*)(Qb + ((size_t)blk*256 + d)*16);
    #pragma unroll
    for (int q = 0; q < 4; ++q){
        float4 pv, qv;
        pv.x = __expf(S*A[q*4+0]); pv.y = __expf(S*A[q*4+1]);
        pv.z = __expf(S*A[q*4+2]); pv.w = __expf(S*A[q*4+3]);
        qv.x = Q[q*4+0]; qv.y = Q[q*4+1]; qv.z = Q[q*4+2]; qv.w = Q[q*4+3];
        Pp[q] = pv; Qp[q] = qv;
    }
}

// ------- scan pass P: exclusive prefix over NCH chunks per (bk,d,s); H overwrites P -------
__global__ void __launch_bounds__(256)
k_scanP(float* __restrict__ Pb, const float* __restrict__ Qb)
{
    int bk = blockIdx.x >> 4;
    int dg = blockIdx.x & 15;       // group of 16 d
    int tid = threadIdx.x;          // dl*16 + s
    size_t idx0 = (size_t)bk*NCH*4096 + dg*256 + tid;
    float Pv[NCH], Qv[NCH];
    #pragma unroll
    for (int c = 0; c < NCH; ++c){
        Pv[c] = Pb[idx0 + (size_t)c*4096];
        Qv[c] = Qb[idx0 + (size_t)c*4096];
    }
    float h = 0.f;
    #pragma unroll
    for (int c = 0; c < NCH; ++c){
        Pb[idx0 + (size_t)c*4096] = h;      // h_in for chunk c
        h = fmaf(Pv[c], h, Qv[c]);
    }
}

// ------- scan pass B: replay chunk with h_in; y[l,d] = sum_s h*C; thread per d -------
__global__ void __launch_bounds__(256)
k_scanB(const float* __restrict__ dt, const float* __restrict__ u, const float* __restrict__ Bm,
        const float* __restrict__ Cm, const float* __restrict__ Alog,
        const float* __restrict__ Hb, float* __restrict__ y, int K)
{
    int blk = blockIdx.x;            // bk*NCH + c
    int c = blk & (NCH-1); int bk = blk >> 6; int k = bk % K;
    int d = threadIdx.x;
    __shared__ float Bsh[CH][16], Csh[CH][16];
    {
        int j = threadIdx.x >> 4, s = threadIdx.x & 15;
        size_t bi = ((size_t)bk*1024 + c*CH + j)*16 + s;
        Bsh[j][s] = Bm[bi];
        Csh[j][s] = Cm[bi];
    }
    float dtv[CH], duv[CH];
    size_t base = ((size_t)bk*1024 + c*CH)*256 + d;
    #pragma unroll
    for (int j = 0; j < CH; ++j){
        float a = dt[base + (size_t)j*256];
        float b = u [base + (size_t)j*256];
        dtv[j] = a; duv[j] = a*b;
    }
    float A[16];
    const float4* Ap = (const float4*)(Alog + ((size_t)k*256 + d)*16);
    #pragma unroll
    for (int q = 0; q < 4; ++q){
        float4 v = Ap[q];
        A[q*4+0] = -__expf(v.x); A[q*4+1] = -__expf(v.y);
        A[q*4+2] = -__expf(v.z); A[q*4+3] = -__expf(v.w);
    }
    float h[16];
    const float4* Hp = (const float4*)(Hb + ((size_t)blk*256 + d)*16);
    #pragma unroll
    for (int q = 0; q < 4; ++q){
        float4 v = Hp[q];
        h[q*4+0] = v.x; h[q*4+1] = v.y; h[q*4+2] = v.z; h[q*4+3] = v.w;
    }
    __syncthreads();
    float* yp = y + base;
    #pragma unroll
    for (int j = 0; j < CH; ++j){
        float py = 0.f;
        #pragma unroll
        for (int s = 0; s < 16; ++s){
            float av = __expf(dtv[j]*A[s]);
            h[s] = fmaf(av, h[s], duv[j]*Bsh[j][s]);
            py = fmaf(h[s], Csh[j][s], py);
        }
        yp[(size_t)j*256] = py;
    }
}

// ---------------- mamba epilogue: (y + u*D) * silu(z) @ ow  -> sm += ----------------
__global__ void __launch_bounds__(256)
k_mout(const float* __restrict__ y, const float* __restrict__ uc, const float* __restrict__ z,
       const float* __restrict__ Dp, const float* __restrict__ ow, float* __restrict__ sm)
{
    int bl = blockIdx.x; int tid = threadIdx.x;
    __shared__ float gld[256];
    float yv = y[(size_t)bl*256 + tid] + uc[(size_t)bl*256 + tid]*Dp[tid];
    gld[tid] = yv * dev_silu(z[(size_t)bl*256 + tid]);
    __syncthreads();
    if (tid < 128){
        float a = 0.f;
        for (int c = 0; c < 256; ++c) a = fmaf(gld[c], ow[c*128 + tid], a);
        sm[(size_t)bl*128 + tid] += a;
    }
}

// ---------------- vss epilogue: gather 4 dirs (+us*D), LN(256), *silu(z), @ ow -> sv += ----
__global__ void __launch_bounds__(256)
k_vcomb(const float* __restrict__ y, const float* __restrict__ us, const float* __restrict__ z,
        const float* __restrict__ Dp, const float* __restrict__ onw, const float* __restrict__ onb,
        const float* __restrict__ ow, float* __restrict__ sv)
{
    int bl = blockIdx.x; int b = bl >> 10, l = bl & 1023; int d = threadIdx.x;
    int h = l >> 5, w = l & 31;
    int l1 = (w<<5) + h;
    int l2 = 1023 - l;
    int l3 = 1023 - l1;
    size_t base = (size_t)b*4*1024*256;
    size_t i0 = base + ((size_t)0*1024 + l )*256 + d;
    size_t i1 = base + ((size_t)1*1024 + l1)*256 + d;
    size_t i2 = base + ((size_t)2*1024 + l2)*256 + d;
    size_t i3 = base + ((size_t)3*1024 + l3)*256 + d;
    float t = (y[i0] + us[i0]*Dp[0*256 + d])
            + (y[i1] + us[i1]*Dp[1*256 + d])
            + (y[i2] + us[i2]*Dp[2*256 + d])
            + (y[i3] + us[i3]*Dp[3*256 + d]);
    __shared__ float gld[256];
    __shared__ float sA[4], sB[4];
    float a = t, q = t*t;
    for (int o = 32; o; o >>= 1){ a += __shfl_down(a,o); q += __shfl_down(q,o); }
    if ((d & 63) == 0){ sA[d>>6] = a; sB[d>>6] = q; }
    __syncthreads();
    float mean = (sA[0]+sA[1]+sA[2]+sA[3]) * (1.0f/256.0f);
    float var  = (sB[0]+sB[1]+sB[2]+sB[3]) * (1.0f/256.0f) - mean*mean;
    float rs = rsqrtf(var + 1e-5f);
    float ym = (t - mean)*rs*onw[d] + onb[d];
    gld[d] = ym * dev_silu(z[(size_t)bl*256 + d]);
    __syncthreads();
    if (d < 128){
        float acc = 0.f;
        for (int c = 0; c < 256; ++c) acc = fmaf(gld[c], ow[c*128 + d], acc);
        sv[(size_t)bl*128 + d] += acc;
    }
}

// ---------------- repack (B,L,128)+(B,L,128) -> zero-padded NCHW (B,256,34,34) ----------------
__global__ void __launch_bounds__(256)
k_repack(const float* __restrict__ sm, const float* __restrict__ sv, float* __restrict__ xcp)
{
    int bc = blockIdx.x;            // b*256 + c
    int b = bc >> 8, c = bc & 255;
    const float* src = (c < 128) ? (sm + (size_t)b*1024*128 + c)
                                 : (sv + (size_t)b*1024*128 + (c - 128));
    float* dst = xcp + (size_t)bc*34*34;
    for (int i = threadIdx.x; i < 34*34; i += 256){
        int hp = i / 34, wp = i % 34;
        float v = 0.f;
        if (hp >= 1 && hp <= 32 && wp >= 1 && wp <= 32)
            v = src[(size_t)(((hp-1)<<5) + (wp-1))*128];
        dst[i] = v;
    }
}

// ---------------- fuse 3x3 conv (256->256) + BN + ReLU ----------------
__global__ void __launch_bounds__(256)
k_fuse(const float* __restrict__ xcp, const float* __restrict__ fw, const float* __restrict__ fb,
       const float* __restrict__ bg, const float* __restrict__ bb, const float* __restrict__ bm,
       const float* __restrict__ bv, float* __restrict__ out)
{
    int gid = blockIdx.x;           // (b*256 + o)*4 + hg
    int hg = gid & 3; int bo = gid >> 2; int b = bo >> 8, o = bo & 255;
    int tid = threadIdx.x;
    int hl = tid >> 5, wx = tid & 31;
    int h0 = hg * 8;
    __shared__ float wt[2304];       // 256 c x 9
    __shared__ float xt[4][340];     // 4 c x 10 rows x 34
    for (int i = tid; i < 2304; i += 256) wt[i] = fw[(size_t)o*2304 + i];
    float acc = 0.f;
    for (int c0 = 0; c0 < 256; c0 += 4){
        __syncthreads();
        for (int i = tid; i < 4*340; i += 256){
            int cc = i / 340, j = i % 340;
            xt[cc][j] = xcp[((size_t)(b*256 + c0 + cc)*34 + h0)*34 + j];
        }
        __syncthreads();
        #pragma unroll
        for (int cc = 0; cc < 4; ++cc){
            const float* wp_ = &wt[(c0 + cc)*9];
            const float* xp  = &xt[cc][hl*34 + wx];
            acc += xp[0]*wp_[0] + xp[1]*wp_[1] + xp[2]*wp_[2]
                 + xp[34]*wp_[3] + xp[35]*wp_[4] + xp[36]*wp_[5]
                 + xp[68]*wp_[6] + xp[69]*wp_[7] + xp[70]*wp_[8];
        }
    }
    acc += fb[o];
    float yv = (acc - bm[o]) * rsqrtf(bv[o] + 1e-5f) * bg[o] + bb[o];
    out[((size_t)(b*256 + o)*32 + (h0 + hl))*32 + wx] = fmaxf(yv, 0.f);
}

extern "C" void kernel_launch(void* const* d_in, const int* in_sizes, int n_in,
                              void* d_out, int out_size, void* d_ws, size_t ws_size,
                              hipStream_t stream)
{
    const float* x         = (const float*)d_in[0];
    const float* proj1_w   = (const float*)d_in[1];
    const float* proj1_b   = (const float*)d_in[2];
    const float* proj2_w   = (const float*)d_in[3];
    const float* proj2_b   = (const float*)d_in[4];
    const float* m_ln_w    = (const float*)d_in[5];
    const float* m_ln_b    = (const float*)d_in[6];
    const float* m_in_w    = (const float*)d_in[7];
    const float* m_conv_w  = (const float*)d_in[8];
    const float* m_conv_b  = (const float*)d_in[9];
    const float* m_xproj_w = (const float*)d_in[10];
    const float* m_dt_w    = (const float*)d_in[11];
    const float* m_dt_b    = (const float*)d_in[12];
    const float* m_Alog    = (const float*)d_in[13];
    const float* m_D       = (const float*)d_in[14];
    const float* m_out_w   = (const float*)d_in[15];
    const float* v_ln_w    = (const float*)d_in[16];
    const float* v_ln_b    = (const float*)d_in[17];
    const float* v_in_w    = (const float*)d_in[18];
    const float* v_conv_w  = (const float*)d_in[19];
    const float* v_conv_b  = (const float*)d_in[20];
    const float* v_xproj_w = (const float*)d_in[21];
    const float* v_dt_w    = (const float*)d_in[22];
    const float* v_dt_b    = (const float*)d_in[23];
    const float* v_Alog    = (const float*)d_in[24];
    const float* v_D       = (const float*)d_in[25];
    const float* v_onorm_w = (const float*)d_in[26];
    const float* v_onorm_b = (const float*)d_in[27];
    const float* v_out_w   = (const float*)d_in[28];
    const float* fuse_w    = (const float*)d_in[29];
    const float* fuse_b    = (const float*)d_in[30];
    const float* bn_g      = (const float*)d_in[31];
    const float* bn_b      = (const float*)d_in[32];
    const float* bn_m      = (const float*)d_in[33];
    const float* bn_v      = (const float*)d_in[34];
    float* out = (float*)d_out;

    float* ws = (float*)d_ws;
    float* sm    = ws;  ws += 2*1024*128;      // (B,L,128) mamba state
    float* sv    = ws;  ws += 2*1024*128;      // (B,L,128) vss state
    float* uraw  = ws;  ws += 2*1024*256;      // pre-conv u
    float* zb    = ws;  ws += 2*1024*256;      // z
    float* uc    = ws;  ws += 2*1024*256;      // mamba post-conv u
    float* usb   = ws;  ws += 2*4*1024*256;    // vss 4-direction sequences
    float* dtb_  = ws;  ws += 2*4*1024*256;    // dt (B,K,L,D)
    float* yb    = ws;  ws += 2*4*1024*256;    // scan output (B,K,L,D)
    float* Pb    = ws;  ws += 2*4*NCH*256*16;  // chunk products (then h_in, in place)
    float* Qb    = ws;  ws += 2*4*NCH*256*16;  // chunk-local states
    float* Bmb   = ws;  ws += 2*4*1024*16;
    float* Cmb   = ws;  ws += 2*4*1024*16;
    float* xcp   = Qb;                          // alias: Qb dead before repack; 0.6M < 2M floats

    k_proj<<<2*1024, 256, 0, stream>>>(x, proj1_w, proj1_b, proj2_w, proj2_b, sm, sv);

    for (int i = 0; i < 2; ++i){
        k_lnmm <<<2*1024, 256, 0, stream>>>(sm, m_ln_w + i*128, m_ln_b + i*128,
                                            m_in_w + (size_t)i*128*512, uraw, zb);
        k_mconv<<<2*1024, 256, 0, stream>>>(uraw, m_conv_w + (size_t)i*256*4, m_conv_b + i*256, uc);
        k_xproj<<<2*1024, 256, 0, stream>>>(uc, m_xproj_w + (size_t)i*256*40,
                                            m_dt_w + (size_t)i*8*256, m_dt_b + i*256,
                                            dtb_, Bmb, Cmb, 1);
        k_scanA<<<2*NCH, 256, 0, stream>>>(dtb_, uc, Bmb, m_Alog + (size_t)i*256*16, Pb, Qb, 1);
        k_scanP<<<2*16,  256, 0, stream>>>(Pb, Qb);
        k_scanB<<<2*NCH, 256, 0, stream>>>(dtb_, uc, Bmb, Cmb, m_Alog + (size_t)i*256*16,
                                           Pb, yb, 1);
        k_mout <<<2*1024, 256, 0, stream>>>(yb, uc, zb, m_D + i*256,
                                            m_out_w + (size_t)i*256*128, sm);
    }

    for (int i = 0; i < 2; ++i){
        k_lnmm <<<2*1024,   256, 0, stream>>>(sv, v_ln_w + i*128, v_ln_b + i*128,
                                              v_in_w + (size_t)i*128*512, uraw, zb);
        k_vconv<<<2*1024,   256, 0, stream>>>(uraw, v_conv_w + (size_t)i*256*9, v_conv_b + i*256, usb);
        k_xproj<<<2*4*1024, 256, 0, stream>>>(usb, v_xproj_w + (size_t)i*4*256*40,
                                              v_dt_w + (size_t)i*4*8*256, v_dt_b + (size_t)i*4*256,
                                              dtb_, Bmb, Cmb, 4);
        k_scanA<<<2*4*NCH, 256, 0, stream>>>(dtb_, usb, Bmb, v_Alog + (size_t)i*4*256*16,
                                             Pb, Qb, 4);
        k_scanP<<<2*4*16,  256, 0, stream>>>(Pb, Qb);
        k_scanB<<<2*4*NCH, 256, 0, stream>>>(dtb_, usb, Bmb, Cmb, v_Alog + (size_t)i*4*256*16,
                                             Pb, yb, 4);
        k_vcomb<<<2*1024,   256, 0, stream>>>(yb, usb, zb, v_D + (size_t)i*4*256,
                                              v_onorm_w + i*256, v_onorm_b + i*256,
                                              v_out_w + (size_t)i*256*128, sv);
    }

    k_repack<<<2*256,   256, 0, stream>>>(sm, sv, xcp);
    k_fuse  <<<2*256*4, 256, 0, stream>>>(xcp, fuse_w, fuse_b, bn_g, bn_b, bn_m, bn_v, out);
}

// Round 4
// 419.022 us; speedup vs baseline: 5.1487x; 1.3687x over previous
//
#include <hip/hip_runtime.h>
#include <math.h>

// Problem constants
// B=2, DIM=256, H=W=32, L=1024, HALF=128, DI=256, DS=16, DTR=8, DEPTH=2, K1=4
#define CH  16      // scan chunk length
#define NCH 64      // chunks per sequence (L / CH)

typedef __attribute__((ext_vector_type(8))) short bf16x8;
typedef __attribute__((ext_vector_type(4))) float f32x4;
typedef __attribute__((ext_vector_type(4))) unsigned int u32x4;

__device__ __forceinline__ float dev_silu(float x){ return x * (1.0f/(1.0f + __expf(-x))); }
__device__ __forceinline__ float dev_softplus(float x){ return fmaxf(x,0.0f) + log1pf(__expf(-fabsf(x))); }
__device__ __forceinline__ unsigned short dev_bf16(float f){
    unsigned int u = __float_as_uint(f);
    return (unsigned short)((u + 0x7fffu + ((u >> 16) & 1u)) >> 16);
}

// ---------------- proj: p1/p2 = proj_w @ x + b ; store as (B, L, 128) ----------------
__global__ void __launch_bounds__(256)
k_proj(const float* __restrict__ x, const float* __restrict__ w1, const float* __restrict__ b1,
       const float* __restrict__ w2, const float* __restrict__ b2,
       float* __restrict__ sm, float* __restrict__ sv)
{
    int bl = blockIdx.x;            // b*L + l
    int b = bl >> 10, l = bl & 1023;
    int tid = threadIdx.x;
    __shared__ float xs[256];
    xs[tid] = x[(size_t)(b*256 + tid)*1024 + l];
    __syncthreads();
    int o = tid & 127;
    const float* wr = (tid < 128) ? (w1 + o*256) : (w2 + o*256);
    float acc = (tid < 128) ? b1[o] : b2[o];
    #pragma unroll 8
    for (int c = 0; c < 256; ++c) acc = fmaf(wr[c], xs[c], acc);
    if (tid < 128) sm[(size_t)bl*128 + o] = acc;
    else           sv[(size_t)bl*128 + o] = acc;
}

// ---------------- LN over 128 + matmul (128->512) -> u (B,L,256), z (B,L,256) --------
__global__ void __launch_bounds__(256)
k_lnmm(const float* __restrict__ s, const float* __restrict__ lnw, const float* __restrict__ lnb,
       const float* __restrict__ inw, float* __restrict__ u, float* __restrict__ z)
{
    int bl = blockIdx.x; int tid = threadIdx.x;
    __shared__ float row[128];
    __shared__ float hn[128];
    __shared__ float sA[4], sB[4];
    float v = 0.f;
    if (tid < 128){ v = s[(size_t)bl*128 + tid]; row[tid] = v; }
    float a = v, q = v*v;
    for (int o = 32; o; o >>= 1){ a += __shfl_down(a,o); q += __shfl_down(q,o); }
    if ((tid & 63) == 0){ sA[tid>>6] = a; sB[tid>>6] = q; }
    __syncthreads();
    float mean = (sA[0]+sA[1]+sA[2]+sA[3]) * (1.0f/128.0f);
    float var  = (sB[0]+sB[1]+sB[2]+sB[3]) * (1.0f/128.0f) - mean*mean;
    float rs = rsqrtf(var + 1e-5f);
    if (tid < 128) hn[tid] = (row[tid]-mean)*rs*lnw[tid] + lnb[tid];
    __syncthreads();
    float a0 = 0.f, a1 = 0.f;
    for (int c = 0; c < 128; ++c){
        float hc = hn[c];
        a0 = fmaf(hc, inw[c*512 + tid],       a0);
        a1 = fmaf(hc, inw[c*512 + tid + 256], a1);
    }
    u[(size_t)bl*256 + tid] = a0;
    z[(size_t)bl*256 + tid] = a1;
}

// ---------------- mamba causal conv (K1=4) + silu ----------------
__global__ void __launch_bounds__(256)
k_mconv(const float* __restrict__ ur, const float* __restrict__ cw, const float* __restrict__ cb,
        float* __restrict__ uc)
{
    int bl = blockIdx.x; int b = bl >> 10, l = bl & 1023; int d = threadIdx.x;
    float acc = cb[d];
    #pragma unroll
    for (int k = 0; k < 4; ++k){
        int lp = l - 3 + k;
        if (lp >= 0) acc = fmaf(ur[((size_t)(b<<10) + lp)*256 + d], cw[d*4 + k], acc);
    }
    uc[(size_t)bl*256 + d] = dev_silu(acc);
}

// ---------------- vss depthwise 3x3 conv + silu + 4-direction scatter ----------------
__global__ void __launch_bounds__(256)
k_vconv(const float* __restrict__ ur, const float* __restrict__ cw, const float* __restrict__ cb,
        float* __restrict__ us)
{
    int bl = blockIdx.x; int b = bl >> 10, l = bl & 1023; int d = threadIdx.x;
    int h = l >> 5, w = l & 31;
    float acc = cb[d];
    #pragma unroll
    for (int kh = 0; kh < 3; ++kh){
        int hh = h + kh - 1; if (hh < 0 || hh > 31) continue;
        #pragma unroll
        for (int kw = 0; kw < 3; ++kw){
            int ww = w + kw - 1; if (ww < 0 || ww > 31) continue;
            acc = fmaf(ur[((size_t)(b<<10) + (hh<<5) + ww)*256 + d], cw[d*9 + kh*3 + kw], acc);
        }
    }
    float v = dev_silu(acc);
    int l1 = (w<<5) + h;   // column-major scan position
    size_t base = (size_t)b*4*1024*256;
    us[base + ((size_t)0*1024 + l        )*256 + d] = v;
    us[base + ((size_t)1*1024 + l1       )*256 + d] = v;
    us[base + ((size_t)2*1024 + (1023-l ))*256 + d] = v;
    us[base + ((size_t)3*1024 + (1023-l1))*256 + d] = v;
}

// ---------------- xproj (u @ xw -> dtr,B,C) + dt = softplus(dtr@dtw + dtb) ----------------
__global__ void __launch_bounds__(256)
k_xproj(const float* __restrict__ u, const float* __restrict__ xw, const float* __restrict__ dtw,
        const float* __restrict__ dtb, float* __restrict__ dt, float* __restrict__ Bm,
        float* __restrict__ Cm, int K)
{
    int idx = blockIdx.x;          // bk*L + l   (bk = b*K + k)
    int bk = idx >> 10;
    int k = bk % K;
    int tid = threadIdx.x;
    __shared__ float ursh[256];
    __shared__ float part[4][40];
    __shared__ float dbc[40];
    ursh[tid] = u[(size_t)idx*256 + tid];
    __syncthreads();
    if (tid < 160){
        int r = tid % 40, p = tid / 40;    // p in [0,4)
        const float* xwc = xw + (size_t)k*256*40 + r;
        float a = 0.f;
        int c0 = p*64;
        for (int c = c0; c < c0 + 64; ++c) a = fmaf(ursh[c], xwc[c*40], a);
        part[p][r] = a;
    }
    __syncthreads();
    if (tid < 40) dbc[tid] = part[0][tid] + part[1][tid] + part[2][tid] + part[3][tid];
    __syncthreads();
    const float* dtwk = dtw + (size_t)k*8*256;
    float a = dtb[k*256 + tid];
    #pragma unroll
    for (int r = 0; r < 8; ++r) a = fmaf(dbc[r], dtwk[r*256 + tid], a);
    dt[(size_t)idx*256 + tid] = dev_softplus(a);
    if (tid < 16)      Bm[(size_t)idx*16 + tid]        = dbc[8 + tid];
    else if (tid < 32) Cm[(size_t)idx*16 + (tid - 16)] = dbc[8 + tid];  // dbc[24..39]
}

// ------- scan pass A: per-chunk (P = exp(A*sum dt), Q = chunk-local h), thread per d -------
__global__ void __launch_bounds__(256)
k_scanA(const float* __restrict__ dt, const float* __restrict__ u, const float* __restrict__ Bm,
        const float* __restrict__ Alog, float* __restrict__ Pb, float* __restrict__ Qb, int K)
{
    int blk = blockIdx.x;            // bk*NCH + c
    int c = blk & (NCH-1); int bk = blk >> 6; int k = bk % K;
    int d = threadIdx.x;
    __shared__ float Bsh[CH][16];
    {
        int j = threadIdx.x >> 4, s = threadIdx.x & 15;
        Bsh[j][s] = Bm[((size_t)bk*1024 + c*CH + j)*16 + s];
    }
    float dtv[CH], duv[CH];
    size_t base = ((size_t)bk*1024 + c*CH)*256 + d;
    #pragma unroll
    for (int j = 0; j < CH; ++j){
        float a = dt[base + (size_t)j*256];
        float b = u [base + (size_t)j*256];
        dtv[j] = a; duv[j] = a*b;
    }
    float A[16];
    const float4* Ap = (const float4*)(Alog + ((size_t)k*256 + d)*16);
    #pragma unroll
    for (int q = 0; q < 4; ++q){
        float4 v = Ap[q];
        A[q*4+0] = -__expf(v.x); A[q*4+1] = -__expf(v.y);
        A[q*4+2] = -__expf(v.z); A[q*4+3] = -__expf(v.w);
    }
    __syncthreads();
    float Q[16];
    #pragma unroll
    for (int s = 0; s < 16; ++s) Q[s] = 0.f;
    float S = 0.f;
    #pragma unroll
    for (int j = 0; j < CH; ++j){
        S += dtv[j];
        #pragma unroll
        for (int s = 0; s < 16; ++s){
            float av = __expf(dtv[j]*A[s]);
            Q[s] = fmaf(av, Q[s], duv[j]*Bsh[j][s]);
        }
    }
    float4* Pp = (float4*)(Pb + ((size_t)blk*256 + d)*16);
    float4* Qp = (float4*)(Qb + ((size_t)blk*256 + d)*16);
    #pragma unroll
    for (int q = 0; q < 4; ++q){
        float4 pv, qv;
        pv.x = __expf(S*A[q*4+0]); pv.y = __expf(S*A[q*4+1]);
        pv.z = __expf(S*A[q*4+2]); pv.w = __expf(S*A[q*4+3]);
        qv.x = Q[q*4+0]; qv.y = Q[q*4+1]; qv.z = Q[q*4+2]; qv.w = Q[q*4+3];
        Pp[q] = pv; Qp[q] = qv;
    }
}

// ------- scan pass P: exclusive prefix over NCH chunks per (bk,d,s); H overwrites P -------
__global__ void __launch_bounds__(256)
k_scanP(float* __restrict__ Pb, const float* __restrict__ Qb)
{
    int bk = blockIdx.x >> 4;
    int dg = blockIdx.x & 15;       // group of 16 d
    int tid = threadIdx.x;          // dl*16 + s
    size_t idx0 = (size_t)bk*NCH*4096 + dg*256 + tid;
    float Pv[NCH], Qv[NCH];
    #pragma unroll
    for (int c = 0; c < NCH; ++c){
        Pv[c] = Pb[idx0 + (size_t)c*4096];
        Qv[c] = Qb[idx0 + (size_t)c*4096];
    }
    float h = 0.f;
    #pragma unroll
    for (int c = 0; c < NCH; ++c){
        Pb[idx0 + (size_t)c*4096] = h;      // h_in for chunk c
        h = fmaf(Pv[c], h, Qv[c]);
    }
}

// ------- scan pass B: replay chunk with h_in; y[l,d] = sum_s h*C; thread per d -------
__global__ void __launch_bounds__(256)
k_scanB(const float* __restrict__ dt, const float* __restrict__ u, const float* __restrict__ Bm,
        const float* __restrict__ Cm, const float* __restrict__ Alog,
        const float* __restrict__ Hb, float* __restrict__ y, int K)
{
    int blk = blockIdx.x;            // bk*NCH + c
    int c = blk & (NCH-1); int bk = blk >> 6; int k = bk % K;
    int d = threadIdx.x;
    __shared__ float Bsh[CH][16], Csh[CH][16];
    {
        int j = threadIdx.x >> 4, s = threadIdx.x & 15;
        size_t bi = ((size_t)bk*1024 + c*CH + j)*16 + s;
        Bsh[j][s] = Bm[bi];
        Csh[j][s] = Cm[bi];
    }
    float dtv[CH], duv[CH];
    size_t base = ((size_t)bk*1024 + c*CH)*256 + d;
    #pragma unroll
    for (int j = 0; j < CH; ++j){
        float a = dt[base + (size_t)j*256];
        float b = u [base + (size_t)j*256];
        dtv[j] = a; duv[j] = a*b;
    }
    float A[16];
    const float4* Ap = (const float4*)(Alog + ((size_t)k*256 + d)*16);
    #pragma unroll
    for (int q = 0; q < 4; ++q){
        float4 v = Ap[q];
        A[q*4+0] = -__expf(v.x); A[q*4+1] = -__expf(v.y);
        A[q*4+2] = -__expf(v.z); A[q*4+3] = -__expf(v.w);
    }
    float h[16];
    const float4* Hp = (const float4*)(Hb + ((size_t)blk*256 + d)*16);
    #pragma unroll
    for (int q = 0; q < 4; ++q){
        float4 v = Hp[q];
        h[q*4+0] = v.x; h[q*4+1] = v.y; h[q*4+2] = v.z; h[q*4+3] = v.w;
    }
    __syncthreads();
    float* yp = y + base;
    #pragma unroll
    for (int j = 0; j < CH; ++j){
        float py = 0.f;
        #pragma unroll
        for (int s = 0; s < 16; ++s){
            float av = __expf(dtv[j]*A[s]);
            h[s] = fmaf(av, h[s], duv[j]*Bsh[j][s]);
            py = fmaf(h[s], Csh[j][s], py);
        }
        yp[(size_t)j*256] = py;
    }
}

// ---------------- mamba epilogue: (y + u*D) * silu(z) @ ow  -> sm += ----------------
__global__ void __launch_bounds__(256)
k_mout(const float* __restrict__ y, const float* __restrict__ uc, const float* __restrict__ z,
       const float* __restrict__ Dp, const float* __restrict__ ow, float* __restrict__ sm)
{
    int bl = blockIdx.x; int tid = threadIdx.x;
    __shared__ float gld[256];
    float yv = y[(size_t)bl*256 + tid] + uc[(size_t)bl*256 + tid]*Dp[tid];
    gld[tid] = yv * dev_silu(z[(size_t)bl*256 + tid]);
    __syncthreads();
    if (tid < 128){
        float a = 0.f;
        for (int c = 0; c < 256; ++c) a = fmaf(gld[c], ow[c*128 + tid], a);
        sm[(size_t)bl*128 + tid] += a;
    }
}

// ---------------- vss epilogue: gather 4 dirs (+us*D), LN(256), *silu(z), @ ow -> sv += ----
__global__ void __launch_bounds__(256)
k_vcomb(const float* __restrict__ y, const float* __restrict__ us, const float* __restrict__ z,
        const float* __restrict__ Dp, const float* __restrict__ onw, const float* __restrict__ onb,
        const float* __restrict__ ow, float* __restrict__ sv)
{
    int bl = blockIdx.x; int b = bl >> 10, l = bl & 1023; int d = threadIdx.x;
    int h = l >> 5, w = l & 31;
    int l1 = (w<<5) + h;
    int l2 = 1023 - l;
    int l3 = 1023 - l1;
    size_t base = (size_t)b*4*1024*256;
    size_t i0 = base + ((size_t)0*1024 + l )*256 + d;
    size_t i1 = base + ((size_t)1*1024 + l1)*256 + d;
    size_t i2 = base + ((size_t)2*1024 + l2)*256 + d;
    size_t i3 = base + ((size_t)3*1024 + l3)*256 + d;
    float t = (y[i0] + us[i0]*Dp[0*256 + d])
            + (y[i1] + us[i1]*Dp[1*256 + d])
            + (y[i2] + us[i2]*Dp[2*256 + d])
            + (y[i3] + us[i3]*Dp[3*256 + d]);
    __shared__ float gld[256];
    __shared__ float sA[4], sB[4];
    float a = t, q = t*t;
    for (int o = 32; o; o >>= 1){ a += __shfl_down(a,o); q += __shfl_down(q,o); }
    if ((d & 63) == 0){ sA[d>>6] = a; sB[d>>6] = q; }
    __syncthreads();
    float mean = (sA[0]+sA[1]+sA[2]+sA[3]) * (1.0f/256.0f);
    float var  = (sB[0]+sB[1]+sB[2]+sB[3]) * (1.0f/256.0f) - mean*mean;
    float rs = rsqrtf(var + 1e-5f);
    float ym = (t - mean)*rs*onw[d] + onb[d];
    gld[d] = ym * dev_silu(z[(size_t)bl*256 + d]);
    __syncthreads();
    if (d < 128){
        float acc = 0.f;
        for (int c = 0; c < 256; ++c) acc = fmaf(gld[c], ow[c*128 + d], acc);
        sv[(size_t)bl*128 + d] += acc;
    }
}

// ---------------- fuse conv as implicit GEMM: weight cast to bf16 ----------------
__global__ void __launch_bounds__(256)
k_wconv(const float* __restrict__ fw, unsigned short* __restrict__ Wb)
{
    int idx = (blockIdx.x*256 + threadIdx.x)*4;      // 589824 = 576*1024
    float4 v = *(const float4*)(fw + idx);
    unsigned int r0 = dev_bf16(v.x), r1 = dev_bf16(v.y), r2 = dev_bf16(v.z), r3 = dev_bf16(v.w);
    uint2 pk; pk.x = r0 | (r1 << 16); pk.y = r2 | (r3 << 16);
    *(uint2*)(Wb + idx) = pk;
}

// ---- im2col (zero-pad folded): Bt[n=b*1024+p][k=c*9+kh*3+kw] bf16, from sm/sv ----
__global__ void __launch_bounds__(256)
k_im2col(const float* __restrict__ sm, const float* __restrict__ sv,
         unsigned short* __restrict__ Bt)
{
    int n = blockIdx.x; int b = n >> 10, p = n & 1023;
    int h = p >> 5, w = p & 31;
    int tid = threadIdx.x;
    #pragma unroll
    for (int it = 0; it < 9; ++it){                  // 9*256 = 2304 = K exactly
        int k = it*256 + tid;
        int c = k / 9, r = k - c*9;
        int kh = r / 3, kw = r - kh*3;
        int hh = h + kh - 1, ww = w + kw - 1;
        float v = 0.f;
        if (hh >= 0 && hh < 32 && ww >= 0 && ww < 32){
            int l = (hh << 5) + ww;
            v = (c < 128) ? sm[((size_t)b*1024 + l)*128 + c]
                          : sv[((size_t)b*1024 + l)*128 + (c - 128)];
        }
        Bt[(size_t)n*2304 + k] = dev_bf16(v);
    }
}

// ---- bf16 MFMA GEMM: out[o][n] = W[o][:]·Bt[n][:], + bias + BN + ReLU ----
// M=256, N=2048, K=2304; BM=BN=64, BK=32; 4 waves, each 32x32 (2x2 16x16x32 frags)
__global__ void __launch_bounds__(256)
k_fgemm(const unsigned short* __restrict__ Wb, const unsigned short* __restrict__ Bt,
        const float* __restrict__ fb, const float* __restrict__ bg, const float* __restrict__ bb,
        const float* __restrict__ bm, const float* __restrict__ bv, float* __restrict__ out)
{
    int o0 = (blockIdx.x & 3) * 64;
    int n0 = (blockIdx.x >> 2) * 64;
    int tid = threadIdx.x, lane = tid & 63, wid = tid >> 6;
    int wm = (wid >> 1) * 32, wn = (wid & 1) * 32;
    __shared__ unsigned short sA[64*40];   // rows padded to 80B (bank-even)
    __shared__ unsigned short sB[64*40];
    f32x4 acc[2][2] = {};
    int srow = tid >> 2, scol = (tid & 3) * 8;
    const u32x4* gA = (const u32x4*)(Wb + (size_t)(o0 + srow)*2304 + scol);
    const u32x4* gB = (const u32x4*)(Bt + (size_t)(n0 + srow)*2304 + scol);
    u32x4* wA = (u32x4*)(sA + srow*40 + scol);
    u32x4* wB = (u32x4*)(sB + srow*40 + scol);
    int fr = lane & 15, fk = (lane >> 4) * 8;
    const unsigned short* rA0 = sA + (wm + fr)*40 + fk;
    const unsigned short* rA1 = sA + (wm + 16 + fr)*40 + fk;
    const unsigned short* rB0 = sB + (wn + fr)*40 + fk;
    const unsigned short* rB1 = sB + (wn + 16 + fr)*40 + fk;
    for (int kt = 0; kt < 72; ++kt){
        u32x4 va = gA[kt*4];            // k advances 32 shorts = 4x16B
        u32x4 vb = gB[kt*4];
        __syncthreads();
        *wA = va; *wB = vb;
        __syncthreads();
        bf16x8 a0 = *(const bf16x8*)rA0;
        bf16x8 a1 = *(const bf16x8*)rA1;
        bf16x8 b0 = *(const bf16x8*)rB0;
        bf16x8 b1 = *(const bf16x8*)rB1;
        acc[0][0] = __builtin_amdgcn_mfma_f32_16x16x32_bf16(a0, b0, acc[0][0], 0, 0, 0);
        acc[0][1] = __builtin_amdgcn_mfma_f32_16x16x32_bf16(a0, b1, acc[0][1], 0, 0, 0);
        acc[1][0] = __builtin_amdgcn_mfma_f32_16x16x32_bf16(a1, b0, acc[1][0], 0, 0, 0);
        acc[1][1] = __builtin_amdgcn_mfma_f32_16x16x32_bf16(a1, b1, acc[1][1], 0, 0, 0);
    }
    #pragma unroll
    for (int i = 0; i < 2; ++i){
        int ob = o0 + wm + i*16 + (lane >> 4) * 4;   // D row = (lane>>4)*4 + reg
        #pragma unroll
        for (int j = 0; j < 2; ++j){
            int n = n0 + wn + j*16 + (lane & 15);    // D col = lane&15
            int b = n >> 10, p = n & 1023;
            #pragma unroll
            for (int q = 0; q < 4; ++q){
                int o = ob + q;
                float v = acc[i][j][q] + fb[o];
                v = (v - bm[o]) * rsqrtf(bv[o] + 1e-5f) * bg[o] + bb[o];
                out[((size_t)(b*256 + o))*1024 + p] = fmaxf(v, 0.f);
            }
        }
    }
}

extern "C" void kernel_launch(void* const* d_in, const int* in_sizes, int n_in,
                              void* d_out, int out_size, void* d_ws, size_t ws_size,
                              hipStream_t stream)
{
    const float* x         = (const float*)d_in[0];
    const float* proj1_w   = (const float*)d_in[1];
    const float* proj1_b   = (const float*)d_in[2];
    const float* proj2_w   = (const float*)d_in[3];
    const float* proj2_b   = (const float*)d_in[4];
    const float* m_ln_w    = (const float*)d_in[5];
    const float* m_ln_b    = (const float*)d_in[6];
    const float* m_in_w    = (const float*)d_in[7];
    const float* m_conv_w  = (const float*)d_in[8];
    const float* m_conv_b  = (const float*)d_in[9];
    const float* m_xproj_w = (const float*)d_in[10];
    const float* m_dt_w    = (const float*)d_in[11];
    const float* m_dt_b    = (const float*)d_in[12];
    const float* m_Alog    = (const float*)d_in[13];
    const float* m_D       = (const float*)d_in[14];
    const float* m_out_w   = (const float*)d_in[15];
    const float* v_ln_w    = (const float*)d_in[16];
    const float* v_ln_b    = (const float*)d_in[17];
    const float* v_in_w    = (const float*)d_in[18];
    const float* v_conv_w  = (const float*)d_in[19];
    const float* v_conv_b  = (const float*)d_in[20];
    const float* v_xproj_w = (const float*)d_in[21];
    const float* v_dt_w    = (const float*)d_in[22];
    const float* v_dt_b    = (const float*)d_in[23];
    const float* v_Alog    = (const float*)d_in[24];
    const float* v_D       = (const float*)d_in[25];
    const float* v_onorm_w = (const float*)d_in[26];
    const float* v_onorm_b = (const float*)d_in[27];
    const float* v_out_w   = (const float*)d_in[28];
    const float* fuse_w    = (const float*)d_in[29];
    const float* fuse_b    = (const float*)d_in[30];
    const float* bn_g      = (const float*)d_in[31];
    const float* bn_b      = (const float*)d_in[32];
    const float* bn_m      = (const float*)d_in[33];
    const float* bn_v      = (const float*)d_in[34];
    float* out = (float*)d_out;

    float* ws = (float*)d_ws;
    float* sm    = ws;  ws += 2*1024*128;      // (B,L,128) mamba state
    float* sv    = ws;  ws += 2*1024*128;      // (B,L,128) vss state
    float* uraw  = ws;  ws += 2*1024*256;      // pre-conv u
    float* zb    = ws;  ws += 2*1024*256;      // z
    float* uc    = ws;  ws += 2*1024*256;      // mamba post-conv u
    float* usb   = ws;  ws += 2*4*1024*256;    // vss 4-direction sequences
    float* dtb_  = ws;  ws += 2*4*1024*256;    // dt (B,K,L,D)
    float* yb    = ws;  ws += 2*4*1024*256;    // scan output (B,K,L,D)
    float* Pb    = ws;  ws += 2*4*NCH*256*16;  // chunk products (then h_in, in place)
    float* Qb    = ws;  ws += 2*4*NCH*256*16;  // chunk-local states
    float* Bmb   = ws;  ws += 2*4*1024*16;
    float* Cmb   = ws;  ws += 2*4*1024*16;
    // aliases (only live after both path loops finish):
    unsigned short* Wbf   = (unsigned short*)uraw;   // 1.18 MB <= 2.1 MB
    unsigned short* Bmat  = (unsigned short*)dtb_;   // 9.44 MB <= dtb_+yb (16.8 MB)

    k_proj<<<2*1024, 256, 0, stream>>>(x, proj1_w, proj1_b, proj2_w, proj2_b, sm, sv);

    for (int i = 0; i < 2; ++i){
        k_lnmm <<<2*1024, 256, 0, stream>>>(sm, m_ln_w + i*128, m_ln_b + i*128,
                                            m_in_w + (size_t)i*128*512, uraw, zb);
        k_mconv<<<2*1024, 256, 0, stream>>>(uraw, m_conv_w + (size_t)i*256*4, m_conv_b + i*256, uc);
        k_xproj<<<2*1024, 256, 0, stream>>>(uc, m_xproj_w + (size_t)i*256*40,
                                            m_dt_w + (size_t)i*8*256, m_dt_b + i*256,
                                            dtb_, Bmb, Cmb, 1);
        k_scanA<<<2*NCH, 256, 0, stream>>>(dtb_, uc, Bmb, m_Alog + (size_t)i*256*16, Pb, Qb, 1);
        k_scanP<<<2*16,  256, 0, stream>>>(Pb, Qb);
        k_scanB<<<2*NCH, 256, 0, stream>>>(dtb_, uc, Bmb, Cmb, m_Alog + (size_t)i*256*16,
                                           Pb, yb, 1);
        k_mout <<<2*1024, 256, 0, stream>>>(yb, uc, zb, m_D + i*256,
                                            m_out_w + (size_t)i*256*128, sm);
    }

    for (int i = 0; i < 2; ++i){
        k_lnmm <<<2*1024,   256, 0, stream>>>(sv, v_ln_w + i*128, v_ln_b + i*128,
                                              v_in_w + (size_t)i*128*512, uraw, zb);
        k_vconv<<<2*1024,   256, 0, stream>>>(uraw, v_conv_w + (size_t)i*256*9, v_conv_b + i*256, usb);
        k_xproj<<<2*4*1024, 256, 0, stream>>>(usb, v_xproj_w + (size_t)i*4*256*40,
                                              v_dt_w + (size_t)i*4*8*256, v_dt_b + (size_t)i*4*256,
                                              dtb_, Bmb, Cmb, 4);
        k_scanA<<<2*4*NCH, 256, 0, stream>>>(dtb_, usb, Bmb, v_Alog + (size_t)i*4*256*16,
                                             Pb, Qb, 4);
        k_scanP<<<2*4*16,  256, 0, stream>>>(Pb, Qb);
        k_scanB<<<2*4*NCH, 256, 0, stream>>>(dtb_, usb, Bmb, Cmb, v_Alog + (size_t)i*4*256*16,
                                             Pb, yb, 4);
        k_vcomb<<<2*1024,   256, 0, stream>>>(yb, usb, zb, v_D + (size_t)i*4*256,
                                              v_onorm_w + i*256, v_onorm_b + i*256,
                                              v_out_w + (size_t)i*256*128, sv);
    }

    k_wconv <<<576,     256, 0, stream>>>(fuse_w, Wbf);
    k_im2col<<<2*1024,  256, 0, stream>>>(sm, sv, Bmat);
    k_fgemm <<<4*32,    256, 0, stream>>>(Wbf, Bmat, fuse_b, bn_g, bn_b, bn_m, bn_v, out);
}

// Round 5
// 381.823 us; speedup vs baseline: 5.6504x; 1.0974x over previous
//
#include <hip/hip_runtime.h>
#include <math.h>

// Problem constants
// B=2, DIM=256, H=W=32, L=1024, HALF=128, DI=256, DS=16, DTR=8, DEPTH=2, K1=4
#define CH  16      // scan chunk length
#define NCH 64      // chunks per sequence (L / CH)

typedef __attribute__((ext_vector_type(8))) short bf16x8;
typedef __attribute__((ext_vector_type(4))) float f32x4;
typedef __attribute__((ext_vector_type(4))) unsigned int u32x4;

__device__ __forceinline__ float dev_silu(float x){ return x * (1.0f/(1.0f + __expf(-x))); }
__device__ __forceinline__ float dev_softplus(float x){ return fmaxf(x,0.0f) + log1pf(__expf(-fabsf(x))); }
__device__ __forceinline__ unsigned short dev_bf16(float f){
    unsigned int u = __float_as_uint(f);
    return (unsigned short)((u + 0x7fffu + ((u >> 16) & 1u)) >> 16);
}

// ---- transpose proj weights: wtc[c][o] ; o in [0,128)=w1 row, [128,256)=w2 row ----
__global__ void __launch_bounds__(256)
k_wt(const float* __restrict__ w1, const float* __restrict__ w2, float* __restrict__ wtc)
{
    int bc = blockIdx.x;           // 8 o-tiles x 8 c-tiles
    int ot = bc & 7, ct = bc >> 3;
    __shared__ float t[32][33];
    int col = threadIdx.x & 31, r8 = threadIdx.x >> 5;
    #pragma unroll
    for (int i = 0; i < 4; ++i){
        int r = i*8 + r8;
        int o = ot*32 + r;
        const float* src = (o < 128) ? (w1 + (size_t)o*256) : (w2 + (size_t)(o-128)*256);
        t[r][col] = src[ct*32 + col];
    }
    __syncthreads();
    #pragma unroll
    for (int i = 0; i < 4; ++i){
        int r = i*8 + r8;
        int c = ct*32 + r, o = ot*32 + col;
        wtc[(size_t)c*256 + o] = t[col][r];
    }
}

// ---- proj v2: block per (b, 4-l tile); coalesced transposed-weight reads ----
__global__ void __launch_bounds__(256)
k_proj(const float* __restrict__ x, const float* __restrict__ wtc,
       const float* __restrict__ b1, const float* __restrict__ b2,
       float* __restrict__ sm, float* __restrict__ sv)
{
    int blk = blockIdx.x;          // b*256 + lt
    int b = blk >> 8, l0 = (blk & 255) * 4;
    int tid = threadIdx.x;
    __shared__ float4 xs[256];
    xs[tid] = *(const float4*)(x + ((size_t)(b*256 + tid))*1024 + l0);
    __syncthreads();
    int o = tid & 127;
    float bias = (tid < 128) ? b1[o] : b2[o - 0];   // tid<128: b1[o]; else b2[o]
    if (tid >= 128) bias = b2[o];
    float a0 = bias, a1 = bias, a2 = bias, a3 = bias;
    #pragma unroll 4
    for (int c = 0; c < 256; ++c){
        float wv = wtc[(size_t)c*256 + tid];
        float4 xv = xs[c];
        a0 = fmaf(wv, xv.x, a0);
        a1 = fmaf(wv, xv.y, a1);
        a2 = fmaf(wv, xv.z, a2);
        a3 = fmaf(wv, xv.w, a3);
    }
    float* dst = (tid < 128) ? sm : sv;
    size_t base = ((size_t)b*1024 + l0)*128 + o;
    dst[base        ] = a0;
    dst[base + 128  ] = a1;
    dst[base + 256  ] = a2;
    dst[base + 384  ] = a3;
}

// ---------------- LN over 128 + matmul (128->512) -> u (B,L,256), z (B,L,256) --------
__global__ void __launch_bounds__(256)
k_lnmm(const float* __restrict__ s, const float* __restrict__ lnw, const float* __restrict__ lnb,
       const float* __restrict__ inw, float* __restrict__ u, float* __restrict__ z)
{
    int bl = blockIdx.x; int tid = threadIdx.x;
    __shared__ float row[128];
    __shared__ float hn[128];
    __shared__ float sA[4], sB[4];
    float v = 0.f;
    if (tid < 128){ v = s[(size_t)bl*128 + tid]; row[tid] = v; }
    float a = v, q = v*v;
    for (int o = 32; o; o >>= 1){ a += __shfl_down(a,o); q += __shfl_down(q,o); }
    if ((tid & 63) == 0){ sA[tid>>6] = a; sB[tid>>6] = q; }
    __syncthreads();
    float mean = (sA[0]+sA[1]+sA[2]+sA[3]) * (1.0f/128.0f);
    float var  = (sB[0]+sB[1]+sB[2]+sB[3]) * (1.0f/128.0f) - mean*mean;
    float rs = rsqrtf(var + 1e-5f);
    if (tid < 128) hn[tid] = (row[tid]-mean)*rs*lnw[tid] + lnb[tid];
    __syncthreads();
    float a0 = 0.f, a1 = 0.f;
    for (int c = 0; c < 128; ++c){
        float hc = hn[c];
        a0 = fmaf(hc, inw[c*512 + tid],       a0);
        a1 = fmaf(hc, inw[c*512 + tid + 256], a1);
    }
    u[(size_t)bl*256 + tid] = a0;
    z[(size_t)bl*256 + tid] = a1;
}

// ---------------- mamba causal conv (K1=4) + silu ----------------
__global__ void __launch_bounds__(256)
k_mconv(const float* __restrict__ ur, const float* __restrict__ cw, const float* __restrict__ cb,
        float* __restrict__ uc)
{
    int bl = blockIdx.x; int b = bl >> 10, l = bl & 1023; int d = threadIdx.x;
    float acc = cb[d];
    #pragma unroll
    for (int k = 0; k < 4; ++k){
        int lp = l - 3 + k;
        if (lp >= 0) acc = fmaf(ur[((size_t)(b<<10) + lp)*256 + d], cw[d*4 + k], acc);
    }
    uc[(size_t)bl*256 + d] = dev_silu(acc);
}

// ---------------- vss depthwise 3x3 conv + silu + 4-direction scatter ----------------
__global__ void __launch_bounds__(256)
k_vconv(const float* __restrict__ ur, const float* __restrict__ cw, const float* __restrict__ cb,
        float* __restrict__ us)
{
    int bl = blockIdx.x; int b = bl >> 10, l = bl & 1023; int d = threadIdx.x;
    int h = l >> 5, w = l & 31;
    float acc = cb[d];
    #pragma unroll
    for (int kh = 0; kh < 3; ++kh){
        int hh = h + kh - 1; if (hh < 0 || hh > 31) continue;
        #pragma unroll
        for (int kw = 0; kw < 3; ++kw){
            int ww = w + kw - 1; if (ww < 0 || ww > 31) continue;
            acc = fmaf(ur[((size_t)(b<<10) + (hh<<5) + ww)*256 + d], cw[d*9 + kh*3 + kw], acc);
        }
    }
    float v = dev_silu(acc);
    int l1 = (w<<5) + h;   // column-major scan position
    size_t base = (size_t)b*4*1024*256;
    us[base + ((size_t)0*1024 + l        )*256 + d] = v;
    us[base + ((size_t)1*1024 + l1       )*256 + d] = v;
    us[base + ((size_t)2*1024 + (1023-l ))*256 + d] = v;
    us[base + ((size_t)3*1024 + (1023-l1))*256 + d] = v;
}

// ---------------- xproj (u @ xw -> dtr,B,C) + dt = softplus(dtr@dtw + dtb) ----------------
__global__ void __launch_bounds__(256)
k_xproj(const float* __restrict__ u, const float* __restrict__ xw, const float* __restrict__ dtw,
        const float* __restrict__ dtb, float* __restrict__ dt, float* __restrict__ Bm,
        float* __restrict__ Cm, int K)
{
    int idx = blockIdx.x;          // bk*L + l   (bk = b*K + k)
    int bk = idx >> 10;
    int k = bk % K;
    int tid = threadIdx.x;
    __shared__ float ursh[256];
    __shared__ float part[4][40];
    __shared__ float dbc[40];
    ursh[tid] = u[(size_t)idx*256 + tid];
    __syncthreads();
    if (tid < 160){
        int r = tid % 40, p = tid / 40;    // p in [0,4)
        const float* xwc = xw + (size_t)k*256*40 + r;
        float a = 0.f;
        int c0 = p*64;
        for (int c = c0; c < c0 + 64; ++c) a = fmaf(ursh[c], xwc[c*40], a);
        part[p][r] = a;
    }
    __syncthreads();
    if (tid < 40) dbc[tid] = part[0][tid] + part[1][tid] + part[2][tid] + part[3][tid];
    __syncthreads();
    const float* dtwk = dtw + (size_t)k*8*256;
    float a = dtb[k*256 + tid];
    #pragma unroll
    for (int r = 0; r < 8; ++r) a = fmaf(dbc[r], dtwk[r*256 + tid], a);
    dt[(size_t)idx*256 + tid] = dev_softplus(a);
    if (tid < 16)      Bm[(size_t)idx*16 + tid]        = dbc[8 + tid];
    else if (tid < 32) Cm[(size_t)idx*16 + (tid - 16)] = dbc[8 + tid];  // dbc[24..39]
}

// ------- scan pass A: per-chunk (P = exp(A*sum dt), Q = chunk-local h), thread per d -------
__global__ void __launch_bounds__(256)
k_scanA(const float* __restrict__ dt, const float* __restrict__ u, const float* __restrict__ Bm,
        const float* __restrict__ Alog, float* __restrict__ Pb, float* __restrict__ Qb, int K)
{
    int blk = blockIdx.x;            // bk*NCH + c
    int c = blk & (NCH-1); int bk = blk >> 6; int k = bk % K;
    int d = threadIdx.x;
    __shared__ float Bsh[CH][16];
    {
        int j = threadIdx.x >> 4, s = threadIdx.x & 15;
        Bsh[j][s] = Bm[((size_t)bk*1024 + c*CH + j)*16 + s];
    }
    float dtv[CH], duv[CH];
    size_t base = ((size_t)bk*1024 + c*CH)*256 + d;
    #pragma unroll
    for (int j = 0; j < CH; ++j){
        float a = dt[base + (size_t)j*256];
        float b = u [base + (size_t)j*256];
        dtv[j] = a; duv[j] = a*b;
    }
    float A[16];
    const float4* Ap = (const float4*)(Alog + ((size_t)k*256 + d)*16);
    #pragma unroll
    for (int q = 0; q < 4; ++q){
        float4 v = Ap[q];
        A[q*4+0] = -__expf(v.x); A[q*4+1] = -__expf(v.y);
        A[q*4+2] = -__expf(v.z); A[q*4+3] = -__expf(v.w);
    }
    __syncthreads();
    float Q[16];
    #pragma unroll
    for (int s = 0; s < 16; ++s) Q[s] = 0.f;
    float S = 0.f;
    #pragma unroll
    for (int j = 0; j < CH; ++j){
        S += dtv[j];
        #pragma unroll
        for (int s = 0; s < 16; ++s){
            float av = __expf(dtv[j]*A[s]);
            Q[s] = fmaf(av, Q[s], duv[j]*Bsh[j][s]);
        }
    }
    float4* Pp = (float4*)(Pb + ((size_t)blk*256 + d)*16);
    float4* Qp = (float4*)(Qb + ((size_t)blk*256 + d)*16);
    #pragma unroll
    for (int q = 0; q < 4; ++q){
        float4 pv, qv;
        pv.x = __expf(S*A[q*4+0]); pv.y = __expf(S*A[q*4+1]);
        pv.z = __expf(S*A[q*4+2]); pv.w = __expf(S*A[q*4+3]);
        qv.x = Q[q*4+0]; qv.y = Q[q*4+1]; qv.z = Q[q*4+2]; qv.w = Q[q*4+3];
        Pp[q] = pv; Qp[q] = qv;
    }
}

// ------- scan pass P: exclusive prefix over NCH chunks per (bk,d,s); H overwrites P -------
__global__ void __launch_bounds__(256)
k_scanP(float* __restrict__ Pb, const float* __restrict__ Qb)
{
    int bk = blockIdx.x >> 4;
    int dg = blockIdx.x & 15;       // group of 16 d
    int tid = threadIdx.x;          // dl*16 + s
    size_t idx0 = (size_t)bk*NCH*4096 + dg*256 + tid;
    float Pv[NCH], Qv[NCH];
    #pragma unroll
    for (int c = 0; c < NCH; ++c){
        Pv[c] = Pb[idx0 + (size_t)c*4096];
        Qv[c] = Qb[idx0 + (size_t)c*4096];
    }
    float h = 0.f;
    #pragma unroll
    for (int c = 0; c < NCH; ++c){
        Pb[idx0 + (size_t)c*4096] = h;      // h_in for chunk c
        h = fmaf(Pv[c], h, Qv[c]);
    }
}

// ------- scan pass B: replay chunk with h_in; y[l,d] = sum_s h*C; thread per d -------
__global__ void __launch_bounds__(256)
k_scanB(const float* __restrict__ dt, const float* __restrict__ u, const float* __restrict__ Bm,
        const float* __restrict__ Cm, const float* __restrict__ Alog,
        const float* __restrict__ Hb, float* __restrict__ y, int K)
{
    int blk = blockIdx.x;            // bk*NCH + c
    int c = blk & (NCH-1); int bk = blk >> 6; int k = bk % K;
    int d = threadIdx.x;
    __shared__ float Bsh[CH][16], Csh[CH][16];
    {
        int j = threadIdx.x >> 4, s = threadIdx.x & 15;
        size_t bi = ((size_t)bk*1024 + c*CH + j)*16 + s;
        Bsh[j][s] = Bm[bi];
        Csh[j][s] = Cm[bi];
    }
    float dtv[CH], duv[CH];
    size_t base = ((size_t)bk*1024 + c*CH)*256 + d;
    #pragma unroll
    for (int j = 0; j < CH; ++j){
        float a = dt[base + (size_t)j*256];
        float b = u [base + (size_t)j*256];
        dtv[j] = a; duv[j] = a*b;
    }
    float A[16];
    const float4* Ap = (const float4*)(Alog + ((size_t)k*256 + d)*16);
    #pragma unroll
    for (int q = 0; q < 4; ++q){
        float4 v = Ap[q];
        A[q*4+0] = -__expf(v.x); A[q*4+1] = -__expf(v.y);
        A[q*4+2] = -__expf(v.z); A[q*4+3] = -__expf(v.w);
    }
    float h[16];
    const float4* Hp = (const float4*)(Hb + ((size_t)blk*256 + d)*16);
    #pragma unroll
    for (int q = 0; q < 4; ++q){
        float4 v = Hp[q];
        h[q*4+0] = v.x; h[q*4+1] = v.y; h[q*4+2] = v.z; h[q*4+3] = v.w;
    }
    __syncthreads();
    float* yp = y + base;
    #pragma unroll
    for (int j = 0; j < CH; ++j){
        float py = 0.f;
        #pragma unroll
        for (int s = 0; s < 16; ++s){
            float av = __expf(dtv[j]*A[s]);
            h[s] = fmaf(av, h[s], duv[j]*Bsh[j][s]);
            py = fmaf(h[s], Csh[j][s], py);
        }
        yp[(size_t)j*256] = py;
    }
}

// ---------------- mamba epilogue: (y + u*D) * silu(z) @ ow  -> sm += ----------------
__global__ void __launch_bounds__(256)
k_mout(const float* __restrict__ y, const float* __restrict__ uc, const float* __restrict__ z,
       const float* __restrict__ Dp, const float* __restrict__ ow, float* __restrict__ sm)
{
    int bl = blockIdx.x; int tid = threadIdx.x;
    __shared__ float gld[256];
    float yv = y[(size_t)bl*256 + tid] + uc[(size_t)bl*256 + tid]*Dp[tid];
    gld[tid] = yv * dev_silu(z[(size_t)bl*256 + tid]);
    __syncthreads();
    if (tid < 128){
        float a = 0.f;
        for (int c = 0; c < 256; ++c) a = fmaf(gld[c], ow[c*128 + tid], a);
        sm[(size_t)bl*128 + tid] += a;
    }
}

// ---------------- vss epilogue: gather 4 dirs (+us*D), LN(256), *silu(z), @ ow -> sv += ----
__global__ void __launch_bounds__(256)
k_vcomb(const float* __restrict__ y, const float* __restrict__ us, const float* __restrict__ z,
        const float* __restrict__ Dp, const float* __restrict__ onw, const float* __restrict__ onb,
        const float* __restrict__ ow, float* __restrict__ sv)
{
    int bl = blockIdx.x; int b = bl >> 10, l = bl & 1023; int d = threadIdx.x;
    int h = l >> 5, w = l & 31;
    int l1 = (w<<5) + h;
    int l2 = 1023 - l;
    int l3 = 1023 - l1;
    size_t base = (size_t)b*4*1024*256;
    size_t i0 = base + ((size_t)0*1024 + l )*256 + d;
    size_t i1 = base + ((size_t)1*1024 + l1)*256 + d;
    size_t i2 = base + ((size_t)2*1024 + l2)*256 + d;
    size_t i3 = base + ((size_t)3*1024 + l3)*256 + d;
    float t = (y[i0] + us[i0]*Dp[0*256 + d])
            + (y[i1] + us[i1]*Dp[1*256 + d])
            + (y[i2] + us[i2]*Dp[2*256 + d])
            + (y[i3] + us[i3]*Dp[3*256 + d]);
    __shared__ float gld[256];
    __shared__ float sA[4], sB[4];
    float a = t, q = t*t;
    for (int o = 32; o; o >>= 1){ a += __shfl_down(a,o); q += __shfl_down(q,o); }
    if ((d & 63) == 0){ sA[d>>6] = a; sB[d>>6] = q; }
    __syncthreads();
    float mean = (sA[0]+sA[1]+sA[2]+sA[3]) * (1.0f/256.0f);
    float var  = (sB[0]+sB[1]+sB[2]+sB[3]) * (1.0f/256.0f) - mean*mean;
    float rs = rsqrtf(var + 1e-5f);
    float ym = (t - mean)*rs*onw[d] + onb[d];
    gld[d] = ym * dev_silu(z[(size_t)bl*256 + d]);
    __syncthreads();
    if (d < 128){
        float acc = 0.f;
        for (int c = 0; c < 256; ++c) acc = fmaf(gld[c], ow[c*128 + d], acc);
        sv[(size_t)bl*128 + d] += acc;
    }
}

// ---------------- fuse conv as implicit GEMM: weight cast to bf16 ----------------
__global__ void __launch_bounds__(256)
k_wconv(const float* __restrict__ fw, unsigned short* __restrict__ Wb)
{
    int idx = (blockIdx.x*256 + threadIdx.x)*4;      // 589824 = 576*1024
    float4 v = *(const float4*)(fw + idx);
    unsigned int r0 = dev_bf16(v.x), r1 = dev_bf16(v.y), r2 = dev_bf16(v.z), r3 = dev_bf16(v.w);
    uint2 pk; pk.x = r0 | (r1 << 16); pk.y = r2 | (r3 << 16);
    *(uint2*)(Wb + idx) = pk;
}

// ---- im2col (zero-pad folded): Bt[n=b*1024+p][k=c*9+kh*3+kw] bf16, from sm/sv ----
__global__ void __launch_bounds__(256)
k_im2col(const float* __restrict__ sm, const float* __restrict__ sv,
         unsigned short* __restrict__ Bt)
{
    int n = blockIdx.x; int b = n >> 10, p = n & 1023;
    int h = p >> 5, w = p & 31;
    int tid = threadIdx.x;
    #pragma unroll
    for (int it = 0; it < 9; ++it){                  // 9*256 = 2304 = K exactly
        int k = it*256 + tid;
        int c = k / 9, r = k - c*9;
        int kh = r / 3, kw = r - kh*3;
        int hh = h + kh - 1, ww = w + kw - 1;
        float v = 0.f;
        if (hh >= 0 && hh < 32 && ww >= 0 && ww < 32){
            int l = (hh << 5) + ww;
            v = (c < 128) ? sm[((size_t)b*1024 + l)*128 + c]
                          : sv[((size_t)b*1024 + l)*128 + (c - 128)];
        }
        Bt[(size_t)n*2304 + k] = dev_bf16(v);
    }
}

// ---- bf16 MFMA GEMM: out[o][n] = W[o][:]·Bt[n][:], + bias + BN + ReLU ----
// M=256, N=2048, K=2304; BM=BN=64, BK=32; 4 waves, each 32x32 (2x2 16x16x32 frags)
__global__ void __launch_bounds__(256)
k_fgemm(const unsigned short* __restrict__ Wb, const unsigned short* __restrict__ Bt,
        const float* __restrict__ fb, const float* __restrict__ bg, const float* __restrict__ bb,
        const float* __restrict__ bm, const float* __restrict__ bv, float* __restrict__ out)
{
    int o0 = (blockIdx.x & 3) * 64;
    int n0 = (blockIdx.x >> 2) * 64;
    int tid = threadIdx.x, lane = tid & 63, wid = tid >> 6;
    int wm = (wid >> 1) * 32, wn = (wid & 1) * 32;
    __shared__ unsigned short sA[64*40];   // rows padded to 80B (bank-even)
    __shared__ unsigned short sB[64*40];
    f32x4 acc[2][2] = {};
    int srow = tid >> 2, scol = (tid & 3) * 8;
    const u32x4* gA = (const u32x4*)(Wb + (size_t)(o0 + srow)*2304 + scol);
    const u32x4* gB = (const u32x4*)(Bt + (size_t)(n0 + srow)*2304 + scol);
    u32x4* wA = (u32x4*)(sA + srow*40 + scol);
    u32x4* wB = (u32x4*)(sB + srow*40 + scol);
    int fr = lane & 15, fk = (lane >> 4) * 8;
    const unsigned short* rA0 = sA + (wm + fr)*40 + fk;
    const unsigned short* rA1 = sA + (wm + 16 + fr)*40 + fk;
    const unsigned short* rB0 = sB + (wn + fr)*40 + fk;
    const unsigned short* rB1 = sB + (wn + 16 + fr)*40 + fk;
    for (int kt = 0; kt < 72; ++kt){
        u32x4 va = gA[kt*4];            // k advances 32 shorts = 4x16B
        u32x4 vb = gB[kt*4];
        __syncthreads();
        *wA = va; *wB = vb;
        __syncthreads();
        bf16x8 a0 = *(const bf16x8*)rA0;
        bf16x8 a1 = *(const bf16x8*)rA1;
        bf16x8 b0 = *(const bf16x8*)rB0;
        bf16x8 b1 = *(const bf16x8*)rB1;
        acc[0][0] = __builtin_amdgcn_mfma_f32_16x16x32_bf16(a0, b0, acc[0][0], 0, 0, 0);
        acc[0][1] = __builtin_amdgcn_mfma_f32_16x16x32_bf16(a0, b1, acc[0][1], 0, 0, 0);
        acc[1][0] = __builtin_amdgcn_mfma_f32_16x16x32_bf16(a1, b0, acc[1][0], 0, 0, 0);
        acc[1][1] = __builtin_amdgcn_mfma_f32_16x16x32_bf16(a1, b1, acc[1][1], 0, 0, 0);
    }
    #pragma unroll
    for (int i = 0; i < 2; ++i){
        int ob = o0 + wm + i*16 + (lane >> 4) * 4;   // D row = (lane>>4)*4 + reg
        #pragma unroll
        for (int j = 0; j < 2; ++j){
            int n = n0 + wn + j*16 + (lane & 15);    // D col = lane&15
            int b = n >> 10, p = n & 1023;
            #pragma unroll
            for (int q = 0; q < 4; ++q){
                int o = ob + q;
                float v = acc[i][j][q] + fb[o];
                v = (v - bm[o]) * rsqrtf(bv[o] + 1e-5f) * bg[o] + bb[o];
                out[((size_t)(b*256 + o))*1024 + p] = fmaxf(v, 0.f);
            }
        }
    }
}

extern "C" void kernel_launch(void* const* d_in, const int* in_sizes, int n_in,
                              void* d_out, int out_size, void* d_ws, size_t ws_size,
                              hipStream_t stream)
{
    const float* x         = (const float*)d_in[0];
    const float* proj1_w   = (const float*)d_in[1];
    const float* proj1_b   = (const float*)d_in[2];
    const float* proj2_w   = (const float*)d_in[3];
    const float* proj2_b   = (const float*)d_in[4];
    const float* m_ln_w    = (const float*)d_in[5];
    const float* m_ln_b    = (const float*)d_in[6];
    const float* m_in_w    = (const float*)d_in[7];
    const float* m_conv_w  = (const float*)d_in[8];
    const float* m_conv_b  = (const float*)d_in[9];
    const float* m_xproj_w = (const float*)d_in[10];
    const float* m_dt_w    = (const float*)d_in[11];
    const float* m_dt_b    = (const float*)d_in[12];
    const float* m_Alog    = (const float*)d_in[13];
    const float* m_D       = (const float*)d_in[14];
    const float* m_out_w   = (const float*)d_in[15];
    const float* v_ln_w    = (const float*)d_in[16];
    const float* v_ln_b    = (const float*)d_in[17];
    const float* v_in_w    = (const float*)d_in[18];
    const float* v_conv_w  = (const float*)d_in[19];
    const float* v_conv_b  = (const float*)d_in[20];
    const float* v_xproj_w = (const float*)d_in[21];
    const float* v_dt_w    = (const float*)d_in[22];
    const float* v_dt_b    = (const float*)d_in[23];
    const float* v_Alog    = (const float*)d_in[24];
    const float* v_D       = (const float*)d_in[25];
    const float* v_onorm_w = (const float*)d_in[26];
    const float* v_onorm_b = (const float*)d_in[27];
    const float* v_out_w   = (const float*)d_in[28];
    const float* fuse_w    = (const float*)d_in[29];
    const float* fuse_b    = (const float*)d_in[30];
    const float* bn_g      = (const float*)d_in[31];
    const float* bn_b      = (const float*)d_in[32];
    const float* bn_m      = (const float*)d_in[33];
    const float* bn_v      = (const float*)d_in[34];
    float* out = (float*)d_out;

    float* ws = (float*)d_ws;
    float* sm    = ws;  ws += 2*1024*128;      // (B,L,128) mamba state
    float* sv    = ws;  ws += 2*1024*128;      // (B,L,128) vss state
    float* uraw  = ws;  ws += 2*1024*256;      // pre-conv u
    float* zb    = ws;  ws += 2*1024*256;      // z
    float* uc    = ws;  ws += 2*1024*256;      // mamba post-conv u
    float* usb   = ws;  ws += 2*4*1024*256;    // vss 4-direction sequences
    float* dtb_  = ws;  ws += 2*4*1024*256;    // dt (B,K,L,D)
    float* yb    = ws;  ws += 2*4*1024*256;    // scan output (B,K,L,D)
    float* Pb    = ws;  ws += 2*4*NCH*256*16;  // chunk products (then h_in, in place)
    float* Qb    = ws;  ws += 2*4*NCH*256*16;  // chunk-local states
    float* Bmb   = ws;  ws += 2*4*1024*16;
    float* Cmb   = ws;  ws += 2*4*1024*16;
    float* wtc   = ws;  ws += 256*256;         // transposed proj weights [c][o]
    // aliases (only live after both path loops finish):
    unsigned short* Wbf   = (unsigned short*)uraw;   // 1.18 MB <= 2.1 MB
    unsigned short* Bmat  = (unsigned short*)dtb_;   // 9.44 MB <= dtb_+yb (16.8 MB)

    k_wt  <<<64,    256, 0, stream>>>(proj1_w, proj2_w, wtc);
    k_proj<<<2*256, 256, 0, stream>>>(x, wtc, proj1_b, proj2_b, sm, sv);

    for (int i = 0; i < 2; ++i){
        k_lnmm <<<2*1024, 256, 0, stream>>>(sm, m_ln_w + i*128, m_ln_b + i*128,
                                            m_in_w + (size_t)i*128*512, uraw, zb);
        k_mconv<<<2*1024, 256, 0, stream>>>(uraw, m_conv_w + (size_t)i*256*4, m_conv_b + i*256, uc);
        k_xproj<<<2*1024, 256, 0, stream>>>(uc, m_xproj_w + (size_t)i*256*40,
                                            m_dt_w + (size_t)i*8*256, m_dt_b + i*256,
                                            dtb_, Bmb, Cmb, 1);
        k_scanA<<<2*NCH, 256, 0, stream>>>(dtb_, uc, Bmb, m_Alog + (size_t)i*256*16, Pb, Qb, 1);
        k_scanP<<<2*16,  256, 0, stream>>>(Pb, Qb);
        k_scanB<<<2*NCH, 256, 0, stream>>>(dtb_, uc, Bmb, Cmb, m_Alog + (size_t)i*256*16,
                                           Pb, yb, 1);
        k_mout <<<2*1024, 256, 0, stream>>>(yb, uc, zb, m_D + i*256,
                                            m_out_w + (size_t)i*256*128, sm);
    }

    for (int i = 0; i < 2; ++i){
        k_lnmm <<<2*1024,   256, 0, stream>>>(sv, v_ln_w + i*128, v_ln_b + i*128,
                                              v_in_w + (size_t)i*128*512, uraw, zb);
        k_vconv<<<2*1024,   256, 0, stream>>>(uraw, v_conv_w + (size_t)i*256*9, v_conv_b + i*256, usb);
        k_xproj<<<2*4*1024, 256, 0, stream>>>(usb, v_xproj_w + (size_t)i*4*256*40,
                                              v_dt_w + (size_t)i*4*8*256, v_dt_b + (size_t)i*4*256,
                                              dtb_, Bmb, Cmb, 4);
        k_scanA<<<2*4*NCH, 256, 0, stream>>>(dtb_, usb, Bmb, v_Alog + (size_t)i*4*256*16,
                                             Pb, Qb, 4);
        k_scanP<<<2*4*16,  256, 0, stream>>>(Pb, Qb);
        k_scanB<<<2*4*NCH, 256, 0, stream>>>(dtb_, usb, Bmb, Cmb, v_Alog + (size_t)i*4*256*16,
                                             Pb, yb, 4);
        k_vcomb<<<2*1024,   256, 0, stream>>>(yb, usb, zb, v_D + (size_t)i*4*256,
                                              v_onorm_w + i*256, v_onorm_b + i*256,
                                              v_out_w + (size_t)i*256*128, sv);
    }

    k_wconv <<<576,     256, 0, stream>>>(fuse_w, Wbf);
    k_im2col<<<2*1024,  256, 0, stream>>>(sm, sv, Bmat);
    k_fgemm <<<4*32,    256, 0, stream>>>(Wbf, Bmat, fuse_b, bn_g, bn_b, bn_m, bn_v, out);
}

// Round 6
// 362.595 us; speedup vs baseline: 5.9500x; 1.0530x over previous
//
#include <hip/hip_runtime.h>
#include <math.h>

// Problem constants
// B=2, DIM=256, H=W=32, L=1024, HALF=128, DI=256, DS=16, DTR=8, DEPTH=2, K1=4
#define CH  16      // scan chunk length
#define NCH 64      // chunks per sequence (L / CH)

typedef __attribute__((ext_vector_type(8))) short bf16x8;
typedef __attribute__((ext_vector_type(4))) float f32x4;
typedef __attribute__((ext_vector_type(4))) unsigned int u32x4;

__device__ __forceinline__ float dev_silu(float x){ return x * (1.0f/(1.0f + __expf(-x))); }
__device__ __forceinline__ float dev_softplus(float x){ return fmaxf(x,0.0f) + log1pf(__expf(-fabsf(x))); }
__device__ __forceinline__ unsigned short dev_bf16(float f){
    unsigned int u = __float_as_uint(f);
    return (unsigned short)((u + 0x7fffu + ((u >> 16) & 1u)) >> 16);
}

// ---- transpose proj weights: wtc[c][o] ----
__global__ void __launch_bounds__(256)
k_wt(const float* __restrict__ w1, const float* __restrict__ w2, float* __restrict__ wtc)
{
    int bc = blockIdx.x;           // 8 o-tiles x 8 c-tiles
    int ot = bc & 7, ct = bc >> 3;
    __shared__ float t[32][33];
    int col = threadIdx.x & 31, r8 = threadIdx.x >> 5;
    #pragma unroll
    for (int i = 0; i < 4; ++i){
        int r = i*8 + r8;
        int o = ot*32 + r;
        const float* src = (o < 128) ? (w1 + (size_t)o*256) : (w2 + (size_t)(o-128)*256);
        t[r][col] = src[ct*32 + col];
    }
    __syncthreads();
    #pragma unroll
    for (int i = 0; i < 4; ++i){
        int r = i*8 + r8;
        int c = ct*32 + r, o = ot*32 + col;
        wtc[(size_t)c*256 + o] = t[col][r];
    }
}

// ---- proj: block per (b, 4-l tile); coalesced transposed-weight reads ----
__global__ void __launch_bounds__(256)
k_proj(const float* __restrict__ x, const float* __restrict__ wtc,
       const float* __restrict__ b1, const float* __restrict__ b2,
       float* __restrict__ sm, float* __restrict__ sv)
{
    int blk = blockIdx.x;          // b*256 + lt
    int b = blk >> 8, l0 = (blk & 255) * 4;
    int tid = threadIdx.x;
    __shared__ float4 xs[256];
    xs[tid] = *(const float4*)(x + ((size_t)(b*256 + tid))*1024 + l0);
    __syncthreads();
    int o = tid & 127;
    float bias = (tid < 128) ? b1[o] : b2[o];
    float a0 = bias, a1 = bias, a2 = bias, a3 = bias;
    #pragma unroll 4
    for (int c = 0; c < 256; ++c){
        float wv = wtc[(size_t)c*256 + tid];
        float4 xv = xs[c];
        a0 = fmaf(wv, xv.x, a0);
        a1 = fmaf(wv, xv.y, a1);
        a2 = fmaf(wv, xv.z, a2);
        a3 = fmaf(wv, xv.w, a3);
    }
    float* dst = (tid < 128) ? sm : sv;
    size_t base = ((size_t)b*1024 + l0)*128 + o;
    dst[base      ] = a0;
    dst[base + 128] = a1;
    dst[base + 256] = a2;
    dst[base + 384] = a3;
}

// ---- LN(128) + matmul (128->512), 8 rows per block; grid 256 ----
__global__ void __launch_bounds__(256)
k_lnmm(const float* __restrict__ s, const float* __restrict__ lnw, const float* __restrict__ lnb,
       const float* __restrict__ inw, float* __restrict__ u, float* __restrict__ z)
{
    int bl0 = blockIdx.x * 8;
    int tid = threadIdx.x;
    int row = tid >> 5, lane = tid & 31;
    __shared__ float hn[8][132];
    float4 v = *(const float4*)(s + (size_t)(bl0 + row)*128 + lane*4);
    float a = v.x + v.y + v.z + v.w;
    float q = v.x*v.x + v.y*v.y + v.z*v.z + v.w*v.w;
    #pragma unroll
    for (int o = 16; o; o >>= 1){ a += __shfl_xor(a, o); q += __shfl_xor(q, o); }
    float mean = a * (1.0f/128.0f);
    float rs = rsqrtf(q * (1.0f/128.0f) - mean*mean + 1e-5f);
    float4 w4 = *(const float4*)(lnw + lane*4);
    float4 b4 = *(const float4*)(lnb + lane*4);
    float4 hv;
    hv.x = (v.x-mean)*rs*w4.x + b4.x;
    hv.y = (v.y-mean)*rs*w4.y + b4.y;
    hv.z = (v.z-mean)*rs*w4.z + b4.z;
    hv.w = (v.w-mean)*rs*w4.w + b4.w;
    *(float4*)&hn[row][lane*4] = hv;
    __syncthreads();
    float acc0[8] = {0,0,0,0,0,0,0,0};
    float acc1[8] = {0,0,0,0,0,0,0,0};
    for (int c = 0; c < 128; c += 4){
        float w0[4], w1[4];
        #pragma unroll
        for (int i = 0; i < 4; ++i){
            w0[i] = inw[(size_t)(c+i)*512 + tid];
            w1[i] = inw[(size_t)(c+i)*512 + tid + 256];
        }
        #pragma unroll
        for (int r = 0; r < 8; ++r){
            float4 h4 = *(const float4*)&hn[r][c];
            acc0[r] = fmaf(h4.x, w0[0], acc0[r]);
            acc0[r] = fmaf(h4.y, w0[1], acc0[r]);
            acc0[r] = fmaf(h4.z, w0[2], acc0[r]);
            acc0[r] = fmaf(h4.w, w0[3], acc0[r]);
            acc1[r] = fmaf(h4.x, w1[0], acc1[r]);
            acc1[r] = fmaf(h4.y, w1[1], acc1[r]);
            acc1[r] = fmaf(h4.z, w1[2], acc1[r]);
            acc1[r] = fmaf(h4.w, w1[3], acc1[r]);
        }
    }
    #pragma unroll
    for (int r = 0; r < 8; ++r){
        u[(size_t)(bl0 + r)*256 + tid] = acc0[r];
        z[(size_t)(bl0 + r)*256 + tid] = acc1[r];
    }
}

// ---------------- mamba causal conv (K1=4) + silu ----------------
__global__ void __launch_bounds__(256)
k_mconv(const float* __restrict__ ur, const float* __restrict__ cw, const float* __restrict__ cb,
        float* __restrict__ uc)
{
    int bl = blockIdx.x; int b = bl >> 10, l = bl & 1023; int d = threadIdx.x;
    float acc = cb[d];
    #pragma unroll
    for (int k = 0; k < 4; ++k){
        int lp = l - 3 + k;
        if (lp >= 0) acc = fmaf(ur[((size_t)(b<<10) + lp)*256 + d], cw[d*4 + k], acc);
    }
    uc[(size_t)bl*256 + d] = dev_silu(acc);
}

// ---------------- vss depthwise 3x3 conv + silu + 4-direction scatter ----------------
__global__ void __launch_bounds__(256)
k_vconv(const float* __restrict__ ur, const float* __restrict__ cw, const float* __restrict__ cb,
        float* __restrict__ us)
{
    int bl = blockIdx.x; int b = bl >> 10, l = bl & 1023; int d = threadIdx.x;
    int h = l >> 5, w = l & 31;
    float acc = cb[d];
    #pragma unroll
    for (int kh = 0; kh < 3; ++kh){
        int hh = h + kh - 1; if (hh < 0 || hh > 31) continue;
        #pragma unroll
        for (int kw = 0; kw < 3; ++kw){
            int ww = w + kw - 1; if (ww < 0 || ww > 31) continue;
            acc = fmaf(ur[((size_t)(b<<10) + (hh<<5) + ww)*256 + d], cw[d*9 + kh*3 + kw], acc);
        }
    }
    float v = dev_silu(acc);
    int l1 = (w<<5) + h;   // column-major scan position
    size_t base = (size_t)b*4*1024*256;
    us[base + ((size_t)0*1024 + l        )*256 + d] = v;
    us[base + ((size_t)1*1024 + l1       )*256 + d] = v;
    us[base + ((size_t)2*1024 + (1023-l ))*256 + d] = v;
    us[base + ((size_t)3*1024 + (1023-l1))*256 + d] = v;
}

// ---- xproj: 4 l-positions per block; grid bk*256 ----
__global__ void __launch_bounds__(256)
k_xproj(const float* __restrict__ u, const float* __restrict__ xw, const float* __restrict__ dtw,
        const float* __restrict__ dtb, float* __restrict__ dt, float* __restrict__ Bm,
        float* __restrict__ Cm, int K)
{
    int blk = blockIdx.x;          // bk*256 + lt
    int bk = blk >> 8; int k = bk % K;
    int l0 = (blk & 255) * 4;
    size_t idx0 = (size_t)bk*1024 + l0;
    int tid = threadIdx.x;
    __shared__ float ursh[4][256];
    __shared__ float dbc[4][44];
    #pragma unroll
    for (int p = 0; p < 4; ++p)
        ursh[p][tid] = u[(idx0 + p)*256 + tid];
    __syncthreads();
    if (tid < 160){
        int r = tid % 40, p = tid / 40;
        const float* xwc = xw + (size_t)k*256*40 + r;
        float a0 = 0.f, a1 = 0.f;
        for (int c = 0; c < 128; ++c){
            a0 = fmaf(ursh[p][c],       xwc[(size_t)c*40],       a0);
            a1 = fmaf(ursh[p][c + 128], xwc[(size_t)(c+128)*40], a1);
        }
        dbc[p][r] = a0 + a1;
    }
    __syncthreads();
    const float* dtwk = dtw + (size_t)k*8*256;
    float bias = dtb[k*256 + tid];
    float wv[8];
    #pragma unroll
    for (int r = 0; r < 8; ++r) wv[r] = dtwk[r*256 + tid];
    #pragma unroll
    for (int p = 0; p < 4; ++p){
        float a = bias;
        #pragma unroll
        for (int r = 0; r < 8; ++r) a = fmaf(dbc[p][r], wv[r], a);
        dt[(idx0 + p)*256 + tid] = dev_softplus(a);
    }
    if (tid < 128){
        int p = tid >> 5, j = tid & 31;
        if (j < 16) Bm[(idx0 + p)*16 + j]        = dbc[p][8 + j];
        else        Cm[(idx0 + p)*16 + (j - 16)] = dbc[p][8 + j];   // dbc[24..39]
    }
}

// ------- scan pass A: per-chunk (P = exp(A*sum dt), Q = chunk-local h), thread per d -------
__global__ void __launch_bounds__(256)
k_scanA(const float* __restrict__ dt, const float* __restrict__ u, const float* __restrict__ Bm,
        const float* __restrict__ Alog, float* __restrict__ Pb, float* __restrict__ Qb, int K)
{
    int blk = blockIdx.x;            // bk*NCH + c
    int c = blk & (NCH-1); int bk = blk >> 6; int k = bk % K;
    int d = threadIdx.x;
    __shared__ float Bsh[CH][16];
    {
        int j = threadIdx.x >> 4, s = threadIdx.x & 15;
        Bsh[j][s] = Bm[((size_t)bk*1024 + c*CH + j)*16 + s];
    }
    float dtv[CH], duv[CH];
    size_t base = ((size_t)bk*1024 + c*CH)*256 + d;
    #pragma unroll
    for (int j = 0; j < CH; ++j){
        float a = dt[base + (size_t)j*256];
        float b = u [base + (size_t)j*256];
        dtv[j] = a; duv[j] = a*b;
    }
    float A[16];
    const float4* Ap = (const float4*)(Alog + ((size_t)k*256 + d)*16);
    #pragma unroll
    for (int q = 0; q < 4; ++q){
        float4 v = Ap[q];
        A[q*4+0] = -__expf(v.x); A[q*4+1] = -__expf(v.y);
        A[q*4+2] = -__expf(v.z); A[q*4+3] = -__expf(v.w);
    }
    __syncthreads();
    float Q[16];
    #pragma unroll
    for (int s = 0; s < 16; ++s) Q[s] = 0.f;
    float S = 0.f;
    #pragma unroll
    for (int j = 0; j < CH; ++j){
        S += dtv[j];
        #pragma unroll
        for (int s = 0; s < 16; ++s){
            float av = __expf(dtv[j]*A[s]);
            Q[s] = fmaf(av, Q[s], duv[j]*Bsh[j][s]);
        }
    }
    float4* Pp = (float4*)(Pb + ((size_t)blk*256 + d)*16);
    float4* Qp = (float4*)(Qb + ((size_t)blk*256 + d)*16);
    #pragma unroll
    for (int q = 0; q < 4; ++q){
        float4 pv, qv;
        pv.x = __expf(S*A[q*4+0]); pv.y = __expf(S*A[q*4+1]);
        pv.z = __expf(S*A[q*4+2]); pv.w = __expf(S*A[q*4+3]);
        qv.x = Q[q*4+0]; qv.y = Q[q*4+1]; qv.z = Q[q*4+2]; qv.w = Q[q*4+3];
        Pp[q] = pv; Qp[q] = qv;
    }
}

// ------- scan pass P: exclusive prefix over NCH chunks per (bk,d,s); H overwrites P -------
__global__ void __launch_bounds__(256)
k_scanP(float* __restrict__ Pb, const float* __restrict__ Qb)
{
    int bk = blockIdx.x >> 4;
    int dg = blockIdx.x & 15;       // group of 16 d
    int tid = threadIdx.x;          // dl*16 + s
    size_t idx0 = (size_t)bk*NCH*4096 + dg*256 + tid;
    float Pv[NCH], Qv[NCH];
    #pragma unroll
    for (int c = 0; c < NCH; ++c){
        Pv[c] = Pb[idx0 + (size_t)c*4096];
        Qv[c] = Qb[idx0 + (size_t)c*4096];
    }
    float h = 0.f;
    #pragma unroll
    for (int c = 0; c < NCH; ++c){
        Pb[idx0 + (size_t)c*4096] = h;      // h_in for chunk c
        h = fmaf(Pv[c], h, Qv[c]);
    }
}

// ------- scan pass B: replay chunk with h_in; y[l,d] = sum_s h*C; thread per d -------
__global__ void __launch_bounds__(256)
k_scanB(const float* __restrict__ dt, const float* __restrict__ u, const float* __restrict__ Bm,
        const float* __restrict__ Cm, const float* __restrict__ Alog,
        const float* __restrict__ Hb, float* __restrict__ y, int K)
{
    int blk = blockIdx.x;            // bk*NCH + c
    int c = blk & (NCH-1); int bk = blk >> 6; int k = bk % K;
    int d = threadIdx.x;
    __shared__ float Bsh[CH][16], Csh[CH][16];
    {
        int j = threadIdx.x >> 4, s = threadIdx.x & 15;
        size_t bi = ((size_t)bk*1024 + c*CH + j)*16 + s;
        Bsh[j][s] = Bm[bi];
        Csh[j][s] = Cm[bi];
    }
    float dtv[CH], duv[CH];
    size_t base = ((size_t)bk*1024 + c*CH)*256 + d;
    #pragma unroll
    for (int j = 0; j < CH; ++j){
        float a = dt[base + (size_t)j*256];
        float b = u [base + (size_t)j*256];
        dtv[j] = a; duv[j] = a*b;
    }
    float A[16];
    const float4* Ap = (const float4*)(Alog + ((size_t)k*256 + d)*16);
    #pragma unroll
    for (int q = 0; q < 4; ++q){
        float4 v = Ap[q];
        A[q*4+0] = -__expf(v.x); A[q*4+1] = -__expf(v.y);
        A[q*4+2] = -__expf(v.z); A[q*4+3] = -__expf(v.w);
    }
    float h[16];
    const float4* Hp = (const float4*)(Hb + ((size_t)blk*256 + d)*16);
    #pragma unroll
    for (int q = 0; q < 4; ++q){
        float4 v = Hp[q];
        h[q*4+0] = v.x; h[q*4+1] = v.y; h[q*4+2] = v.z; h[q*4+3] = v.w;
    }
    __syncthreads();
    float* yp = y + base;
    #pragma unroll
    for (int j = 0; j < CH; ++j){
        float py = 0.f;
        #pragma unroll
        for (int s = 0; s < 16; ++s){
            float av = __expf(dtv[j]*A[s]);
            h[s] = fmaf(av, h[s], duv[j]*Bsh[j][s]);
            py = fmaf(h[s], Csh[j][s], py);
        }
        yp[(size_t)j*256] = py;
    }
}

// ---- mamba epilogue: (y + u*D) * silu(z) @ ow -> sm += ; 8 rows per block; grid 256 ----
__global__ void __launch_bounds__(256)
k_mout(const float* __restrict__ y, const float* __restrict__ uc, const float* __restrict__ z,
       const float* __restrict__ Dp, const float* __restrict__ ow, float* __restrict__ sm)
{
    int bl0 = blockIdx.x * 8;
    int tid = threadIdx.x;
    int row = tid >> 5, c0 = (tid & 31) * 8;
    __shared__ float gld[8][264];
    size_t base = (size_t)(bl0 + row)*256 + c0;
    #pragma unroll
    for (int i = 0; i < 8; i += 4){
        float4 yv = *(const float4*)(y + base + i);
        float4 uv = *(const float4*)(uc + base + i);
        float4 zv = *(const float4*)(z + base + i);
        float4 dv = *(const float4*)(Dp + c0 + i);
        gld[row][c0+i+0] = (yv.x + uv.x*dv.x) * dev_silu(zv.x);
        gld[row][c0+i+1] = (yv.y + uv.y*dv.y) * dev_silu(zv.y);
        gld[row][c0+i+2] = (yv.z + uv.z*dv.z) * dev_silu(zv.z);
        gld[row][c0+i+3] = (yv.w + uv.w*dv.w) * dev_silu(zv.w);
    }
    __syncthreads();
    int o = tid & 127, rg = tid >> 7;
    float acc[4] = {0,0,0,0};
    for (int c = 0; c < 256; c += 4){
        float w[4];
        #pragma unroll
        for (int i = 0; i < 4; ++i) w[i] = ow[(size_t)(c+i)*128 + o];
        #pragma unroll
        for (int r = 0; r < 4; ++r){
            float4 h4 = *(const float4*)&gld[rg*4 + r][c];
            acc[r] = fmaf(h4.x, w[0], acc[r]);
            acc[r] = fmaf(h4.y, w[1], acc[r]);
            acc[r] = fmaf(h4.z, w[2], acc[r]);
            acc[r] = fmaf(h4.w, w[3], acc[r]);
        }
    }
    #pragma unroll
    for (int r = 0; r < 4; ++r)
        sm[(size_t)(bl0 + rg*4 + r)*128 + o] += acc[r];
}

// ---- vss epilogue: gather 4 dirs (+us*D), LN(256), *silu(z), @ ow -> sv += ; 8 rows/block ----
__global__ void __launch_bounds__(256)
k_vcomb(const float* __restrict__ y, const float* __restrict__ us, const float* __restrict__ z,
        const float* __restrict__ Dp, const float* __restrict__ onw, const float* __restrict__ onb,
        const float* __restrict__ ow, float* __restrict__ sv)
{
    int blk = blockIdx.x;           // b*128 + lt
    int b = blk >> 7;
    int l0 = (blk & 127) * 8;
    int tid = threadIdx.x;
    int row = tid >> 5, c0 = (tid & 31) * 8;
    int l = l0 + row;
    int h = l >> 5, w = l & 31;
    int l1 = (w<<5) + h, l2 = 1023 - l, l3 = 1023 - l1;
    size_t base = (size_t)b*4*1024*256;
    size_t i0 = base + ((size_t)0*1024 + l )*256 + c0;
    size_t i1 = base + ((size_t)1*1024 + l1)*256 + c0;
    size_t i2 = base + ((size_t)2*1024 + l2)*256 + c0;
    size_t i3 = base + ((size_t)3*1024 + l3)*256 + c0;
    float t[8];
    #pragma unroll
    for (int i = 0; i < 8; i += 4){
        float4 yv = *(const float4*)(y + i0 + i);
        float4 uv = *(const float4*)(us + i0 + i);
        float4 dv = *(const float4*)(Dp + 0*256 + c0 + i);
        t[i+0] = yv.x + uv.x*dv.x; t[i+1] = yv.y + uv.y*dv.y;
        t[i+2] = yv.z + uv.z*dv.z; t[i+3] = yv.w + uv.w*dv.w;
    }
    #pragma unroll
    for (int i = 0; i < 8; i += 4){
        float4 yv = *(const float4*)(y + i1 + i);
        float4 uv = *(const float4*)(us + i1 + i);
        float4 dv = *(const float4*)(Dp + 1*256 + c0 + i);
        t[i+0] += yv.x + uv.x*dv.x; t[i+1] += yv.y + uv.y*dv.y;
        t[i+2] += yv.z + uv.z*dv.z; t[i+3] += yv.w + uv.w*dv.w;
    }
    #pragma unroll
    for (int i = 0; i < 8; i += 4){
        float4 yv = *(const float4*)(y + i2 + i);
        float4 uv = *(const float4*)(us + i2 + i);
        float4 dv = *(const float4*)(Dp + 2*256 + c0 + i);
        t[i+0] += yv.x + uv.x*dv.x; t[i+1] += yv.y + uv.y*dv.y;
        t[i+2] += yv.z + uv.z*dv.z; t[i+3] += yv.w + uv.w*dv.w;
    }
    #pragma unroll
    for (int i = 0; i < 8; i += 4){
        float4 yv = *(const float4*)(y + i3 + i);
        float4 uv = *(const float4*)(us + i3 + i);
        float4 dv = *(const float4*)(Dp + 3*256 + c0 + i);
        t[i+0] += yv.x + uv.x*dv.x; t[i+1] += yv.y + uv.y*dv.y;
        t[i+2] += yv.z + uv.z*dv.z; t[i+3] += yv.w + uv.w*dv.w;
    }
    float a = 0.f, q = 0.f;
    #pragma unroll
    for (int i = 0; i < 8; ++i){ a += t[i]; q += t[i]*t[i]; }
    #pragma unroll
    for (int o = 16; o; o >>= 1){ a += __shfl_xor(a, o); q += __shfl_xor(q, o); }
    float mean = a * (1.0f/256.0f);
    float rs = rsqrtf(q * (1.0f/256.0f) - mean*mean + 1e-5f);
    __shared__ float gld[8][264];
    size_t zbase = (size_t)(b*1024 + l)*256 + c0;
    #pragma unroll
    for (int i = 0; i < 8; i += 4){
        float4 wv = *(const float4*)(onw + c0 + i);
        float4 bv = *(const float4*)(onb + c0 + i);
        float4 zv = *(const float4*)(z + zbase + i);
        gld[row][c0+i+0] = ((t[i+0]-mean)*rs*wv.x + bv.x) * dev_silu(zv.x);
        gld[row][c0+i+1] = ((t[i+1]-mean)*rs*wv.y + bv.y) * dev_silu(zv.y);
        gld[row][c0+i+2] = ((t[i+2]-mean)*rs*wv.z + bv.z) * dev_silu(zv.z);
        gld[row][c0+i+3] = ((t[i+3]-mean)*rs*wv.w + bv.w) * dev_silu(zv.w);
    }
    __syncthreads();
    int o = tid & 127, rg = tid >> 7;
    float acc[4] = {0,0,0,0};
    for (int c = 0; c < 256; c += 4){
        float wv[4];
        #pragma unroll
        for (int i = 0; i < 4; ++i) wv[i] = ow[(size_t)(c+i)*128 + o];
        #pragma unroll
        for (int r = 0; r < 4; ++r){
            float4 h4 = *(const float4*)&gld[rg*4 + r][c];
            acc[r] = fmaf(h4.x, wv[0], acc[r]);
            acc[r] = fmaf(h4.y, wv[1], acc[r]);
            acc[r] = fmaf(h4.z, wv[2], acc[r]);
            acc[r] = fmaf(h4.w, wv[3], acc[r]);
        }
    }
    #pragma unroll
    for (int r = 0; r < 4; ++r)
        sv[(size_t)(b*1024 + l0 + rg*4 + r)*128 + o] += acc[r];
}

// ---------------- fuse conv as implicit GEMM: weight cast to bf16 ----------------
__global__ void __launch_bounds__(256)
k_wconv(const float* __restrict__ fw, unsigned short* __restrict__ Wb)
{
    int idx = (blockIdx.x*256 + threadIdx.x)*4;      // 589824 = 576*1024
    float4 v = *(const float4*)(fw + idx);
    unsigned int r0 = dev_bf16(v.x), r1 = dev_bf16(v.y), r2 = dev_bf16(v.z), r3 = dev_bf16(v.w);
    uint2 pk; pk.x = r0 | (r1 << 16); pk.y = r2 | (r3 << 16);
    *(uint2*)(Wb + idx) = pk;
}

// ---- im2col (zero-pad folded): Bt[n=b*1024+p][k=c*9+kh*3+kw] bf16, from sm/sv ----
__global__ void __launch_bounds__(256)
k_im2col(const float* __restrict__ sm, const float* __restrict__ sv,
         unsigned short* __restrict__ Bt)
{
    int n = blockIdx.x; int b = n >> 10, p = n & 1023;
    int h = p >> 5, w = p & 31;
    int tid = threadIdx.x;
    #pragma unroll
    for (int it = 0; it < 9; ++it){                  // 9*256 = 2304 = K exactly
        int k = it*256 + tid;
        int c = k / 9, r = k - c*9;
        int kh = r / 3, kw = r - kh*3;
        int hh = h + kh - 1, ww = w + kw - 1;
        float v = 0.f;
        if (hh >= 0 && hh < 32 && ww >= 0 && ww < 32){
            int l = (hh << 5) + ww;
            v = (c < 128) ? sm[((size_t)b*1024 + l)*128 + c]
                          : sv[((size_t)b*1024 + l)*128 + (c - 128)];
        }
        Bt[(size_t)n*2304 + k] = dev_bf16(v);
    }
}

// ---- bf16 MFMA GEMM: out[o][n] = W[o][:]·Bt[n][:], + bias + BN + ReLU ----
__global__ void __launch_bounds__(256)
k_fgemm(const unsigned short* __restrict__ Wb, const unsigned short* __restrict__ Bt,
        const float* __restrict__ fb, const float* __restrict__ bg, const float* __restrict__ bb,
        const float* __restrict__ bm, const float* __restrict__ bv, float* __restrict__ out)
{
    int o0 = (blockIdx.x & 3) * 64;
    int n0 = (blockIdx.x >> 2) * 64;
    int tid = threadIdx.x, lane = tid & 63, wid = tid >> 6;
    int wm = (wid >> 1) * 32, wn = (wid & 1) * 32;
    __shared__ unsigned short sA[64*40];   // rows padded to 80B (bank-even)
    __shared__ unsigned short sB[64*40];
    f32x4 acc[2][2] = {};
    int srow = tid >> 2, scol = (tid & 3) * 8;
    const u32x4* gA = (const u32x4*)(Wb + (size_t)(o0 + srow)*2304 + scol);
    const u32x4* gB = (const u32x4*)(Bt + (size_t)(n0 + srow)*2304 + scol);
    u32x4* wA = (u32x4*)(sA + srow*40 + scol);
    u32x4* wB = (u32x4*)(sB + srow*40 + scol);
    int fr = lane & 15, fk = (lane >> 4) * 8;
    const unsigned short* rA0 = sA + (wm + fr)*40 + fk;
    const unsigned short* rA1 = sA + (wm + 16 + fr)*40 + fk;
    const unsigned short* rB0 = sB + (wn + fr)*40 + fk;
    const unsigned short* rB1 = sB + (wn + 16 + fr)*40 + fk;
    for (int kt = 0; kt < 72; ++kt){
        u32x4 va = gA[kt*4];            // k advances 32 shorts = 4x16B
        u32x4 vb = gB[kt*4];
        __syncthreads();
        *wA = va; *wB = vb;
        __syncthreads();
        bf16x8 a0 = *(const bf16x8*)rA0;
        bf16x8 a1 = *(const bf16x8*)rA1;
        bf16x8 b0 = *(const bf16x8*)rB0;
        bf16x8 b1 = *(const bf16x8*)rB1;
        acc[0][0] = __builtin_amdgcn_mfma_f32_16x16x32_bf16(a0, b0, acc[0][0], 0, 0, 0);
        acc[0][1] = __builtin_amdgcn_mfma_f32_16x16x32_bf16(a0, b1, acc[0][1], 0, 0, 0);
        acc[1][0] = __builtin_amdgcn_mfma_f32_16x16x32_bf16(a1, b0, acc[1][0], 0, 0, 0);
        acc[1][1] = __builtin_amdgcn_mfma_f32_16x16x32_bf16(a1, b1, acc[1][1], 0, 0, 0);
    }
    #pragma unroll
    for (int i = 0; i < 2; ++i){
        int ob = o0 + wm + i*16 + (lane >> 4) * 4;
        #pragma unroll
        for (int j = 0; j < 2; ++j){
            int n = n0 + wn + j*16 + (lane & 15);
            int b = n >> 10, p = n & 1023;
            #pragma unroll
            for (int q = 0; q < 4; ++q){
                int o = ob + q;
                float v = acc[i][j][q] + fb[o];
                v = (v - bm[o]) * rsqrtf(bv[o] + 1e-5f) * bg[o] + bb[o];
                out[((size_t)(b*256 + o))*1024 + p] = fmaxf(v, 0.f);
            }
        }
    }
}

extern "C" void kernel_launch(void* const* d_in, const int* in_sizes, int n_in,
                              void* d_out, int out_size, void* d_ws, size_t ws_size,
                              hipStream_t stream)
{
    const float* x         = (const float*)d_in[0];
    const float* proj1_w   = (const float*)d_in[1];
    const float* proj1_b   = (const float*)d_in[2];
    const float* proj2_w   = (const float*)d_in[3];
    const float* proj2_b   = (const float*)d_in[4];
    const float* m_ln_w    = (const float*)d_in[5];
    const float* m_ln_b    = (const float*)d_in[6];
    const float* m_in_w    = (const float*)d_in[7];
    const float* m_conv_w  = (const float*)d_in[8];
    const float* m_conv_b  = (const float*)d_in[9];
    const float* m_xproj_w = (const float*)d_in[10];
    const float* m_dt_w    = (const float*)d_in[11];
    const float* m_dt_b    = (const float*)d_in[12];
    const float* m_Alog    = (const float*)d_in[13];
    const float* m_D       = (const float*)d_in[14];
    const float* m_out_w   = (const float*)d_in[15];
    const float* v_ln_w    = (const float*)d_in[16];
    const float* v_ln_b    = (const float*)d_in[17];
    const float* v_in_w    = (const float*)d_in[18];
    const float* v_conv_w  = (const float*)d_in[19];
    const float* v_conv_b  = (const float*)d_in[20];
    const float* v_xproj_w = (const float*)d_in[21];
    const float* v_dt_w    = (const float*)d_in[22];
    const float* v_dt_b    = (const float*)d_in[23];
    const float* v_Alog    = (const float*)d_in[24];
    const float* v_D       = (const float*)d_in[25];
    const float* v_onorm_w = (const float*)d_in[26];
    const float* v_onorm_b = (const float*)d_in[27];
    const float* v_out_w   = (const float*)d_in[28];
    const float* fuse_w    = (const float*)d_in[29];
    const float* fuse_b    = (const float*)d_in[30];
    const float* bn_g      = (const float*)d_in[31];
    const float* bn_b      = (const float*)d_in[32];
    const float* bn_m      = (const float*)d_in[33];
    const float* bn_v      = (const float*)d_in[34];
    float* out = (float*)d_out;

    float* ws = (float*)d_ws;
    float* sm    = ws;  ws += 2*1024*128;      // (B,L,128) mamba state
    float* sv    = ws;  ws += 2*1024*128;      // (B,L,128) vss state
    float* uraw  = ws;  ws += 2*1024*256;      // pre-conv u
    float* zb    = ws;  ws += 2*1024*256;      // z
    float* uc    = ws;  ws += 2*1024*256;      // mamba post-conv u
    float* usb   = ws;  ws += 2*4*1024*256;    // vss 4-direction sequences
    float* dtb_  = ws;  ws += 2*4*1024*256;    // dt (B,K,L,D)
    float* yb    = ws;  ws += 2*4*1024*256;    // scan output (B,K,L,D)
    float* Pb    = ws;  ws += 2*4*NCH*256*16;  // chunk products (then h_in, in place)
    float* Qb    = ws;  ws += 2*4*NCH*256*16;  // chunk-local states
    float* Bmb   = ws;  ws += 2*4*1024*16;
    float* Cmb   = ws;  ws += 2*4*1024*16;
    float* wtc   = ws;  ws += 256*256;         // transposed proj weights [c][o]
    // aliases (only live after both path loops finish):
    unsigned short* Wbf   = (unsigned short*)uraw;   // 1.18 MB <= 2.1 MB
    unsigned short* Bmat  = (unsigned short*)dtb_;   // 9.44 MB <= dtb_+yb (16.8 MB)

    k_wt  <<<64,    256, 0, stream>>>(proj1_w, proj2_w, wtc);
    k_proj<<<2*256, 256, 0, stream>>>(x, wtc, proj1_b, proj2_b, sm, sv);

    for (int i = 0; i < 2; ++i){
        k_lnmm <<<256,    256, 0, stream>>>(sm, m_ln_w + i*128, m_ln_b + i*128,
                                            m_in_w + (size_t)i*128*512, uraw, zb);
        k_mconv<<<2*1024, 256, 0, stream>>>(uraw, m_conv_w + (size_t)i*256*4, m_conv_b + i*256, uc);
        k_xproj<<<2*256,  256, 0, stream>>>(uc, m_xproj_w + (size_t)i*256*40,
                                            m_dt_w + (size_t)i*8*256, m_dt_b + i*256,
                                            dtb_, Bmb, Cmb, 1);
        k_scanA<<<2*NCH, 256, 0, stream>>>(dtb_, uc, Bmb, m_Alog + (size_t)i*256*16, Pb, Qb, 1);
        k_scanP<<<2*16,  256, 0, stream>>>(Pb, Qb);
        k_scanB<<<2*NCH, 256, 0, stream>>>(dtb_, uc, Bmb, Cmb, m_Alog + (size_t)i*256*16,
                                           Pb, yb, 1);
        k_mout <<<256,   256, 0, stream>>>(yb, uc, zb, m_D + i*256,
                                           m_out_w + (size_t)i*256*128, sm);
    }

    for (int i = 0; i < 2; ++i){
        k_lnmm <<<256,      256, 0, stream>>>(sv, v_ln_w + i*128, v_ln_b + i*128,
                                              v_in_w + (size_t)i*128*512, uraw, zb);
        k_vconv<<<2*1024,   256, 0, stream>>>(uraw, v_conv_w + (size_t)i*256*9, v_conv_b + i*256, usb);
        k_xproj<<<2*4*256,  256, 0, stream>>>(usb, v_xproj_w + (size_t)i*4*256*40,
                                              v_dt_w + (size_t)i*4*8*256, v_dt_b + (size_t)i*4*256,
                                              dtb_, Bmb, Cmb, 4);
        k_scanA<<<2*4*NCH, 256, 0, stream>>>(dtb_, usb, Bmb, v_Alog + (size_t)i*4*256*16,
                                             Pb, Qb, 4);
        k_scanP<<<2*4*16,  256, 0, stream>>>(Pb, Qb);
        k_scanB<<<2*4*NCH, 256, 0, stream>>>(dtb_, usb, Bmb, Cmb, v_Alog + (size_t)i*4*256*16,
                                             Pb, yb, 4);
        k_vcomb<<<256,      256, 0, stream>>>(yb, usb, zb, v_D + (size_t)i*4*256,
                                              v_onorm_w + i*256, v_onorm_b + i*256,
                                              v_out_w + (size_t)i*256*128, sv);
    }

    k_wconv <<<576,     256, 0, stream>>>(fuse_w, Wbf);
    k_im2col<<<2*1024,  256, 0, stream>>>(sm, sv, Bmat);
    k_fgemm <<<4*32,    256, 0, stream>>>(Wbf, Bmat, fuse_b, bn_g, bn_b, bn_m, bn_v, out);
}

// Round 7
// 297.057 us; speedup vs baseline: 7.2627x; 1.2206x over previous
//
#include <hip/hip_runtime.h>
#include <math.h>

// Problem constants
// B=2, DIM=256, H=W=32, L=1024, HALF=128, DI=256, DS=16, DTR=8, DEPTH=2, K1=4
#define CH  16      // scan chunk length
#define NCH 64      // chunks per sequence (L / CH)

typedef __attribute__((ext_vector_type(8))) short bf16x8;
typedef __attribute__((ext_vector_type(4))) float f32x4;
typedef __attribute__((ext_vector_type(4))) unsigned int u32x4;

__device__ __forceinline__ float dev_silu(float x){ return x * (1.0f/(1.0f + __expf(-x))); }
__device__ __forceinline__ float dev_softplus(float x){ return fmaxf(x,0.0f) + log1pf(__expf(-fabsf(x))); }
__device__ __forceinline__ unsigned short dev_bf16(float f){
    unsigned int u = __float_as_uint(f);
    return (unsigned short)((u + 0x7fffu + ((u >> 16) & 1u)) >> 16);
}

// ================= prep: proj-weight transpose (blocks 0-63) + fuse-weight bf16 (64-639) ====
__global__ void __launch_bounds__(256)
k_prep(const float* __restrict__ w1, const float* __restrict__ w2, float* __restrict__ wtc,
       const float* __restrict__ fw, unsigned short* __restrict__ Wb)
{
    if (blockIdx.x < 64){
        int bc = blockIdx.x;           // 8 o-tiles x 8 c-tiles
        int ot = bc & 7, ct = bc >> 3;
        __shared__ float t[32][33];
        int col = threadIdx.x & 31, r8 = threadIdx.x >> 5;
        #pragma unroll
        for (int i = 0; i < 4; ++i){
            int r = i*8 + r8;
            int o = ot*32 + r;
            const float* src = (o < 128) ? (w1 + (size_t)o*256) : (w2 + (size_t)(o-128)*256);
            t[r][col] = src[ct*32 + col];
        }
        __syncthreads();
        #pragma unroll
        for (int i = 0; i < 4; ++i){
            int r = i*8 + r8;
            int c = ct*32 + r, o = ot*32 + col;
            wtc[(size_t)c*256 + o] = t[col][r];
        }
    } else {
        int idx = ((blockIdx.x - 64)*256 + threadIdx.x)*4;   // 576*1024 elements
        float4 v = *(const float4*)(fw + idx);
        unsigned int r0 = dev_bf16(v.x), r1 = dev_bf16(v.y), r2 = dev_bf16(v.z), r3 = dev_bf16(v.w);
        uint2 pk; pk.x = r0 | (r1 << 16); pk.y = r2 | (r3 << 16);
        *(uint2*)(Wb + idx) = pk;
    }
}

// ---- proj: block per (b, 4-l tile); coalesced transposed-weight reads ----
__global__ void __launch_bounds__(256)
k_proj(const float* __restrict__ x, const float* __restrict__ wtc,
       const float* __restrict__ b1, const float* __restrict__ b2,
       float* __restrict__ sm, float* __restrict__ sv)
{
    int blk = blockIdx.x;          // b*256 + lt
    int b = blk >> 8, l0 = (blk & 255) * 4;
    int tid = threadIdx.x;
    __shared__ float4 xs[256];
    xs[tid] = *(const float4*)(x + ((size_t)(b*256 + tid))*1024 + l0);
    __syncthreads();
    int o = tid & 127;
    float bias = (tid < 128) ? b1[o] : b2[o];
    float a0 = bias, a1 = bias, a2 = bias, a3 = bias;
    #pragma unroll 4
    for (int c = 0; c < 256; ++c){
        float wv = wtc[(size_t)c*256 + tid];
        float4 xv = xs[c];
        a0 = fmaf(wv, xv.x, a0);
        a1 = fmaf(wv, xv.y, a1);
        a2 = fmaf(wv, xv.z, a2);
        a3 = fmaf(wv, xv.w, a3);
    }
    float* dst = (tid < 128) ? sm : sv;
    size_t base = ((size_t)b*1024 + l0)*128 + o;
    dst[base      ] = a0;
    dst[base + 128] = a1;
    dst[base + 256] = a2;
    dst[base + 384] = a3;
}

// ================= LN(128) + matmul (128->512), 8 rows per block =================
__device__ __forceinline__ void lnmm_body(int bl0, const float* __restrict__ s,
    const float* __restrict__ lnw, const float* __restrict__ lnb,
    const float* __restrict__ inw, float* __restrict__ u, float* __restrict__ z)
{
    int tid = threadIdx.x;
    int row = tid >> 5, lane = tid & 31;
    __shared__ float hn[8][132];
    float4 v = *(const float4*)(s + (size_t)(bl0 + row)*128 + lane*4);
    float a = v.x + v.y + v.z + v.w;
    float q = v.x*v.x + v.y*v.y + v.z*v.z + v.w*v.w;
    #pragma unroll
    for (int o = 16; o; o >>= 1){ a += __shfl_xor(a, o); q += __shfl_xor(q, o); }
    float mean = a * (1.0f/128.0f);
    float rs = rsqrtf(q * (1.0f/128.0f) - mean*mean + 1e-5f);
    float4 w4 = *(const float4*)(lnw + lane*4);
    float4 b4 = *(const float4*)(lnb + lane*4);
    float4 hv;
    hv.x = (v.x-mean)*rs*w4.x + b4.x;
    hv.y = (v.y-mean)*rs*w4.y + b4.y;
    hv.z = (v.z-mean)*rs*w4.z + b4.z;
    hv.w = (v.w-mean)*rs*w4.w + b4.w;
    *(float4*)&hn[row][lane*4] = hv;
    __syncthreads();
    float acc0[8] = {0,0,0,0,0,0,0,0};
    float acc1[8] = {0,0,0,0,0,0,0,0};
    for (int c = 0; c < 128; c += 4){
        float w0[4], w1[4];
        #pragma unroll
        for (int i = 0; i < 4; ++i){
            w0[i] = inw[(size_t)(c+i)*512 + tid];
            w1[i] = inw[(size_t)(c+i)*512 + tid + 256];
        }
        #pragma unroll
        for (int r = 0; r < 8; ++r){
            float4 h4 = *(const float4*)&hn[r][c];
            acc0[r] = fmaf(h4.x, w0[0], acc0[r]);
            acc0[r] = fmaf(h4.y, w0[1], acc0[r]);
            acc0[r] = fmaf(h4.z, w0[2], acc0[r]);
            acc0[r] = fmaf(h4.w, w0[3], acc0[r]);
            acc1[r] = fmaf(h4.x, w1[0], acc1[r]);
            acc1[r] = fmaf(h4.y, w1[1], acc1[r]);
            acc1[r] = fmaf(h4.z, w1[2], acc1[r]);
            acc1[r] = fmaf(h4.w, w1[3], acc1[r]);
        }
    }
    #pragma unroll
    for (int r = 0; r < 8; ++r){
        u[(size_t)(bl0 + r)*256 + tid] = acc0[r];
        z[(size_t)(bl0 + r)*256 + tid] = acc1[r];
    }
}

__global__ void __launch_bounds__(256)
k_lnmm2(const float* __restrict__ sm_, const float* __restrict__ mlnw, const float* __restrict__ mlnb,
        const float* __restrict__ minw, float* __restrict__ um, float* __restrict__ zm,
        const float* __restrict__ sv_, const float* __restrict__ vlnw, const float* __restrict__ vlnb,
        const float* __restrict__ vinw, float* __restrict__ uv, float* __restrict__ zv)
{
    if (blockIdx.x < 256) lnmm_body(blockIdx.x*8, sm_, mlnw, mlnb, minw, um, zm);
    else                  lnmm_body((blockIdx.x-256)*8, sv_, vlnw, vlnb, vinw, uv, zv);
}

// ================= conv: mamba causal K=4 (blocks 0-2047) + vss dw3x3+scatter =================
__global__ void __launch_bounds__(256)
k_conv2(const float* __restrict__ urm, const float* __restrict__ cwm, const float* __restrict__ cbm,
        float* __restrict__ uc,
        const float* __restrict__ urv, const float* __restrict__ cwv, const float* __restrict__ cbv,
        float* __restrict__ us)
{
    int d = threadIdx.x;
    if (blockIdx.x < 2048){
        int bl = blockIdx.x; int b = bl >> 10, l = bl & 1023;
        float acc = cbm[d];
        #pragma unroll
        for (int k = 0; k < 4; ++k){
            int lp = l - 3 + k;
            if (lp >= 0) acc = fmaf(urm[((size_t)(b<<10) + lp)*256 + d], cwm[d*4 + k], acc);
        }
        uc[(size_t)bl*256 + d] = dev_silu(acc);
    } else {
        int bl = blockIdx.x - 2048; int b = bl >> 10, l = bl & 1023;
        int h = l >> 5, w = l & 31;
        float acc = cbv[d];
        #pragma unroll
        for (int kh = 0; kh < 3; ++kh){
            int hh = h + kh - 1; if (hh < 0 || hh > 31) continue;
            #pragma unroll
            for (int kw = 0; kw < 3; ++kw){
                int ww = w + kw - 1; if (ww < 0 || ww > 31) continue;
                acc = fmaf(urv[((size_t)(b<<10) + (hh<<5) + ww)*256 + d], cwv[d*9 + kh*3 + kw], acc);
            }
        }
        float v = dev_silu(acc);
        int l1 = (w<<5) + h;
        size_t base = (size_t)b*4*1024*256;
        us[base + ((size_t)0*1024 + l        )*256 + d] = v;
        us[base + ((size_t)1*1024 + l1       )*256 + d] = v;
        us[base + ((size_t)2*1024 + (1023-l ))*256 + d] = v;
        us[base + ((size_t)3*1024 + (1023-l1))*256 + d] = v;
    }
}

// ================= xproj: 4 l-positions per block =================
__device__ __forceinline__ void xproj_body(size_t idx0, int k, const float* __restrict__ u,
    const float* __restrict__ xw, const float* __restrict__ dtw, const float* __restrict__ dtb,
    float* __restrict__ dt, float* __restrict__ Bm, float* __restrict__ Cm)
{
    int tid = threadIdx.x;
    __shared__ float ursh[4][256];
    __shared__ float dbc[4][44];
    #pragma unroll
    for (int p = 0; p < 4; ++p)
        ursh[p][tid] = u[(idx0 + p)*256 + tid];
    __syncthreads();
    if (tid < 160){
        int r = tid % 40, p = tid / 40;
        const float* xwc = xw + (size_t)k*256*40 + r;
        float a0 = 0.f, a1 = 0.f;
        for (int c = 0; c < 128; ++c){
            a0 = fmaf(ursh[p][c],       xwc[(size_t)c*40],       a0);
            a1 = fmaf(ursh[p][c + 128], xwc[(size_t)(c+128)*40], a1);
        }
        dbc[p][r] = a0 + a1;
    }
    __syncthreads();
    const float* dtwk = dtw + (size_t)k*8*256;
    float bias = dtb[k*256 + tid];
    float wv[8];
    #pragma unroll
    for (int r = 0; r < 8; ++r) wv[r] = dtwk[r*256 + tid];
    #pragma unroll
    for (int p = 0; p < 4; ++p){
        float a = bias;
        #pragma unroll
        for (int r = 0; r < 8; ++r) a = fmaf(dbc[p][r], wv[r], a);
        dt[(idx0 + p)*256 + tid] = dev_softplus(a);
    }
    if (tid < 128){
        int p = tid >> 5, j = tid & 31;
        if (j < 16) Bm[(idx0 + p)*16 + j]        = dbc[p][8 + j];
        else        Cm[(idx0 + p)*16 + (j - 16)] = dbc[p][8 + j];
    }
}

__global__ void __launch_bounds__(256)
k_xproj2(const float* __restrict__ um, const float* __restrict__ mxw, const float* __restrict__ mdtw,
         const float* __restrict__ mdtb, float* __restrict__ dtm, float* __restrict__ Bmm,
         float* __restrict__ Cmm,
         const float* __restrict__ uv, const float* __restrict__ vxw, const float* __restrict__ vdtw,
         const float* __restrict__ vdtb, float* __restrict__ dtv, float* __restrict__ Bmv,
         float* __restrict__ Cmv)
{
    if (blockIdx.x < 512){
        int bk = blockIdx.x >> 8;
        size_t idx0 = (size_t)bk*1024 + (blockIdx.x & 255)*4;
        xproj_body(idx0, 0, um, mxw, mdtw, mdtb, dtm, Bmm, Cmm);
    } else {
        int blk = blockIdx.x - 512;
        int bk = blk >> 8;
        size_t idx0 = (size_t)bk*1024 + (blk & 255)*4;
        xproj_body(idx0, bk & 3, uv, vxw, vdtw, vdtb, dtv, Bmv, Cmv);
    }
}

// ================= scan pass A =================
__device__ __forceinline__ void scanA_body(int bk, int c, int k, const float* __restrict__ dt,
    const float* __restrict__ u, const float* __restrict__ Bm, const float* __restrict__ Alog,
    float* __restrict__ Pb, float* __restrict__ Qb)
{
    int d = threadIdx.x;
    __shared__ float Bsh[CH][16];
    {
        int j = threadIdx.x >> 4, s = threadIdx.x & 15;
        Bsh[j][s] = Bm[((size_t)bk*1024 + c*CH + j)*16 + s];
    }
    float dtv[CH], duv[CH];
    size_t base = ((size_t)bk*1024 + c*CH)*256 + d;
    #pragma unroll
    for (int j = 0; j < CH; ++j){
        float a = dt[base + (size_t)j*256];
        float b = u [base + (size_t)j*256];
        dtv[j] = a; duv[j] = a*b;
    }
    float A[16];
    const float4* Ap = (const float4*)(Alog + ((size_t)k*256 + d)*16);
    #pragma unroll
    for (int q = 0; q < 4; ++q){
        float4 v = Ap[q];
        A[q*4+0] = -__expf(v.x); A[q*4+1] = -__expf(v.y);
        A[q*4+2] = -__expf(v.z); A[q*4+3] = -__expf(v.w);
    }
    __syncthreads();
    float Q[16];
    #pragma unroll
    for (int s = 0; s < 16; ++s) Q[s] = 0.f;
    float S = 0.f;
    #pragma unroll
    for (int j = 0; j < CH; ++j){
        S += dtv[j];
        #pragma unroll
        for (int s = 0; s < 16; ++s){
            float av = __expf(dtv[j]*A[s]);
            Q[s] = fmaf(av, Q[s], duv[j]*Bsh[j][s]);
        }
    }
    size_t oidx = ((size_t)(bk*NCH + c)*256 + d)*16;
    float4* Pp = (float4*)(Pb + oidx);
    float4* Qp = (float4*)(Qb + oidx);
    #pragma unroll
    for (int q = 0; q < 4; ++q){
        float4 pv, qv;
        pv.x = __expf(S*A[q*4+0]); pv.y = __expf(S*A[q*4+1]);
        pv.z = __expf(S*A[q*4+2]); pv.w = __expf(S*A[q*4+3]);
        qv.x = Q[q*4+0]; qv.y = Q[q*4+1]; qv.z = Q[q*4+2]; qv.w = Q[q*4+3];
        Pp[q] = pv; Qp[q] = qv;
    }
}

__global__ void __launch_bounds__(256)
k_scanA2(const float* __restrict__ dtm, const float* __restrict__ um, const float* __restrict__ Bmm,
         const float* __restrict__ mAlog, float* __restrict__ Pbm, float* __restrict__ Qbm,
         const float* __restrict__ dtv, const float* __restrict__ uv, const float* __restrict__ Bmv,
         const float* __restrict__ vAlog, float* __restrict__ Pbv, float* __restrict__ Qbv)
{
    if (blockIdx.x < 128){
        int blk = blockIdx.x;
        scanA_body(blk >> 6, blk & (NCH-1), 0, dtm, um, Bmm, mAlog, Pbm, Qbm);
    } else {
        int blk = blockIdx.x - 128;
        int bk = blk >> 6;
        scanA_body(bk, blk & (NCH-1), bk & 3, dtv, uv, Bmv, vAlog, Pbv, Qbv);
    }
}

// ================= scan pass P =================
__device__ __forceinline__ void scanP_body(int bk, int dg, float* __restrict__ Pb,
                                           const float* __restrict__ Qb)
{
    int tid = threadIdx.x;
    size_t idx0 = (size_t)bk*NCH*4096 + dg*256 + tid;
    float Pv[NCH], Qv[NCH];
    #pragma unroll
    for (int c = 0; c < NCH; ++c){
        Pv[c] = Pb[idx0 + (size_t)c*4096];
        Qv[c] = Qb[idx0 + (size_t)c*4096];
    }
    float h = 0.f;
    #pragma unroll
    for (int c = 0; c < NCH; ++c){
        Pb[idx0 + (size_t)c*4096] = h;
        h = fmaf(Pv[c], h, Qv[c]);
    }
}

__global__ void __launch_bounds__(256)
k_scanP2(float* __restrict__ Pbm, const float* __restrict__ Qbm,
         float* __restrict__ Pbv, const float* __restrict__ Qbv)
{
    if (blockIdx.x < 32) scanP_body(blockIdx.x >> 4, blockIdx.x & 15, Pbm, Qbm);
    else { int blk = blockIdx.x - 32; scanP_body(blk >> 4, blk & 15, Pbv, Qbv); }
}

// ================= scan pass B =================
__device__ __forceinline__ void scanB_body(int bk, int c, int k, const float* __restrict__ dt,
    const float* __restrict__ u, const float* __restrict__ Bm, const float* __restrict__ Cm,
    const float* __restrict__ Alog, const float* __restrict__ Hb, float* __restrict__ y)
{
    int d = threadIdx.x;
    __shared__ float Bsh[CH][16], Csh[CH][16];
    {
        int j = threadIdx.x >> 4, s = threadIdx.x & 15;
        size_t bi = ((size_t)bk*1024 + c*CH + j)*16 + s;
        Bsh[j][s] = Bm[bi];
        Csh[j][s] = Cm[bi];
    }
    float dtv[CH], duv[CH];
    size_t base = ((size_t)bk*1024 + c*CH)*256 + d;
    #pragma unroll
    for (int j = 0; j < CH; ++j){
        float a = dt[base + (size_t)j*256];
        float b = u [base + (size_t)j*256];
        dtv[j] = a; duv[j] = a*b;
    }
    float A[16];
    const float4* Ap = (const float4*)(Alog + ((size_t)k*256 + d)*16);
    #pragma unroll
    for (int q = 0; q < 4; ++q){
        float4 v = Ap[q];
        A[q*4+0] = -__expf(v.x); A[q*4+1] = -__expf(v.y);
        A[q*4+2] = -__expf(v.z); A[q*4+3] = -__expf(v.w);
    }
    float h[16];
    const float4* Hp = (const float4*)(Hb + ((size_t)(bk*NCH + c)*256 + d)*16);
    #pragma unroll
    for (int q = 0; q < 4; ++q){
        float4 v = Hp[q];
        h[q*4+0] = v.x; h[q*4+1] = v.y; h[q*4+2] = v.z; h[q*4+3] = v.w;
    }
    __syncthreads();
    float* yp = y + base;
    #pragma unroll
    for (int j = 0; j < CH; ++j){
        float py = 0.f;
        #pragma unroll
        for (int s = 0; s < 16; ++s){
            float av = __expf(dtv[j]*A[s]);
            h[s] = fmaf(av, h[s], duv[j]*Bsh[j][s]);
            py = fmaf(h[s], Csh[j][s], py);
        }
        yp[(size_t)j*256] = py;
    }
}

__global__ void __launch_bounds__(256)
k_scanB2(const float* __restrict__ dtm, const float* __restrict__ um, const float* __restrict__ Bmm,
         const float* __restrict__ Cmm, const float* __restrict__ mAlog,
         const float* __restrict__ Hbm, float* __restrict__ ym,
         const float* __restrict__ dtv, const float* __restrict__ uv, const float* __restrict__ Bmv,
         const float* __restrict__ Cmv, const float* __restrict__ vAlog,
         const float* __restrict__ Hbv, float* __restrict__ yv)
{
    if (blockIdx.x < 128){
        int blk = blockIdx.x;
        scanB_body(blk >> 6, blk & (NCH-1), 0, dtm, um, Bmm, Cmm, mAlog, Hbm, ym);
    } else {
        int blk = blockIdx.x - 128;
        int bk = blk >> 6;
        scanB_body(bk, blk & (NCH-1), bk & 3, dtv, uv, Bmv, Cmv, vAlog, Hbv, yv);
    }
}

// ================= epilogues =================
__device__ __forceinline__ void mout_body(int bl0, const float* __restrict__ y,
    const float* __restrict__ uc, const float* __restrict__ z, const float* __restrict__ Dp,
    const float* __restrict__ ow, float* __restrict__ sm)
{
    int tid = threadIdx.x;
    int row = tid >> 5, c0 = (tid & 31) * 8;
    __shared__ float gld[8][264];
    size_t base = (size_t)(bl0 + row)*256 + c0;
    #pragma unroll
    for (int i = 0; i < 8; i += 4){
        float4 yv = *(const float4*)(y + base + i);
        float4 uv = *(const float4*)(uc + base + i);
        float4 zv = *(const float4*)(z + base + i);
        float4 dv = *(const float4*)(Dp + c0 + i);
        gld[row][c0+i+0] = (yv.x + uv.x*dv.x) * dev_silu(zv.x);
        gld[row][c0+i+1] = (yv.y + uv.y*dv.y) * dev_silu(zv.y);
        gld[row][c0+i+2] = (yv.z + uv.z*dv.z) * dev_silu(zv.z);
        gld[row][c0+i+3] = (yv.w + uv.w*dv.w) * dev_silu(zv.w);
    }
    __syncthreads();
    int o = tid & 127, rg = tid >> 7;
    float acc[4] = {0,0,0,0};
    for (int c = 0; c < 256; c += 4){
        float w[4];
        #pragma unroll
        for (int i = 0; i < 4; ++i) w[i] = ow[(size_t)(c+i)*128 + o];
        #pragma unroll
        for (int r = 0; r < 4; ++r){
            float4 h4 = *(const float4*)&gld[rg*4 + r][c];
            acc[r] = fmaf(h4.x, w[0], acc[r]);
            acc[r] = fmaf(h4.y, w[1], acc[r]);
            acc[r] = fmaf(h4.z, w[2], acc[r]);
            acc[r] = fmaf(h4.w, w[3], acc[r]);
        }
    }
    #pragma unroll
    for (int r = 0; r < 4; ++r)
        sm[(size_t)(bl0 + rg*4 + r)*128 + o] += acc[r];
}

__device__ __forceinline__ void vcomb_body(int blk, const float* __restrict__ y,
    const float* __restrict__ us, const float* __restrict__ z, const float* __restrict__ Dp,
    const float* __restrict__ onw, const float* __restrict__ onb, const float* __restrict__ ow,
    float* __restrict__ sv)
{
    int b = blk >> 7;
    int l0 = (blk & 127) * 8;
    int tid = threadIdx.x;
    int row = tid >> 5, c0 = (tid & 31) * 8;
    int l = l0 + row;
    int h = l >> 5, w = l & 31;
    int l1 = (w<<5) + h, l2 = 1023 - l, l3 = 1023 - l1;
    size_t base = (size_t)b*4*1024*256;
    size_t i0 = base + ((size_t)0*1024 + l )*256 + c0;
    size_t i1 = base + ((size_t)1*1024 + l1)*256 + c0;
    size_t i2 = base + ((size_t)2*1024 + l2)*256 + c0;
    size_t i3 = base + ((size_t)3*1024 + l3)*256 + c0;
    float t[8];
    #pragma unroll
    for (int i = 0; i < 8; i += 4){
        float4 yv = *(const float4*)(y + i0 + i);
        float4 uv = *(const float4*)(us + i0 + i);
        float4 dv = *(const float4*)(Dp + 0*256 + c0 + i);
        t[i+0] = yv.x + uv.x*dv.x; t[i+1] = yv.y + uv.y*dv.y;
        t[i+2] = yv.z + uv.z*dv.z; t[i+3] = yv.w + uv.w*dv.w;
    }
    #pragma unroll
    for (int i = 0; i < 8; i += 4){
        float4 yv = *(const float4*)(y + i1 + i);
        float4 uv = *(const float4*)(us + i1 + i);
        float4 dv = *(const float4*)(Dp + 1*256 + c0 + i);
        t[i+0] += yv.x + uv.x*dv.x; t[i+1] += yv.y + uv.y*dv.y;
        t[i+2] += yv.z + uv.z*dv.z; t[i+3] += yv.w + uv.w*dv.w;
    }
    #pragma unroll
    for (int i = 0; i < 8; i += 4){
        float4 yv = *(const float4*)(y + i2 + i);
        float4 uv = *(const float4*)(us + i2 + i);
        float4 dv = *(const float4*)(Dp + 2*256 + c0 + i);
        t[i+0] += yv.x + uv.x*dv.x; t[i+1] += yv.y + uv.y*dv.y;
        t[i+2] += yv.z + uv.z*dv.z; t[i+3] += yv.w + uv.w*dv.w;
    }
    #pragma unroll
    for (int i = 0; i < 8; i += 4){
        float4 yv = *(const float4*)(y + i3 + i);
        float4 uv = *(const float4*)(us + i3 + i);
        float4 dv = *(const float4*)(Dp + 3*256 + c0 + i);
        t[i+0] += yv.x + uv.x*dv.x; t[i+1] += yv.y + uv.y*dv.y;
        t[i+2] += yv.z + uv.z*dv.z; t[i+3] += yv.w + uv.w*dv.w;
    }
    float a = 0.f, q = 0.f;
    #pragma unroll
    for (int i = 0; i < 8; ++i){ a += t[i]; q += t[i]*t[i]; }
    #pragma unroll
    for (int o = 16; o; o >>= 1){ a += __shfl_xor(a, o); q += __shfl_xor(q, o); }
    float mean = a * (1.0f/256.0f);
    float rs = rsqrtf(q * (1.0f/256.0f) - mean*mean + 1e-5f);
    __shared__ float gld[8][264];
    size_t zbase = (size_t)(b*1024 + l)*256 + c0;
    #pragma unroll
    for (int i = 0; i < 8; i += 4){
        float4 wv = *(const float4*)(onw + c0 + i);
        float4 bv = *(const float4*)(onb + c0 + i);
        float4 zv = *(const float4*)(z + zbase + i);
        gld[row][c0+i+0] = ((t[i+0]-mean)*rs*wv.x + bv.x) * dev_silu(zv.x);
        gld[row][c0+i+1] = ((t[i+1]-mean)*rs*wv.y + bv.y) * dev_silu(zv.y);
        gld[row][c0+i+2] = ((t[i+2]-mean)*rs*wv.z + bv.z) * dev_silu(zv.z);
        gld[row][c0+i+3] = ((t[i+3]-mean)*rs*wv.w + bv.w) * dev_silu(zv.w);
    }
    __syncthreads();
    int o = tid & 127, rg = tid >> 7;
    float acc[4] = {0,0,0,0};
    for (int c = 0; c < 256; c += 4){
        float wv[4];
        #pragma unroll
        for (int i = 0; i < 4; ++i) wv[i] = ow[(size_t)(c+i)*128 + o];
        #pragma unroll
        for (int r = 0; r < 4; ++r){
            float4 h4 = *(const float4*)&gld[rg*4 + r][c];
            acc[r] = fmaf(h4.x, wv[0], acc[r]);
            acc[r] = fmaf(h4.y, wv[1], acc[r]);
            acc[r] = fmaf(h4.z, wv[2], acc[r]);
            acc[r] = fmaf(h4.w, wv[3], acc[r]);
        }
    }
    #pragma unroll
    for (int r = 0; r < 4; ++r)
        sv[(size_t)(b*1024 + l0 + rg*4 + r)*128 + o] += acc[r];
}

__global__ void __launch_bounds__(256)
k_epi2(const float* __restrict__ ym, const float* __restrict__ uc, const float* __restrict__ zm,
       const float* __restrict__ mD, const float* __restrict__ mow, float* __restrict__ sm,
       const float* __restrict__ yv, const float* __restrict__ us, const float* __restrict__ zv,
       const float* __restrict__ vD, const float* __restrict__ onw, const float* __restrict__ onb,
       const float* __restrict__ vow, float* __restrict__ sv)
{
    if (blockIdx.x < 256) mout_body(blockIdx.x*8, ym, uc, zm, mD, mow, sm);
    else                  vcomb_body(blockIdx.x-256, yv, us, zv, vD, onw, onb, vow, sv);
}

// ---- im2col (zero-pad folded): Bt[n=b*1024+p][k=c*9+kh*3+kw] bf16, from sm/sv ----
__global__ void __launch_bounds__(256)
k_im2col(const float* __restrict__ sm, const float* __restrict__ sv,
         unsigned short* __restrict__ Bt)
{
    int n = blockIdx.x; int b = n >> 10, p = n & 1023;
    int h = p >> 5, w = p & 31;
    int tid = threadIdx.x;
    #pragma unroll
    for (int it = 0; it < 9; ++it){                  // 9*256 = 2304 = K exactly
        int k = it*256 + tid;
        int c = k / 9, r = k - c*9;
        int kh = r / 3, kw = r - kh*3;
        int hh = h + kh - 1, ww = w + kw - 1;
        float v = 0.f;
        if (hh >= 0 && hh < 32 && ww >= 0 && ww < 32){
            int l = (hh << 5) + ww;
            v = (c < 128) ? sm[((size_t)b*1024 + l)*128 + c]
                          : sv[((size_t)b*1024 + l)*128 + (c - 128)];
        }
        Bt[(size_t)n*2304 + k] = dev_bf16(v);
    }
}

// ---- bf16 MFMA GEMM: out[o][n] = W[o][:]·Bt[n][:], + bias + BN + ReLU ----
__global__ void __launch_bounds__(256)
k_fgemm(const unsigned short* __restrict__ Wb, const unsigned short* __restrict__ Bt,
        const float* __restrict__ fb, const float* __restrict__ bg, const float* __restrict__ bb,
        const float* __restrict__ bm, const float* __restrict__ bv, float* __restrict__ out)
{
    int o0 = (blockIdx.x & 3) * 64;
    int n0 = (blockIdx.x >> 2) * 64;
    int tid = threadIdx.x, lane = tid & 63, wid = tid >> 6;
    int wm = (wid >> 1) * 32, wn = (wid & 1) * 32;
    __shared__ unsigned short sA[64*40];   // rows padded to 80B (bank-even)
    __shared__ unsigned short sB[64*40];
    f32x4 acc[2][2] = {};
    int srow = tid >> 2, scol = (tid & 3) * 8;
    const u32x4* gA = (const u32x4*)(Wb + (size_t)(o0 + srow)*2304 + scol);
    const u32x4* gB = (const u32x4*)(Bt + (size_t)(n0 + srow)*2304 + scol);
    u32x4* wA = (u32x4*)(sA + srow*40 + scol);
    u32x4* wB = (u32x4*)(sB + srow*40 + scol);
    int fr = lane & 15, fk = (lane >> 4) * 8;
    const unsigned short* rA0 = sA + (wm + fr)*40 + fk;
    const unsigned short* rA1 = sA + (wm + 16 + fr)*40 + fk;
    const unsigned short* rB0 = sB + (wn + fr)*40 + fk;
    const unsigned short* rB1 = sB + (wn + 16 + fr)*40 + fk;
    for (int kt = 0; kt < 72; ++kt){
        u32x4 va = gA[kt*4];
        u32x4 vb = gB[kt*4];
        __syncthreads();
        *wA = va; *wB = vb;
        __syncthreads();
        bf16x8 a0 = *(const bf16x8*)rA0;
        bf16x8 a1 = *(const bf16x8*)rA1;
        bf16x8 b0 = *(const bf16x8*)rB0;
        bf16x8 b1 = *(const bf16x8*)rB1;
        acc[0][0] = __builtin_amdgcn_mfma_f32_16x16x32_bf16(a0, b0, acc[0][0], 0, 0, 0);
        acc[0][1] = __builtin_amdgcn_mfma_f32_16x16x32_bf16(a0, b1, acc[0][1], 0, 0, 0);
        acc[1][0] = __builtin_amdgcn_mfma_f32_16x16x32_bf16(a1, b0, acc[1][0], 0, 0, 0);
        acc[1][1] = __builtin_amdgcn_mfma_f32_16x16x32_bf16(a1, b1, acc[1][1], 0, 0, 0);
    }
    #pragma unroll
    for (int i = 0; i < 2; ++i){
        int ob = o0 + wm + i*16 + (lane >> 4) * 4;
        #pragma unroll
        for (int j = 0; j < 2; ++j){
            int n = n0 + wn + j*16 + (lane & 15);
            int b = n >> 10, p = n & 1023;
            #pragma unroll
            for (int q = 0; q < 4; ++q){
                int o = ob + q;
                float v = acc[i][j][q] + fb[o];
                v = (v - bm[o]) * rsqrtf(bv[o] + 1e-5f) * bg[o] + bb[o];
                out[((size_t)(b*256 + o))*1024 + p] = fmaxf(v, 0.f);
            }
        }
    }
}

extern "C" void kernel_launch(void* const* d_in, const int* in_sizes, int n_in,
                              void* d_out, int out_size, void* d_ws, size_t ws_size,
                              hipStream_t stream)
{
    const float* x         = (const float*)d_in[0];
    const float* proj1_w   = (const float*)d_in[1];
    const float* proj1_b   = (const float*)d_in[2];
    const float* proj2_w   = (const float*)d_in[3];
    const float* proj2_b   = (const float*)d_in[4];
    const float* m_ln_w    = (const float*)d_in[5];
    const float* m_ln_b    = (const float*)d_in[6];
    const float* m_in_w    = (const float*)d_in[7];
    const float* m_conv_w  = (const float*)d_in[8];
    const float* m_conv_b  = (const float*)d_in[9];
    const float* m_xproj_w = (const float*)d_in[10];
    const float* m_dt_w    = (const float*)d_in[11];
    const float* m_dt_b    = (const float*)d_in[12];
    const float* m_Alog    = (const float*)d_in[13];
    const float* m_D       = (const float*)d_in[14];
    const float* m_out_w   = (const float*)d_in[15];
    const float* v_ln_w    = (const float*)d_in[16];
    const float* v_ln_b    = (const float*)d_in[17];
    const float* v_in_w    = (const float*)d_in[18];
    const float* v_conv_w  = (const float*)d_in[19];
    const float* v_conv_b  = (const float*)d_in[20];
    const float* v_xproj_w = (const float*)d_in[21];
    const float* v_dt_w    = (const float*)d_in[22];
    const float* v_dt_b    = (const float*)d_in[23];
    const float* v_Alog    = (const float*)d_in[24];
    const float* v_D       = (const float*)d_in[25];
    const float* v_onorm_w = (const float*)d_in[26];
    const float* v_onorm_b = (const float*)d_in[27];
    const float* v_out_w   = (const float*)d_in[28];
    const float* fuse_w    = (const float*)d_in[29];
    const float* fuse_b    = (const float*)d_in[30];
    const float* bn_g      = (const float*)d_in[31];
    const float* bn_b      = (const float*)d_in[32];
    const float* bn_m      = (const float*)d_in[33];
    const float* bn_v      = (const float*)d_in[34];
    float* out = (float*)d_out;

    float* ws = (float*)d_ws;
    float* sm     = ws;  ws += 2*1024*128;
    float* sv     = ws;  ws += 2*1024*128;
    float* uraw_m = ws;  ws += 2*1024*256;
    float* zb_m   = ws;  ws += 2*1024*256;
    float* uc     = ws;  ws += 2*1024*256;     // mamba post-conv u
    float* uraw_v = ws;  ws += 2*1024*256;
    float* zb_v   = ws;  ws += 2*1024*256;
    float* usb    = ws;  ws += 2*4*1024*256;   // vss 4-direction sequences
    float* dt_m   = ws;  ws += 2*1024*256;
    float* yb_m   = ws;  ws += 2*1024*256;
    float* Pb_m   = ws;  ws += 2*NCH*256*16;
    float* Qb_m   = ws;  ws += 2*NCH*256*16;
    float* Bm_m   = ws;  ws += 2*1024*16;
    float* Cm_m   = ws;  ws += 2*1024*16;
    float* dt_v   = ws;  ws += 2*4*1024*256;   // (followed by yb_v for Bmat alias)
    float* yb_v   = ws;  ws += 2*4*1024*256;
    float* Pb_v   = ws;  ws += 2*4*NCH*256*16;
    float* Qb_v   = ws;  ws += 2*4*NCH*256*16;
    float* Bm_v   = ws;  ws += 2*4*1024*16;
    float* Cm_v   = ws;  ws += 2*4*1024*16;
    float* wtc    = ws;  ws += 256*256;
    unsigned short* Wbf = (unsigned short*)ws;  ws += 576*1024/2;
    unsigned short* Bmat = (unsigned short*)dt_v;   // 9.44 MB <= dt_v+yb_v (16.8 MB), dead by then

    k_prep<<<640,   256, 0, stream>>>(proj1_w, proj2_w, wtc, fuse_w, Wbf);
    k_proj<<<2*256, 256, 0, stream>>>(x, wtc, proj1_b, proj2_b, sm, sv);

    for (int i = 0; i < 2; ++i){
        k_lnmm2 <<<512,  256, 0, stream>>>(sm, m_ln_w + i*128, m_ln_b + i*128,
                                           m_in_w + (size_t)i*65536, uraw_m, zb_m,
                                           sv, v_ln_w + i*128, v_ln_b + i*128,
                                           v_in_w + (size_t)i*65536, uraw_v, zb_v);
        k_conv2 <<<4096, 256, 0, stream>>>(uraw_m, m_conv_w + (size_t)i*1024, m_conv_b + i*256, uc,
                                           uraw_v, v_conv_w + (size_t)i*2304, v_conv_b + i*256, usb);
        k_xproj2<<<2560, 256, 0, stream>>>(uc,  m_xproj_w + (size_t)i*10240,
                                           m_dt_w + (size_t)i*2048, m_dt_b + i*256,
                                           dt_m, Bm_m, Cm_m,
                                           usb, v_xproj_w + (size_t)i*40960,
                                           v_dt_w + (size_t)i*8192, v_dt_b + (size_t)i*1024,
                                           dt_v, Bm_v, Cm_v);
        k_scanA2<<<640,  256, 0, stream>>>(dt_m, uc,  Bm_m, m_Alog + (size_t)i*4096,  Pb_m, Qb_m,
                                           dt_v, usb, Bm_v, v_Alog + (size_t)i*16384, Pb_v, Qb_v);
        k_scanP2<<<160,  256, 0, stream>>>(Pb_m, Qb_m, Pb_v, Qb_v);
        k_scanB2<<<640,  256, 0, stream>>>(dt_m, uc,  Bm_m, Cm_m, m_Alog + (size_t)i*4096,
                                           Pb_m, yb_m,
                                           dt_v, usb, Bm_v, Cm_v, v_Alog + (size_t)i*16384,
                                           Pb_v, yb_v);
        k_epi2  <<<512,  256, 0, stream>>>(yb_m, uc, zb_m, m_D + i*256,
                                           m_out_w + (size_t)i*32768, sm,
                                           yb_v, usb, zb_v, v_D + (size_t)i*1024,
                                           v_onorm_w + i*256, v_onorm_b + i*256,
                                           v_out_w + (size_t)i*32768, sv);
    }

    k_im2col<<<2*1024, 256, 0, stream>>>(sm, sv, Bmat);
    k_fgemm <<<4*32,   256, 0, stream>>>(Wbf, Bmat, fuse_b, bn_g, bn_b, bn_m, bn_v, out);
}